// Round 3
// baseline (1322.747 us; speedup 1.0000x reference)
//
#include <hip/hip_runtime.h>
#include <hip/hip_bf16.h>
#include <math.h>
#include <stdint.h>

#define N_NODES 49152
#define N_EDGES 196608
#define NB      2048
#define HIDDEN  256
#define LAT     128
#define FHID    256
#define NFLOWS  4
#define MA      38
#define NNF_    38
#define NEF_    4

typedef __attribute__((ext_vector_type(8))) short bf16x8;
typedef __attribute__((ext_vector_type(4))) float f32x4;

// ---------- hi/lo bf16 packing (hi in top 16 bits, lo in bottom 16) ----------
__device__ inline uint32_t bf16_rne_bits(float v){
    uint32_t u = __float_as_uint(v);
    u += 0x7fffu + ((u >> 16) & 1u);
    return u & 0xffff0000u;
}
__device__ inline uint32_t pack_hl(float v){
    uint32_t hu = bf16_rne_bits(v);
    float r = v - __uint_as_float(hu);
    uint32_t lu = bf16_rne_bits(r);
    return hu | (lu >> 16);
}
__device__ inline float unpack_hl(uint32_t u){
    return __uint_as_float(u & 0xffff0000u) + __uint_as_float(u << 16);
}

__device__ inline void unpack_frag(const uint4& x, const uint4& y, bf16x8& hi, bf16x8& lo){
    union { bf16x8 v; uint32_t u[4]; } H, L;
    H.u[0] = __builtin_amdgcn_perm(x.y, x.x, 0x07060302u);
    H.u[1] = __builtin_amdgcn_perm(x.w, x.z, 0x07060302u);
    H.u[2] = __builtin_amdgcn_perm(y.y, y.x, 0x07060302u);
    H.u[3] = __builtin_amdgcn_perm(y.w, y.z, 0x07060302u);
    L.u[0] = __builtin_amdgcn_perm(x.y, x.x, 0x05040100u);
    L.u[1] = __builtin_amdgcn_perm(x.w, x.z, 0x05040100u);
    L.u[2] = __builtin_amdgcn_perm(y.y, y.x, 0x05040100u);
    L.u[3] = __builtin_amdgcn_perm(y.w, y.z, 0x05040100u);
    hi = H.v; lo = L.v;
}

// ---------------- init / CSR build ----------------

__global__ void k_init(int* __restrict__ cursor, int* __restrict__ gstart, int* __restrict__ gcnt){
    int i = blockIdx.x*256 + threadIdx.x;
    if (i < N_NODES) cursor[i] = 0;
    if (i < NB){ gstart[i] = 0x7fffffff; gcnt[i] = 0; }
}

__global__ void k_embed(const int* __restrict__ x, const float* __restrict__ emb, uint32_t* __restrict__ h){
    int i = blockIdx.x; int c = threadIdx.x;
    h[(size_t)i*HIDDEN + c] = pack_hl(emb[x[i]*HIDDEN + c]);
}

__global__ void k_deg(const int* __restrict__ dst, int* __restrict__ cursor){
    int e = blockIdx.x*256 + threadIdx.x;
    if (e < N_EDGES) atomicAdd(&cursor[dst[e]], 1);
}

__global__ void k_meta(const int* __restrict__ batch, int* __restrict__ gstart, int* __restrict__ gcnt){
    int i = blockIdx.x*256 + threadIdx.x;
    if (i < N_NODES){ int b = batch[i]; atomicMin(&gstart[b], i); atomicAdd(&gcnt[b], 1); }
}

__global__ __launch_bounds__(1024) void k_scan(int* __restrict__ cursor, int* __restrict__ offs){
    __shared__ int part[1024];
    const int tid = threadIdx.x;
    const int CH = N_NODES/1024; // 48
    int local[48];
    int s = 0;
    int base = tid*CH;
    for (int j=0;j<CH;j++){ local[j] = cursor[base+j]; s += local[j]; }
    part[tid] = s;
    __syncthreads();
    for (int off=1; off<1024; off<<=1){
        int v = (tid>=off) ? part[tid-off] : 0;
        __syncthreads();
        part[tid] += v;
        __syncthreads();
    }
    int excl = (tid==0) ? 0 : part[tid-1];
    for (int j=0;j<CH;j++){ offs[base+j] = excl; excl += local[j]; cursor[base+j] = 0; }
    if (tid == 1023) offs[N_NODES] = excl;
}

__global__ void k_scatter(const int* __restrict__ src, const int* __restrict__ dst, const int* __restrict__ attr,
                          const int* __restrict__ offs, int* __restrict__ cursor, int* __restrict__ epack){
    int e = blockIdx.x*256 + threadIdx.x;
    if (e < N_EDGES){
        int d = dst[e];
        int pos = atomicAdd(&cursor[d], 1);
        epack[offs[d] + pos] = (src[e] & 0xffff) | (attr[e] << 16);
    }
}

// ---------------- message aggregation (packed hi/lo activations) ----------------

__global__ void k_aggr(const uint32_t* __restrict__ h, const float* __restrict__ eemb,
                       const int* __restrict__ offs, const int* __restrict__ epack,
                       uint32_t* __restrict__ t){
    int i = blockIdx.x; int c = threadIdx.x;
    float s = unpack_hl(h[(size_t)i*HIDDEN + c]);
    int e0 = offs[i], e1 = offs[i+1];
    for (int j=e0;j<e1;j++){
        int p = epack[j];
        float v = unpack_hl(h[(size_t)(p & 0xffff)*HIDDEN + c]) + eemb[(p>>16)*HIDDEN + c];
        s += fmaxf(v, 0.f);
    }
    t[(size_t)i*HIDDEN + c] = pack_hl(s);
}

// ---------------- weight / activation converters ----------------

__global__ void k_cvt_pack(const float* __restrict__ s, uint32_t* __restrict__ d, int n){
    int i = blockIdx.x*256 + threadIdx.x;
    if (i < n) d[i] = pack_hl(s[i]);
}
__global__ void k_cvt_b16(const float* __restrict__ s, uint16_t* __restrict__ d, int n){
    int i = blockIdx.x*256 + threadIdx.x;
    if (i < n) d[i] = (uint16_t)(bf16_rne_bits(s[i]) >> 16);
}
// masked flow weights, packed split-bf16
__global__ void k_cvt_fw1(const float* __restrict__ w, uint32_t* __restrict__ d){
    int i = blockIdx.x*256 + threadIdx.x;
    if (i >= NFLOWS*FHID*LAT) return;
    int o = (i >> 7) & 255;
    int kk = i & 127;
    float v = (kk <= (o % 127)) ? w[i] : 0.f;
    d[i] = pack_hl(v);
}
__global__ void k_cvt_fw2(const float* __restrict__ w, uint32_t* __restrict__ d){
    int i = blockIdx.x*256 + threadIdx.x;
    if (i >= NFLOWS*2*LAT*FHID) return;
    int o = (i >> 8) & 255;
    int hh = i & 255;
    float v = ((hh % 127) < (o & 127)) ? w[i] : 0.f;
    d[i] = pack_hl(v);
}
// combined mu/lv weight [256][256] + bias [256]
__global__ void k_cvt_mv(const float* __restrict__ mu_w, const float* __restrict__ mu_b,
                         const float* __restrict__ lv_w, const float* __restrict__ lv_b,
                         uint32_t* __restrict__ wpk, float* __restrict__ bpk){
    int i = blockIdx.x*256 + threadIdx.x;
    if (i < 256*256){
        int o = i >> 8, k2 = i & 255;
        float v = (o < 128) ? mu_w[o*256 + k2] : lv_w[(o-128)*256 + k2];
        wpk[i] = pack_hl(v);
    }
    if (i < 256) bpk[i] = (i < 128) ? mu_b[i] : lv_b[i-128];
}

// ---------------- MFMA GEMM:  C[M,N] = act(A[M,K] @ W[N,K]^T + bias) ----------------

template<int SPLIT, int OUTM>
__global__ __launch_bounds__(256) void mfma_gemm(
    const void* __restrict__ Ap, const void* __restrict__ Wp,
    const float* __restrict__ bias, void* __restrict__ Cp,
    int M, int N, int K, int relu)
{
    extern __shared__ __align__(16) char smem[];
    const int tid  = threadIdx.x;
    const int wave = tid >> 6;
    const int lane = tid & 63;
    const int l15  = lane & 15;
    const int lq   = lane >> 4;
    const int l7   = lane & 7;
    const int row0 = blockIdx.y * 64;
    const int n0   = blockIdx.x * 256;
    const int ELB  = SPLIT ? 4 : 2;
    const int KC   = (K < 256) ? K : 256;
    const int GR   = (KC * ELB) >> 4;
    const int rsh  = (GR == 64) ? 6 : ((GR == 32) ? 5 : 4);

    f32x4 acc[4][4];
    #pragma unroll
    for (int mt=0;mt<4;mt++)
        #pragma unroll
        for (int nt=0;nt<4;nt++) acc[mt][nt] = (f32x4)(0.f);

    const char* Ab = (const char*)Ap;
    const char* Wb = (const char*)Wp;

    for (int kbase = 0; kbase < K; kbase += KC) {
        const int rounds = GR >> 2;
        for (int it = 0; it < rounds; ++it) {
            int sbase = it*256 + wave*64;
            int s  = sbase + lane;
            int m  = s >> rsh;
            int gl = (s & (GR-1)) ^ (m & 7);
            const char* gp = Ab + ((size_t)(row0+m)*K + kbase)*ELB + gl*16;
            __builtin_amdgcn_global_load_lds(
                (const __attribute__((address_space(1))) uint32_t*)gp,
                (__attribute__((address_space(3))) uint32_t*)(smem + sbase*16),
                16, 0, 0);
        }
        __syncthreads();

        for (int kc = 0; kc < (KC >> 5); ++kc) {
            bf16x8 bhi[4], blo[4];
            #pragma unroll
            for (int nt=0;nt<4;nt++){
                int n = n0 + wave*64 + nt*16 + l15;
                if (n >= N) n = N-1;
                if (SPLIT){
                    const uint4* wp4 = (const uint4*)(Wb + ((size_t)n*K + kbase + kc*32 + lq*8)*4);
                    uint4 xx = wp4[0], yy = wp4[1];
                    unpack_frag(xx, yy, bhi[nt], blo[nt]);
                } else {
                    bhi[nt] = *(const bf16x8*)(Wb + ((size_t)n*K + kbase + kc*32 + lq*8)*2);
                }
            }
            #pragma unroll
            for (int mt=0;mt<4;mt++){
                const int mb = (mt*16 + l15) << rsh;
                if (SPLIT){
                    int g0 = kc*8 + lq*2;
                    uint4 xx = *(const uint4*)(smem + (size_t)(mb + ((g0  ) ^ l7))*16);
                    uint4 yy = *(const uint4*)(smem + (size_t)(mb + ((g0+1) ^ l7))*16);
                    bf16x8 ahi, alo;
                    unpack_frag(xx, yy, ahi, alo);
                    #pragma unroll
                    for (int nt=0;nt<4;nt++){
                        acc[mt][nt] = __builtin_amdgcn_mfma_f32_16x16x32_bf16(ahi, bhi[nt], acc[mt][nt], 0, 0, 0);
                        acc[mt][nt] = __builtin_amdgcn_mfma_f32_16x16x32_bf16(ahi, blo[nt], acc[mt][nt], 0, 0, 0);
                        acc[mt][nt] = __builtin_amdgcn_mfma_f32_16x16x32_bf16(alo, bhi[nt], acc[mt][nt], 0, 0, 0);
                    }
                } else {
                    int g = kc*4 + lq;
                    bf16x8 a = *(const bf16x8*)(smem + (size_t)(mb + (g ^ l7))*16);
                    #pragma unroll
                    for (int nt=0;nt<4;nt++){
                        acc[mt][nt] = __builtin_amdgcn_mfma_f32_16x16x32_bf16(a, bhi[nt], acc[mt][nt], 0, 0, 0);
                    }
                }
            }
        }
        __syncthreads();
    }

    char* rs = smem + wave*16384;
    const int colbase = n0 + wave*64;
    #pragma unroll
    for (int mt=0;mt<4;mt++){
        #pragma unroll
        for (int nt=0;nt<4;nt++){
            int cl = nt*16 + l15;
            int col = colbase + cl;
            float bb = bias[col < N ? col : N-1];
            #pragma unroll
            for (int reg=0;reg<4;reg++){
                int r = mt*16 + lq*4 + reg;
                float v = acc[mt][nt][reg] + bb;
                if (relu) v = fmaxf(v, 0.f);
                if (OUTM == 0) ((uint32_t*)rs)[r*64 + cl] = pack_hl(v);
                else           ((float*)rs)[r*64 + cl] = v;
            }
        }
    }
    __syncthreads();
    for (int it = 0; it < 32; ++it) {
        int r   = it*2 + (lane>>5);
        int clp = lane & 31;
        int col = colbase + clp*2;
        if (col < N){
            if (OUTM == 0){
                uint2 d = *(const uint2*)((const uint32_t*)rs + r*64 + clp*2);
                *(uint2*)((uint32_t*)Cp + (size_t)(row0+r)*N + col) = d;
            } else if (OUTM == 1){
                const float* f = (const float*)rs + r*64 + clp*2;
                uint32_t b0 = bf16_rne_bits(f[0]) >> 16;
                uint32_t b1 = bf16_rne_bits(f[1]) >> 16;
                *(uint32_t*)((char*)Cp + ((size_t)(row0+r)*N + col)*2) = b0 | (b1 << 16);
            } else {
                float2 d = *(const float2*)((const float*)rs + r*64 + clp*2);
                *(float2*)((float*)Cp + (size_t)(row0+r)*N + col) = d;
            }
        }
    }
}

// ---------------- pooling (packed out) + z0 elementwise ----------------

__global__ void k_pool(const uint32_t* __restrict__ h, const int* __restrict__ gstart,
                       const int* __restrict__ gcnt, uint32_t* __restrict__ hg){
    int b = blockIdx.x; int c = threadIdx.x;
    int s0 = gstart[b]; int n = gcnt[b];
    float s = 0.f;
    for (int j=0;j<n;j++) s += unpack_hl(h[(size_t)(s0+j)*HIDDEN + c]);
    hg[(size_t)b*HIDDEN + c] = pack_hl(s);
}

__global__ void k_z0(const float* __restrict__ mv, const float* __restrict__ eps,
                     float* __restrict__ mu_o, float* __restrict__ lv_o, float* __restrict__ z0_o){
    int i = blockIdx.x*256 + threadIdx.x;
    if (i >= NB*LAT) return;
    int b = i >> 7, l = i & 127;
    float m = mv[(size_t)b*256 + l];
    float v = mv[(size_t)b*256 + l + 128];
    mu_o[i] = m;
    lv_o[i] = v;
    z0_o[i] = m + eps[i]*expf(0.5f*v);
}

// ---------------- fused MFMA flows ----------------
// 32 blocks x 256 threads; wave w owns graphs (rows) [blk*64 + 16w, +16).
// z (packed hi/lo) and h1 (packed) live in LDS; weights (pre-masked, packed) from global.

__global__ __launch_bounds__(256) void k_flows_mfma(
    const float* __restrict__ z0,
    const uint32_t* __restrict__ w1pk, const float* __restrict__ fb1,
    const uint32_t* __restrict__ w2pk, const float* __restrict__ fb2,
    float* __restrict__ zK, uint16_t* __restrict__ zkb, float* __restrict__ sld)
{
    __shared__ __align__(16) uint32_t zS[64][132];    // pad: 132%32=4 -> <=2-way conflicts
    __shared__ __align__(16) uint32_t h1S[64][260];   // pad: 260%32=4
    const int tid  = threadIdx.x;
    const int wave = tid >> 6;
    const int lane = tid & 63;
    const int l15  = lane & 15;
    const int lq   = lane >> 4;
    const int g0   = blockIdx.x * 64;
    const int mrow = wave * 16;

    // load z0 -> packed zS (coalesced)
    #pragma unroll
    for (int i=0;i<32;i++){
        int idx = i*256 + tid;
        int r = idx >> 7, c = idx & 127;
        zS[r][c] = pack_hl(z0[(size_t)(g0+r)*LAT + c]);
    }
    float ldacc[4] = {0.f,0.f,0.f,0.f};
    __syncthreads();

    for (int kf=0; kf<NFLOWS; kf++){
        const uint32_t* w1 = w1pk + (size_t)kf*FHID*LAT;
        const float*    b1 = fb1 + kf*FHID;
        const uint32_t* w2 = w2pk + (size_t)kf*2*LAT*FHID;
        const float*    b2 = fb2 + kf*2*LAT;

        // ---- GEMM1: h1[16x256] = relu(z[16x128] @ w1m^T + b1) ----
        {
            f32x4 acc[16];
            #pragma unroll
            for (int nt=0;nt<16;nt++) acc[nt] = (f32x4)(0.f);
            #pragma unroll
            for (int kc=0;kc<4;kc++){
                uint4 zx = *(const uint4*)&zS[mrow+l15][kc*32 + lq*8];
                uint4 zy = *(const uint4*)&zS[mrow+l15][kc*32 + lq*8 + 4];
                bf16x8 ahi, alo; unpack_frag(zx, zy, ahi, alo);
                #pragma unroll
                for (int nt=0;nt<16;nt++){
                    const uint4* wp = (const uint4*)(w1 + (size_t)(nt*16+l15)*LAT + kc*32 + lq*8);
                    uint4 wx = wp[0], wy = wp[1];
                    bf16x8 bhi, blo; unpack_frag(wx, wy, bhi, blo);
                    acc[nt] = __builtin_amdgcn_mfma_f32_16x16x32_bf16(ahi, bhi, acc[nt], 0, 0, 0);
                    acc[nt] = __builtin_amdgcn_mfma_f32_16x16x32_bf16(ahi, blo, acc[nt], 0, 0, 0);
                    acc[nt] = __builtin_amdgcn_mfma_f32_16x16x32_bf16(alo, bhi, acc[nt], 0, 0, 0);
                }
            }
            #pragma unroll
            for (int nt=0;nt<16;nt++){
                float bb = b1[nt*16 + l15];
                #pragma unroll
                for (int reg=0;reg<4;reg++){
                    float v = fmaxf(acc[nt][reg] + bb, 0.f);
                    h1S[mrow + lq*4 + reg][nt*16 + l15] = pack_hl(v);
                }
            }
        }
        __syncthreads();

        // ---- GEMM2: out[16x256] = h1[16x256] @ w2m^T + b2; update z, log-det ----
        {
            f32x4 acc2[16];
            #pragma unroll
            for (int nt=0;nt<16;nt++) acc2[nt] = (f32x4)(0.f);
            #pragma unroll
            for (int kc=0;kc<8;kc++){
                uint4 hx = *(const uint4*)&h1S[mrow+l15][kc*32 + lq*8];
                uint4 hy = *(const uint4*)&h1S[mrow+l15][kc*32 + lq*8 + 4];
                bf16x8 ahi, alo; unpack_frag(hx, hy, ahi, alo);
                #pragma unroll
                for (int nt=0;nt<16;nt++){
                    const uint4* wp = (const uint4*)(w2 + (size_t)(nt*16+l15)*FHID + kc*32 + lq*8);
                    uint4 wx = wp[0], wy = wp[1];
                    bf16x8 bhi, blo; unpack_frag(wx, wy, bhi, blo);
                    acc2[nt] = __builtin_amdgcn_mfma_f32_16x16x32_bf16(ahi, bhi, acc2[nt], 0, 0, 0);
                    acc2[nt] = __builtin_amdgcn_mfma_f32_16x16x32_bf16(ahi, blo, acc2[nt], 0, 0, 0);
                    acc2[nt] = __builtin_amdgcn_mfma_f32_16x16x32_bf16(alo, bhi, acc2[nt], 0, 0, 0);
                }
            }
            float lg[4] = {0.f,0.f,0.f,0.f};
            #pragma unroll
            for (int nt=0;nt<8;nt++){
                int colm = nt*16 + l15;
                float bbm = b2[colm];
                float bbs = b2[colm + 128];
                #pragma unroll
                for (int reg=0;reg<4;reg++){
                    int row = mrow + lq*4 + reg;
                    float m = acc2[nt][reg] + bbm;
                    float s = acc2[nt+8][reg] + bbs;
                    float g = 1.f/(1.f + expf(-s));
                    float zo = unpack_hl(zS[row][colm]);
                    float zn = g*zo + (1.f - g)*m;
                    zS[row][colm] = pack_hl(zn);
                    lg[reg] += logf(g + 1e-8f);
                }
            }
            #pragma unroll
            for (int reg=0;reg<4;reg++){
                float v = lg[reg];
                v += __shfl_xor(v, 1, 16);
                v += __shfl_xor(v, 2, 16);
                v += __shfl_xor(v, 4, 16);
                v += __shfl_xor(v, 8, 16);
                ldacc[reg] += v;
            }
        }
        __syncthreads();
    }

    // outputs: zK fp32 + bf16, sld
    #pragma unroll
    for (int i=0;i<32;i++){
        int idx = i*256 + tid;
        int r = idx >> 7, c = idx & 127;
        uint32_t u = zS[r][c];
        zK[(size_t)(g0+r)*LAT + c] = unpack_hl(u);
        zkb[(size_t)(g0+r)*LAT + c] = (uint16_t)(u >> 16);
    }
    if (l15 == 0){
        #pragma unroll
        for (int reg=0;reg<4;reg++)
            sld[g0 + mrow + lq*4 + reg] = ldacc[reg];
    }
}

// ---------------- edge-logits symmetrize ----------------

__global__ void k_sym(const float* __restrict__ raw, float* __restrict__ outp){
    int idx = blockIdx.x*256 + threadIdx.x;
    const int total = NB*MA*MA;
    if (idx >= total) return;
    int b = idx / (MA*MA);
    int rem = idx - b*(MA*MA);
    int i = rem / MA;
    int j = rem - i*MA;
    const size_t base = (size_t)b*(MA*MA*NEF_);
    const float4 a  = *(const float4*)(raw + base + (size_t)(i*MA + j)*NEF_);
    const float4 bt = *(const float4*)(raw + base + (size_t)(j*MA + i)*NEF_);
    float4 r;
    r.x = (a.x + bt.x)*0.5f;
    r.y = (a.y + bt.y)*0.5f;
    r.z = (a.z + bt.z)*0.5f;
    r.w = (a.w + bt.w)*0.5f;
    *(float4*)(outp + base + (size_t)(i*MA + j)*NEF_) = r;
}

// ---------------- launch ----------------

extern "C" void kernel_launch(void* const* d_in, const int* in_sizes, int n_in,
                              void* d_out, int out_size, void* d_ws, size_t ws_size,
                              hipStream_t stream){
    (void)in_sizes; (void)n_in; (void)out_size; (void)ws_size;
    const int*   x        = (const int*)d_in[0];
    const int*   eidx     = (const int*)d_in[1];
    const int*   eattr    = (const int*)d_in[2];
    const int*   batch    = (const int*)d_in[3];
    const float* eps      = (const float*)d_in[4];
    const float* node_emb = (const float*)d_in[5];
    const float* edge_emb = (const float*)d_in[6];
    const float* conv_w1  = (const float*)d_in[7];
    const float* conv_b1  = (const float*)d_in[8];
    const float* conv_w2  = (const float*)d_in[9];
    const float* conv_b2  = (const float*)d_in[10];
    const float* mu_w     = (const float*)d_in[11];
    const float* mu_b     = (const float*)d_in[12];
    const float* lv_w     = (const float*)d_in[13];
    const float* lv_b     = (const float*)d_in[14];
    const float* fw1      = (const float*)d_in[15];
    const float* fb1      = (const float*)d_in[16];
    const float* fw2      = (const float*)d_in[17];
    const float* fb2      = (const float*)d_in[18];
    const float* dn_w1    = (const float*)d_in[19];
    const float* dn_b1    = (const float*)d_in[20];
    const float* dn_w2    = (const float*)d_in[21];
    const float* dn_b2    = (const float*)d_in[22];
    const float* de_w1    = (const float*)d_in[23];
    const float* de_b1    = (const float*)d_in[24];
    const float* de_w2    = (const float*)d_in[25];
    const float* de_b2    = (const float*)d_in[26];

    float* out = (float*)d_out;
    const size_t off_node = 0;
    const size_t off_edge = (size_t)NB*MA*NNF_;
    const size_t off_mu   = off_edge + (size_t)NB*MA*MA*NEF_;
    const size_t off_lv   = off_mu + (size_t)NB*LAT;
    const size_t off_z0   = off_lv + (size_t)NB*LAT;
    const size_t off_zk   = off_z0 + (size_t)NB*LAT;
    const size_t off_sld  = off_zk + (size_t)NB*LAT;

    char* p = (char*)d_ws;
    auto alloc = [&](size_t bytes)->char*{ char* r = p; p += (bytes + 255) & ~(size_t)255; return r; };
    uint32_t* h_pk  = (uint32_t*)alloc((size_t)N_NODES*HIDDEN*4);
    uint32_t* t_pk  = (uint32_t*)alloc((size_t)N_NODES*HIDDEN*4);
    int*   offs   = (int*)  alloc((size_t)(N_NODES+1)*4);
    int*   cursor = (int*)  alloc((size_t)N_NODES*4);
    int*   epack  = (int*)  alloc((size_t)N_EDGES*4);
    int*   gstart = (int*)  alloc((size_t)NB*4);
    int*   gcnt   = (int*)  alloc((size_t)NB*4);
    uint32_t* hg_pk = (uint32_t*)alloc((size_t)NB*HIDDEN*4);
    float* mv       = (float*)alloc((size_t)NB*256*4);
    uint32_t* cw1pk = (uint32_t*)alloc((size_t)4*HIDDEN*HIDDEN*4);
    uint32_t* cw2pk = (uint32_t*)alloc((size_t)4*HIDDEN*HIDDEN*4);
    uint32_t* mvwpk = (uint32_t*)alloc((size_t)256*256*4);
    float*    mvb   = (float*)  alloc((size_t)256*4);
    uint32_t* w1pk  = (uint32_t*)alloc((size_t)NFLOWS*FHID*LAT*4);
    uint32_t* w2pk  = (uint32_t*)alloc((size_t)NFLOWS*2*LAT*FHID*4);
    uint16_t* dnw1b = (uint16_t*)alloc((size_t)256*LAT*2);
    uint16_t* dnw2b = (uint16_t*)alloc((size_t)MA*NNF_*256*2);
    uint16_t* dew1b = (uint16_t*)alloc((size_t)512*LAT*2);
    uint16_t* dew2b = (uint16_t*)alloc((size_t)MA*MA*NEF_*512*2);
    uint16_t* zkb   = (uint16_t*)alloc((size_t)NB*LAT*2);
    uint16_t* hnb   = (uint16_t*)alloc((size_t)NB*256*2);
    uint16_t* heb   = (uint16_t*)alloc((size_t)NB*512*2);
    float* edge_raw = (float*)t_pk;   // alias: trunk done before decoder uses it

    const int* esrc = eidx;
    const int* edst = eidx + N_EDGES;

    // weight conversions
    k_cvt_pack<<<(4*HIDDEN*HIDDEN+255)/256, 256, 0, stream>>>(conv_w1, cw1pk, 4*HIDDEN*HIDDEN);
    k_cvt_pack<<<(4*HIDDEN*HIDDEN+255)/256, 256, 0, stream>>>(conv_w2, cw2pk, 4*HIDDEN*HIDDEN);
    k_cvt_mv<<<(256*256+255)/256, 256, 0, stream>>>(mu_w, mu_b, lv_w, lv_b, mvwpk, mvb);
    k_cvt_fw1<<<(NFLOWS*FHID*LAT+255)/256, 256, 0, stream>>>(fw1, w1pk);
    k_cvt_fw2<<<(NFLOWS*2*LAT*FHID+255)/256, 256, 0, stream>>>(fw2, w2pk);
    k_cvt_b16<<<(256*LAT+255)/256, 256, 0, stream>>>(dn_w1, dnw1b, 256*LAT);
    k_cvt_b16<<<(MA*NNF_*256+255)/256, 256, 0, stream>>>(dn_w2, dnw2b, MA*NNF_*256);
    k_cvt_b16<<<(512*LAT+255)/256, 256, 0, stream>>>(de_w1, dew1b, 512*LAT);
    k_cvt_b16<<<(MA*MA*NEF_*512+255)/256, 256, 0, stream>>>(de_w2, dew2b, MA*MA*NEF_*512);

    k_init   <<<(N_NODES+255)/256, 256, 0, stream>>>(cursor, gstart, gcnt);
    k_embed  <<<N_NODES, HIDDEN, 0, stream>>>(x, node_emb, h_pk);
    k_deg    <<<(N_EDGES+255)/256, 256, 0, stream>>>(edst, cursor);
    k_meta   <<<(N_NODES+255)/256, 256, 0, stream>>>(batch, gstart, gcnt);
    k_scan   <<<1, 1024, 0, stream>>>(cursor, offs);
    k_scatter<<<(N_EDGES+255)/256, 256, 0, stream>>>(esrc, edst, eattr, offs, cursor, epack);

    const size_t SM = 65536;
    for (int k=0;k<4;k++){
        k_aggr<<<N_NODES, HIDDEN, 0, stream>>>(h_pk, edge_emb, offs, epack, t_pk);
        mfma_gemm<1,0><<<dim3(1, N_NODES/64), 256, SM, stream>>>(
            t_pk, cw1pk + (size_t)k*HIDDEN*HIDDEN, conv_b1 + (size_t)k*HIDDEN,
            t_pk, N_NODES, HIDDEN, HIDDEN, 1);
        mfma_gemm<1,0><<<dim3(1, N_NODES/64), 256, SM, stream>>>(
            t_pk, cw2pk + (size_t)k*HIDDEN*HIDDEN, conv_b2 + (size_t)k*HIDDEN,
            h_pk, N_NODES, HIDDEN, HIDDEN, 1);
    }

    k_pool<<<NB, HIDDEN, 0, stream>>>(h_pk, gstart, gcnt, hg_pk);
    // mu|lv = hg @ [mu_w;lv_w]^T : one split-bf16 MFMA GEMM
    mfma_gemm<1,2><<<dim3(1, NB/64), 256, SM, stream>>>(hg_pk, mvwpk, mvb, mv, NB, 256, HIDDEN, 0);
    k_z0<<<(NB*LAT+255)/256, 256, 0, stream>>>(mv, eps, out+off_mu, out+off_lv, out+off_z0);

    k_flows_mfma<<<NB/64, 256, 0, stream>>>(out+off_z0, w1pk, fb1, w2pk, fb2,
                                            out+off_zk, zkb, out+off_sld);

    // decoders (plain bf16 MFMA)
    mfma_gemm<0,1><<<dim3(1, NB/64), 256, SM, stream>>>(zkb, dnw1b, dn_b1, hnb, NB, 256, LAT, 1);
    mfma_gemm<0,2><<<dim3(6, NB/64), 256, SM, stream>>>(hnb, dnw2b, dn_b2, out+off_node, NB, MA*NNF_, 256, 0);
    mfma_gemm<0,1><<<dim3(2, NB/64), 256, SM, stream>>>(zkb, dew1b, de_b1, heb, NB, 512, LAT, 1);
    mfma_gemm<0,2><<<dim3(23, NB/64), 256, SM, stream>>>(heb, dew2b, de_b2, edge_raw, NB, MA*MA*NEF_, 512, 0);
    k_sym<<<(NB*MA*MA + 255)/256, 256, 0, stream>>>(edge_raw, out + off_edge);
}

// Round 4
// 1054.627 us; speedup vs baseline: 1.2542x; 1.2542x over previous
//
#include <hip/hip_runtime.h>
#include <hip/hip_bf16.h>
#include <math.h>
#include <stdint.h>

#define N_NODES 49152
#define N_EDGES 196608
#define NB      2048
#define HIDDEN  256
#define LAT     128
#define FHID    256
#define NFLOWS  4
#define MA      38
#define NNF_    38
#define NEF_    4
#define FGPB    8

typedef __attribute__((ext_vector_type(8))) short bf16x8;
typedef __attribute__((ext_vector_type(4))) float f32x4;

// ---------- hi/lo bf16 packing (hi in top 16 bits, lo in bottom 16) ----------
__device__ inline uint32_t bf16_rne_bits(float v){
    uint32_t u = __float_as_uint(v);
    u += 0x7fffu + ((u >> 16) & 1u);
    return u & 0xffff0000u;
}
__device__ inline uint32_t pack_hl(float v){
    uint32_t hu = bf16_rne_bits(v);
    float r = v - __uint_as_float(hu);
    uint32_t lu = bf16_rne_bits(r);
    return hu | (lu >> 16);
}
__device__ inline float unpack_hl(uint32_t u){
    return __uint_as_float(u & 0xffff0000u) + __uint_as_float(u << 16);
}

__device__ inline void unpack_frag(const uint4& x, const uint4& y, bf16x8& hi, bf16x8& lo){
    union { bf16x8 v; uint32_t u[4]; } H, L;
    H.u[0] = __builtin_amdgcn_perm(x.y, x.x, 0x07060302u);
    H.u[1] = __builtin_amdgcn_perm(x.w, x.z, 0x07060302u);
    H.u[2] = __builtin_amdgcn_perm(y.y, y.x, 0x07060302u);
    H.u[3] = __builtin_amdgcn_perm(y.w, y.z, 0x07060302u);
    L.u[0] = __builtin_amdgcn_perm(x.y, x.x, 0x05040100u);
    L.u[1] = __builtin_amdgcn_perm(x.w, x.z, 0x05040100u);
    L.u[2] = __builtin_amdgcn_perm(y.y, y.x, 0x05040100u);
    L.u[3] = __builtin_amdgcn_perm(y.w, y.z, 0x05040100u);
    hi = H.v; lo = L.v;
}

// ---------------- init / CSR build ----------------

__global__ void k_init(int* __restrict__ cursor, int* __restrict__ gstart, int* __restrict__ gcnt){
    int i = blockIdx.x*256 + threadIdx.x;
    if (i < N_NODES) cursor[i] = 0;
    if (i < NB){ gstart[i] = 0x7fffffff; gcnt[i] = 0; }
}

__global__ void k_embed(const int* __restrict__ x, const float* __restrict__ emb, uint32_t* __restrict__ h){
    int i = blockIdx.x; int c = threadIdx.x;
    h[(size_t)i*HIDDEN + c] = pack_hl(emb[x[i]*HIDDEN + c]);
}

__global__ void k_deg(const int* __restrict__ dst, int* __restrict__ cursor){
    int e = blockIdx.x*256 + threadIdx.x;
    if (e < N_EDGES) atomicAdd(&cursor[dst[e]], 1);
}

__global__ void k_meta(const int* __restrict__ batch, int* __restrict__ gstart, int* __restrict__ gcnt){
    int i = blockIdx.x*256 + threadIdx.x;
    if (i < N_NODES){ int b = batch[i]; atomicMin(&gstart[b], i); atomicAdd(&gcnt[b], 1); }
}

__global__ __launch_bounds__(1024) void k_scan(int* __restrict__ cursor, int* __restrict__ offs){
    __shared__ int part[1024];
    const int tid = threadIdx.x;
    const int CH = N_NODES/1024; // 48
    int local[48];
    int s = 0;
    int base = tid*CH;
    for (int j=0;j<CH;j++){ local[j] = cursor[base+j]; s += local[j]; }
    part[tid] = s;
    __syncthreads();
    for (int off=1; off<1024; off<<=1){
        int v = (tid>=off) ? part[tid-off] : 0;
        __syncthreads();
        part[tid] += v;
        __syncthreads();
    }
    int excl = (tid==0) ? 0 : part[tid-1];
    for (int j=0;j<CH;j++){ offs[base+j] = excl; excl += local[j]; cursor[base+j] = 0; }
    if (tid == 1023) offs[N_NODES] = excl;
}

__global__ void k_scatter(const int* __restrict__ src, const int* __restrict__ dst, const int* __restrict__ attr,
                          const int* __restrict__ offs, int* __restrict__ cursor, int* __restrict__ epack){
    int e = blockIdx.x*256 + threadIdx.x;
    if (e < N_EDGES){
        int d = dst[e];
        int pos = atomicAdd(&cursor[d], 1);
        epack[offs[d] + pos] = (src[e] & 0xffff) | (attr[e] << 16);
    }
}

// ---------------- message aggregation (packed hi/lo activations) ----------------

__global__ void k_aggr(const uint32_t* __restrict__ h, const float* __restrict__ eemb,
                       const int* __restrict__ offs, const int* __restrict__ epack,
                       uint32_t* __restrict__ t){
    int i = blockIdx.x; int c = threadIdx.x;
    float s = unpack_hl(h[(size_t)i*HIDDEN + c]);
    int e0 = offs[i], e1 = offs[i+1];
    for (int j=e0;j<e1;j++){
        int p = epack[j];
        float v = unpack_hl(h[(size_t)(p & 0xffff)*HIDDEN + c]) + eemb[(p>>16)*HIDDEN + c];
        s += fmaxf(v, 0.f);
    }
    t[(size_t)i*HIDDEN + c] = pack_hl(s);
}

// ---------------- weight / activation converters ----------------

__global__ void k_cvt_pack(const float* __restrict__ s, uint32_t* __restrict__ d, int n){
    int i = blockIdx.x*256 + threadIdx.x;
    if (i < n) d[i] = pack_hl(s[i]);
}
__global__ void k_cvt_b16(const float* __restrict__ s, uint16_t* __restrict__ d, int n){
    int i = blockIdx.x*256 + threadIdx.x;
    if (i < n) d[i] = (uint16_t)(bf16_rne_bits(s[i]) >> 16);
}
// masked flow weights, separate hi/lo bf16 planes (source layout kept)
__global__ void k_cvt_fw1s(const float* __restrict__ w, uint16_t* __restrict__ hi, uint16_t* __restrict__ lo){
    int i = blockIdx.x*256 + threadIdx.x;
    if (i >= NFLOWS*FHID*LAT) return;
    int o = (i >> 7) & 255;
    int kk = i & 127;
    float v = (kk <= (o % 127)) ? w[i] : 0.f;
    uint32_t h = bf16_rne_bits(v);
    hi[i] = (uint16_t)(h >> 16);
    lo[i] = (uint16_t)(bf16_rne_bits(v - __uint_as_float(h)) >> 16);
}
__global__ void k_cvt_fw2s(const float* __restrict__ w, uint16_t* __restrict__ hi, uint16_t* __restrict__ lo){
    int i = blockIdx.x*256 + threadIdx.x;
    if (i >= NFLOWS*2*LAT*FHID) return;
    int o = (i >> 8) & 255;
    int hh = i & 255;
    float v = ((hh % 127) < (o & 127)) ? w[i] : 0.f;
    uint32_t h = bf16_rne_bits(v);
    hi[i] = (uint16_t)(h >> 16);
    lo[i] = (uint16_t)(bf16_rne_bits(v - __uint_as_float(h)) >> 16);
}
// combined mu/lv weight [256][256] + bias [256]
__global__ void k_cvt_mv(const float* __restrict__ mu_w, const float* __restrict__ mu_b,
                         const float* __restrict__ lv_w, const float* __restrict__ lv_b,
                         uint32_t* __restrict__ wpk, float* __restrict__ bpk){
    int i = blockIdx.x*256 + threadIdx.x;
    if (i < 256*256){
        int o = i >> 8, k2 = i & 255;
        float v = (o < 128) ? mu_w[o*256 + k2] : lv_w[(o-128)*256 + k2];
        wpk[i] = pack_hl(v);
    }
    if (i < 256) bpk[i] = (i < 128) ? mu_b[i] : lv_b[i-128];
}

// ---------------- MFMA GEMM:  C[M,N] = act(A[M,K] @ W[N,K]^T + bias) ----------------

template<int SPLIT, int OUTM>
__global__ __launch_bounds__(256) void mfma_gemm(
    const void* __restrict__ Ap, const void* __restrict__ Wp,
    const float* __restrict__ bias, void* __restrict__ Cp,
    int M, int N, int K, int relu)
{
    extern __shared__ __align__(16) char smem[];
    const int tid  = threadIdx.x;
    const int wave = tid >> 6;
    const int lane = tid & 63;
    const int l15  = lane & 15;
    const int lq   = lane >> 4;
    const int l7   = lane & 7;
    const int row0 = blockIdx.y * 64;
    const int n0   = blockIdx.x * 256;
    const int ELB  = SPLIT ? 4 : 2;
    const int KC   = (K < 256) ? K : 256;
    const int GR   = (KC * ELB) >> 4;
    const int rsh  = (GR == 64) ? 6 : ((GR == 32) ? 5 : 4);

    f32x4 acc[4][4];
    #pragma unroll
    for (int mt=0;mt<4;mt++)
        #pragma unroll
        for (int nt=0;nt<4;nt++) acc[mt][nt] = (f32x4)(0.f);

    const char* Ab = (const char*)Ap;
    const char* Wb = (const char*)Wp;

    for (int kbase = 0; kbase < K; kbase += KC) {
        const int rounds = GR >> 2;
        for (int it = 0; it < rounds; ++it) {
            int sbase = it*256 + wave*64;
            int s  = sbase + lane;
            int m  = s >> rsh;
            int gl = (s & (GR-1)) ^ (m & 7);
            const char* gp = Ab + ((size_t)(row0+m)*K + kbase)*ELB + gl*16;
            __builtin_amdgcn_global_load_lds(
                (const __attribute__((address_space(1))) uint32_t*)gp,
                (__attribute__((address_space(3))) uint32_t*)(smem + sbase*16),
                16, 0, 0);
        }
        __syncthreads();

        for (int kc = 0; kc < (KC >> 5); ++kc) {
            bf16x8 bhi[4], blo[4];
            #pragma unroll
            for (int nt=0;nt<4;nt++){
                int n = n0 + wave*64 + nt*16 + l15;
                if (n >= N) n = N-1;
                if (SPLIT){
                    const uint4* wp4 = (const uint4*)(Wb + ((size_t)n*K + kbase + kc*32 + lq*8)*4);
                    uint4 xx = wp4[0], yy = wp4[1];
                    unpack_frag(xx, yy, bhi[nt], blo[nt]);
                } else {
                    bhi[nt] = *(const bf16x8*)(Wb + ((size_t)n*K + kbase + kc*32 + lq*8)*2);
                }
            }
            #pragma unroll
            for (int mt=0;mt<4;mt++){
                const int mb = (mt*16 + l15) << rsh;
                if (SPLIT){
                    int g0 = kc*8 + lq*2;
                    uint4 xx = *(const uint4*)(smem + (size_t)(mb + ((g0  ) ^ l7))*16);
                    uint4 yy = *(const uint4*)(smem + (size_t)(mb + ((g0+1) ^ l7))*16);
                    bf16x8 ahi, alo;
                    unpack_frag(xx, yy, ahi, alo);
                    #pragma unroll
                    for (int nt=0;nt<4;nt++){
                        acc[mt][nt] = __builtin_amdgcn_mfma_f32_16x16x32_bf16(ahi, bhi[nt], acc[mt][nt], 0, 0, 0);
                        acc[mt][nt] = __builtin_amdgcn_mfma_f32_16x16x32_bf16(ahi, blo[nt], acc[mt][nt], 0, 0, 0);
                        acc[mt][nt] = __builtin_amdgcn_mfma_f32_16x16x32_bf16(alo, bhi[nt], acc[mt][nt], 0, 0, 0);
                    }
                } else {
                    int g = kc*4 + lq;
                    bf16x8 a = *(const bf16x8*)(smem + (size_t)(mb + (g ^ l7))*16);
                    #pragma unroll
                    for (int nt=0;nt<4;nt++){
                        acc[mt][nt] = __builtin_amdgcn_mfma_f32_16x16x32_bf16(a, bhi[nt], acc[mt][nt], 0, 0, 0);
                    }
                }
            }
        }
        __syncthreads();
    }

    char* rs = smem + wave*16384;
    const int colbase = n0 + wave*64;
    #pragma unroll
    for (int mt=0;mt<4;mt++){
        #pragma unroll
        for (int nt=0;nt<4;nt++){
            int cl = nt*16 + l15;
            int col = colbase + cl;
            float bb = bias[col < N ? col : N-1];
            #pragma unroll
            for (int reg=0;reg<4;reg++){
                int r = mt*16 + lq*4 + reg;
                float v = acc[mt][nt][reg] + bb;
                if (relu) v = fmaxf(v, 0.f);
                if (OUTM == 0) ((uint32_t*)rs)[r*64 + cl] = pack_hl(v);
                else           ((float*)rs)[r*64 + cl] = v;
            }
        }
    }
    __syncthreads();
    for (int it = 0; it < 32; ++it) {
        int r   = it*2 + (lane>>5);
        int clp = lane & 31;
        int col = colbase + clp*2;
        if (col < N){
            if (OUTM == 0){
                uint2 d = *(const uint2*)((const uint32_t*)rs + r*64 + clp*2);
                *(uint2*)((uint32_t*)Cp + (size_t)(row0+r)*N + col) = d;
            } else if (OUTM == 1){
                const float* f = (const float*)rs + r*64 + clp*2;
                uint32_t b0 = bf16_rne_bits(f[0]) >> 16;
                uint32_t b1 = bf16_rne_bits(f[1]) >> 16;
                *(uint32_t*)((char*)Cp + ((size_t)(row0+r)*N + col)*2) = b0 | (b1 << 16);
            } else {
                float2 d = *(const float2*)((const float*)rs + r*64 + clp*2);
                *(float2*)((float*)Cp + (size_t)(row0+r)*N + col) = d;
            }
        }
    }
}

// ---------------- pooling (packed out) + z0 elementwise ----------------

__global__ void k_pool(const uint32_t* __restrict__ h, const int* __restrict__ gstart,
                       const int* __restrict__ gcnt, uint32_t* __restrict__ hg){
    int b = blockIdx.x; int c = threadIdx.x;
    int s0 = gstart[b]; int n = gcnt[b];
    float s = 0.f;
    for (int j=0;j<n;j++) s += unpack_hl(h[(size_t)(s0+j)*HIDDEN + c]);
    hg[(size_t)b*HIDDEN + c] = pack_hl(s);
}

__global__ void k_z0(const float* __restrict__ mv, const float* __restrict__ eps,
                     float* __restrict__ mu_o, float* __restrict__ lv_o, float* __restrict__ z0_o){
    int i = blockIdx.x*256 + threadIdx.x;
    if (i >= NB*LAT) return;
    int b = i >> 7, l = i & 127;
    float m = mv[(size_t)b*256 + l];
    float v = mv[(size_t)b*256 + l + 128];
    mu_o[i] = m;
    lv_o[i] = v;
    z0_o[i] = m + eps[i]*expf(0.5f*v);
}

// ---------------- fused MFMA flows v2 ----------------
// 256 blocks x 256 threads; 8 valid graphs/block (rows 8..15 mirror 0..7).
// Waves split N (64 cols each). Weights: pre-masked hi/lo bf16 planes, register
// double-buffered prefetch. z/h1 as hi/lo bf16 LDS planes, out as fp32 LDS.

__global__ __launch_bounds__(256) void k_flows_mfma2(
    const float* __restrict__ z0,
    const uint16_t* __restrict__ w1hi, const uint16_t* __restrict__ w1lo, const float* __restrict__ fb1,
    const uint16_t* __restrict__ w2hi, const uint16_t* __restrict__ w2lo, const float* __restrict__ fb2,
    float* __restrict__ zK, uint16_t* __restrict__ zkb, float* __restrict__ sld)
{
    __shared__ __align__(16) uint16_t zhi[16][136];
    __shared__ __align__(16) uint16_t zlo[16][136];
    __shared__ __align__(16) uint16_t h1hi[16][272];
    __shared__ __align__(16) uint16_t h1lo[16][272];
    __shared__ __align__(16) float    oS[16][264];
    const int tid  = threadIdx.x;
    const int wave = tid >> 6;
    const int lane = tid & 63;
    const int l15  = lane & 15;
    const int lq   = lane >> 4;
    const int g0   = blockIdx.x * FGPB;

    // load z0 (rows 8..15 mirror 0..7)
    #pragma unroll
    for (int q=0;q<8;q++){
        int idx = q*256 + tid;
        int r = idx >> 7, l = idx & 127;
        float v = z0[(size_t)(g0 + (r & 7))*LAT + l];
        uint32_t h = bf16_rne_bits(v);
        zhi[r][l] = (uint16_t)(h >> 16);
        zlo[r][l] = (uint16_t)(bf16_rne_bits(v - __uint_as_float(h)) >> 16);
    }
    float ldacc = 0.f;
    __syncthreads();

    for (int kf=0; kf<NFLOWS; kf++){
        const uint16_t* W1h = w1hi + (size_t)kf*FHID*LAT;
        const uint16_t* W1l = w1lo + (size_t)kf*FHID*LAT;
        const float*    b1  = fb1 + kf*FHID;
        const uint16_t* W2h = w2hi + (size_t)kf*2*LAT*FHID;
        const uint16_t* W2l = w2lo + (size_t)kf*2*LAT*FHID;
        const float*    b2  = fb2 + kf*2*LAT;

        // ---- GEMM1: h1[16x256] = relu(z @ w1m^T + b1), wave cols [64w,64w+64) ----
        {
            f32x4 acc[4];
            #pragma unroll
            for (int nt=0;nt<4;nt++) acc[nt] = (f32x4)(0.f);
            bf16x8 bh[2][4], bl[2][4];
            #pragma unroll
            for (int nt=0;nt<4;nt++){
                size_t o = (size_t)(wave*64 + nt*16 + l15)*LAT + lq*8;
                bh[0][nt] = *(const bf16x8*)(W1h + o);
                bl[0][nt] = *(const bf16x8*)(W1l + o);
            }
            #pragma unroll
            for (int kc=0;kc<4;kc++){
                int cur = kc & 1, nxt = cur ^ 1;
                if (kc < 3){
                    #pragma unroll
                    for (int nt=0;nt<4;nt++){
                        size_t o = (size_t)(wave*64 + nt*16 + l15)*LAT + (kc+1)*32 + lq*8;
                        bh[nxt][nt] = *(const bf16x8*)(W1h + o);
                        bl[nxt][nt] = *(const bf16x8*)(W1l + o);
                    }
                }
                bf16x8 ah = *(const bf16x8*)&zhi[l15][kc*32 + lq*8];
                bf16x8 al = *(const bf16x8*)&zlo[l15][kc*32 + lq*8];
                #pragma unroll
                for (int nt=0;nt<4;nt++){
                    acc[nt] = __builtin_amdgcn_mfma_f32_16x16x32_bf16(ah, bh[cur][nt], acc[nt], 0, 0, 0);
                    acc[nt] = __builtin_amdgcn_mfma_f32_16x16x32_bf16(ah, bl[cur][nt], acc[nt], 0, 0, 0);
                    acc[nt] = __builtin_amdgcn_mfma_f32_16x16x32_bf16(al, bh[cur][nt], acc[nt], 0, 0, 0);
                }
            }
            #pragma unroll
            for (int nt=0;nt<4;nt++){
                int col = wave*64 + nt*16 + l15;
                float bb = b1[col];
                #pragma unroll
                for (int reg=0;reg<4;reg++){
                    int r = lq*4 + reg;
                    float v = fmaxf(acc[nt][reg] + bb, 0.f);
                    uint32_t h = bf16_rne_bits(v);
                    h1hi[r][col] = (uint16_t)(h >> 16);
                    h1lo[r][col] = (uint16_t)(bf16_rne_bits(v - __uint_as_float(h)) >> 16);
                }
            }
        }
        __syncthreads();

        // ---- GEMM2: out[16x256] = h1 @ w2m^T + b2 ----
        {
            f32x4 acc[4];
            #pragma unroll
            for (int nt=0;nt<4;nt++) acc[nt] = (f32x4)(0.f);
            bf16x8 bh[2][4], bl[2][4];
            #pragma unroll
            for (int nt=0;nt<4;nt++){
                size_t o = (size_t)(wave*64 + nt*16 + l15)*FHID + lq*8;
                bh[0][nt] = *(const bf16x8*)(W2h + o);
                bl[0][nt] = *(const bf16x8*)(W2l + o);
            }
            #pragma unroll
            for (int kc=0;kc<8;kc++){
                int cur = kc & 1, nxt = cur ^ 1;
                if (kc < 7){
                    #pragma unroll
                    for (int nt=0;nt<4;nt++){
                        size_t o = (size_t)(wave*64 + nt*16 + l15)*FHID + (kc+1)*32 + lq*8;
                        bh[nxt][nt] = *(const bf16x8*)(W2h + o);
                        bl[nxt][nt] = *(const bf16x8*)(W2l + o);
                    }
                }
                bf16x8 ah = *(const bf16x8*)&h1hi[l15][kc*32 + lq*8];
                bf16x8 al = *(const bf16x8*)&h1lo[l15][kc*32 + lq*8];
                #pragma unroll
                for (int nt=0;nt<4;nt++){
                    acc[nt] = __builtin_amdgcn_mfma_f32_16x16x32_bf16(ah, bh[cur][nt], acc[nt], 0, 0, 0);
                    acc[nt] = __builtin_amdgcn_mfma_f32_16x16x32_bf16(ah, bl[cur][nt], acc[nt], 0, 0, 0);
                    acc[nt] = __builtin_amdgcn_mfma_f32_16x16x32_bf16(al, bh[cur][nt], acc[nt], 0, 0, 0);
                }
            }
            #pragma unroll
            for (int nt=0;nt<4;nt++){
                int col = wave*64 + nt*16 + l15;
                float bb = b2[col];
                #pragma unroll
                for (int reg=0;reg<4;reg++)
                    oS[lq*4 + reg][col] = acc[nt][reg] + bb;
            }
        }
        __syncthreads();

        // ---- z update + log-det (rows 0..7 valid; mirror into 8..15) ----
        {
            int r  = tid >> 5;       // 0..7
            int lc = tid & 31;
            float ldp = 0.f;
            #pragma unroll
            for (int j=0;j<4;j++){
                int l = lc + j*32;
                float m = oS[r][l];
                float s = oS[r][l + 128];
                float g = 1.f/(1.f + expf(-s));
                float zv = __uint_as_float((uint32_t)zhi[r][l] << 16)
                         + __uint_as_float((uint32_t)zlo[r][l] << 16);
                float zn = g*zv + (1.f - g)*m;
                uint32_t h = bf16_rne_bits(zn);
                uint16_t hb = (uint16_t)(h >> 16);
                uint16_t lb = (uint16_t)(bf16_rne_bits(zn - __uint_as_float(h)) >> 16);
                zhi[r][l] = hb; zlo[r][l] = lb;
                zhi[r+8][l] = hb; zlo[r+8][l] = lb;
                ldp += logf(g + 1e-8f);
            }
            ldp += __shfl_xor(ldp, 1, 32);
            ldp += __shfl_xor(ldp, 2, 32);
            ldp += __shfl_xor(ldp, 4, 32);
            ldp += __shfl_xor(ldp, 8, 32);
            ldp += __shfl_xor(ldp, 16, 32);
            ldacc += ldp;
        }
        __syncthreads();
    }

    // outputs
    #pragma unroll
    for (int q=0;q<4;q++){
        int idx = q*256 + tid;
        int r = idx >> 7, l = idx & 127;
        uint32_t h = (uint32_t)zhi[r][l] << 16;
        float zv = __uint_as_float(h) + __uint_as_float((uint32_t)zlo[r][l] << 16);
        zK[(size_t)(g0+r)*LAT + l] = zv;
        zkb[(size_t)(g0+r)*LAT + l] = (uint16_t)(h >> 16);
    }
    if ((tid & 31) == 0)
        sld[g0 + (tid >> 5)] = ldacc;
}

// ---------------- edge-logits symmetrize ----------------

__global__ void k_sym(const float* __restrict__ raw, float* __restrict__ outp){
    int idx = blockIdx.x*256 + threadIdx.x;
    const int total = NB*MA*MA;
    if (idx >= total) return;
    int b = idx / (MA*MA);
    int rem = idx - b*(MA*MA);
    int i = rem / MA;
    int j = rem - i*MA;
    const size_t base = (size_t)b*(MA*MA*NEF_);
    const float4 a  = *(const float4*)(raw + base + (size_t)(i*MA + j)*NEF_);
    const float4 bt = *(const float4*)(raw + base + (size_t)(j*MA + i)*NEF_);
    float4 r;
    r.x = (a.x + bt.x)*0.5f;
    r.y = (a.y + bt.y)*0.5f;
    r.z = (a.z + bt.z)*0.5f;
    r.w = (a.w + bt.w)*0.5f;
    *(float4*)(outp + base + (size_t)(i*MA + j)*NEF_) = r;
}

// ---------------- launch ----------------

extern "C" void kernel_launch(void* const* d_in, const int* in_sizes, int n_in,
                              void* d_out, int out_size, void* d_ws, size_t ws_size,
                              hipStream_t stream){
    (void)in_sizes; (void)n_in; (void)out_size; (void)ws_size;
    const int*   x        = (const int*)d_in[0];
    const int*   eidx     = (const int*)d_in[1];
    const int*   eattr    = (const int*)d_in[2];
    const int*   batch    = (const int*)d_in[3];
    const float* eps      = (const float*)d_in[4];
    const float* node_emb = (const float*)d_in[5];
    const float* edge_emb = (const float*)d_in[6];
    const float* conv_w1  = (const float*)d_in[7];
    const float* conv_b1  = (const float*)d_in[8];
    const float* conv_w2  = (const float*)d_in[9];
    const float* conv_b2  = (const float*)d_in[10];
    const float* mu_w     = (const float*)d_in[11];
    const float* mu_b     = (const float*)d_in[12];
    const float* lv_w     = (const float*)d_in[13];
    const float* lv_b     = (const float*)d_in[14];
    const float* fw1      = (const float*)d_in[15];
    const float* fb1      = (const float*)d_in[16];
    const float* fw2      = (const float*)d_in[17];
    const float* fb2      = (const float*)d_in[18];
    const float* dn_w1    = (const float*)d_in[19];
    const float* dn_b1    = (const float*)d_in[20];
    const float* dn_w2    = (const float*)d_in[21];
    const float* dn_b2    = (const float*)d_in[22];
    const float* de_w1    = (const float*)d_in[23];
    const float* de_b1    = (const float*)d_in[24];
    const float* de_w2    = (const float*)d_in[25];
    const float* de_b2    = (const float*)d_in[26];

    float* out = (float*)d_out;
    const size_t off_node = 0;
    const size_t off_edge = (size_t)NB*MA*NNF_;
    const size_t off_mu   = off_edge + (size_t)NB*MA*MA*NEF_;
    const size_t off_lv   = off_mu + (size_t)NB*LAT;
    const size_t off_z0   = off_lv + (size_t)NB*LAT;
    const size_t off_zk   = off_z0 + (size_t)NB*LAT;
    const size_t off_sld  = off_zk + (size_t)NB*LAT;

    char* p = (char*)d_ws;
    auto alloc = [&](size_t bytes)->char*{ char* r = p; p += (bytes + 255) & ~(size_t)255; return r; };
    uint32_t* h_pk  = (uint32_t*)alloc((size_t)N_NODES*HIDDEN*4);
    uint32_t* t_pk  = (uint32_t*)alloc((size_t)N_NODES*HIDDEN*4);
    int*   offs   = (int*)  alloc((size_t)(N_NODES+1)*4);
    int*   cursor = (int*)  alloc((size_t)N_NODES*4);
    int*   epack  = (int*)  alloc((size_t)N_EDGES*4);
    int*   gstart = (int*)  alloc((size_t)NB*4);
    int*   gcnt   = (int*)  alloc((size_t)NB*4);
    uint32_t* hg_pk = (uint32_t*)alloc((size_t)NB*HIDDEN*4);
    float* mv       = (float*)alloc((size_t)NB*256*4);
    uint32_t* cw1pk = (uint32_t*)alloc((size_t)4*HIDDEN*HIDDEN*4);
    uint32_t* cw2pk = (uint32_t*)alloc((size_t)4*HIDDEN*HIDDEN*4);
    uint32_t* mvwpk = (uint32_t*)alloc((size_t)256*256*4);
    float*    mvb   = (float*)  alloc((size_t)256*4);
    uint16_t* w1hi  = (uint16_t*)alloc((size_t)NFLOWS*FHID*LAT*2);
    uint16_t* w1lo  = (uint16_t*)alloc((size_t)NFLOWS*FHID*LAT*2);
    uint16_t* w2hi  = (uint16_t*)alloc((size_t)NFLOWS*2*LAT*FHID*2);
    uint16_t* w2lo  = (uint16_t*)alloc((size_t)NFLOWS*2*LAT*FHID*2);
    uint16_t* dnw1b = (uint16_t*)alloc((size_t)256*LAT*2);
    uint16_t* dnw2b = (uint16_t*)alloc((size_t)MA*NNF_*256*2);
    uint16_t* dew1b = (uint16_t*)alloc((size_t)512*LAT*2);
    uint16_t* dew2b = (uint16_t*)alloc((size_t)MA*MA*NEF_*512*2);
    uint16_t* zkb   = (uint16_t*)alloc((size_t)NB*LAT*2);
    uint16_t* hnb   = (uint16_t*)alloc((size_t)NB*256*2);
    uint16_t* heb   = (uint16_t*)alloc((size_t)NB*512*2);
    float* edge_raw = (float*)t_pk;   // alias: trunk done before decoder uses it

    const int* esrc = eidx;
    const int* edst = eidx + N_EDGES;

    // weight conversions
    k_cvt_pack<<<(4*HIDDEN*HIDDEN+255)/256, 256, 0, stream>>>(conv_w1, cw1pk, 4*HIDDEN*HIDDEN);
    k_cvt_pack<<<(4*HIDDEN*HIDDEN+255)/256, 256, 0, stream>>>(conv_w2, cw2pk, 4*HIDDEN*HIDDEN);
    k_cvt_mv<<<(256*256+255)/256, 256, 0, stream>>>(mu_w, mu_b, lv_w, lv_b, mvwpk, mvb);
    k_cvt_fw1s<<<(NFLOWS*FHID*LAT+255)/256, 256, 0, stream>>>(fw1, w1hi, w1lo);
    k_cvt_fw2s<<<(NFLOWS*2*LAT*FHID+255)/256, 256, 0, stream>>>(fw2, w2hi, w2lo);
    k_cvt_b16<<<(256*LAT+255)/256, 256, 0, stream>>>(dn_w1, dnw1b, 256*LAT);
    k_cvt_b16<<<(MA*NNF_*256+255)/256, 256, 0, stream>>>(dn_w2, dnw2b, MA*NNF_*256);
    k_cvt_b16<<<(512*LAT+255)/256, 256, 0, stream>>>(de_w1, dew1b, 512*LAT);
    k_cvt_b16<<<(MA*MA*NEF_*512+255)/256, 256, 0, stream>>>(de_w2, dew2b, MA*MA*NEF_*512);

    k_init   <<<(N_NODES+255)/256, 256, 0, stream>>>(cursor, gstart, gcnt);
    k_embed  <<<N_NODES, HIDDEN, 0, stream>>>(x, node_emb, h_pk);
    k_deg    <<<(N_EDGES+255)/256, 256, 0, stream>>>(edst, cursor);
    k_meta   <<<(N_NODES+255)/256, 256, 0, stream>>>(batch, gstart, gcnt);
    k_scan   <<<1, 1024, 0, stream>>>(cursor, offs);
    k_scatter<<<(N_EDGES+255)/256, 256, 0, stream>>>(esrc, edst, eattr, offs, cursor, epack);

    const size_t SM = 65536;
    for (int k=0;k<4;k++){
        k_aggr<<<N_NODES, HIDDEN, 0, stream>>>(h_pk, edge_emb, offs, epack, t_pk);
        mfma_gemm<1,0><<<dim3(1, N_NODES/64), 256, SM, stream>>>(
            t_pk, cw1pk + (size_t)k*HIDDEN*HIDDEN, conv_b1 + (size_t)k*HIDDEN,
            t_pk, N_NODES, HIDDEN, HIDDEN, 1);
        mfma_gemm<1,0><<<dim3(1, N_NODES/64), 256, SM, stream>>>(
            t_pk, cw2pk + (size_t)k*HIDDEN*HIDDEN, conv_b2 + (size_t)k*HIDDEN,
            h_pk, N_NODES, HIDDEN, HIDDEN, 1);
    }

    k_pool<<<NB, HIDDEN, 0, stream>>>(h_pk, gstart, gcnt, hg_pk);
    mfma_gemm<1,2><<<dim3(1, NB/64), 256, SM, stream>>>(hg_pk, mvwpk, mvb, mv, NB, 256, HIDDEN, 0);
    k_z0<<<(NB*LAT+255)/256, 256, 0, stream>>>(mv, eps, out+off_mu, out+off_lv, out+off_z0);

    k_flows_mfma2<<<NB/FGPB, 256, 0, stream>>>(out+off_z0, w1hi, w1lo, fb1, w2hi, w2lo, fb2,
                                               out+off_zk, zkb, out+off_sld);

    // decoders (plain bf16 MFMA)
    mfma_gemm<0,1><<<dim3(1, NB/64), 256, SM, stream>>>(zkb, dnw1b, dn_b1, hnb, NB, 256, LAT, 1);
    mfma_gemm<0,2><<<dim3(6, NB/64), 256, SM, stream>>>(hnb, dnw2b, dn_b2, out+off_node, NB, MA*NNF_, 256, 0);
    mfma_gemm<0,1><<<dim3(2, NB/64), 256, SM, stream>>>(zkb, dew1b, de_b1, heb, NB, 512, LAT, 1);
    mfma_gemm<0,2><<<dim3(23, NB/64), 256, SM, stream>>>(heb, dew2b, de_b2, edge_raw, NB, MA*MA*NEF_, 512, 0);
    k_sym<<<(NB*MA*MA + 255)/256, 256, 0, stream>>>(edge_raw, out + off_edge);
}

// Round 5
// 820.430 us; speedup vs baseline: 1.6123x; 1.2855x over previous
//
#include <hip/hip_runtime.h>
#include <hip/hip_bf16.h>
#include <math.h>
#include <stdint.h>

#define N_NODES 49152
#define N_EDGES 196608
#define NB      2048
#define HIDDEN  256
#define LAT     128
#define FHID    256
#define NFLOWS  4
#define MA      38
#define NNF_    38
#define NEF_    4
#define FGPB    8

typedef __attribute__((ext_vector_type(8))) short bf16x8;
typedef __attribute__((ext_vector_type(4))) float f32x4;

// ---------- bf16 helpers ----------
__device__ inline uint32_t bf16_rne_bits(float v){
    uint32_t u = __float_as_uint(v);
    u += 0x7fffu + ((u >> 16) & 1u);
    return u & 0xffff0000u;
}
__device__ inline uint16_t to_b16(float v){ return (uint16_t)(bf16_rne_bits(v) >> 16); }
__device__ inline float from_b16(uint16_t u){ return __uint_as_float((uint32_t)u << 16); }
__device__ inline uint32_t pack_hl(float v){
    uint32_t hu = bf16_rne_bits(v);
    float r = v - __uint_as_float(hu);
    uint32_t lu = bf16_rne_bits(r);
    return hu | (lu >> 16);
}
__device__ inline float unpack_hl(uint32_t u){
    return __uint_as_float(u & 0xffff0000u) + __uint_as_float(u << 16);
}

__device__ inline void unpack_frag(const uint4& x, const uint4& y, bf16x8& hi, bf16x8& lo){
    union { bf16x8 v; uint32_t u[4]; } H, L;
    H.u[0] = __builtin_amdgcn_perm(x.y, x.x, 0x07060302u);
    H.u[1] = __builtin_amdgcn_perm(x.w, x.z, 0x07060302u);
    H.u[2] = __builtin_amdgcn_perm(y.y, y.x, 0x07060302u);
    H.u[3] = __builtin_amdgcn_perm(y.w, y.z, 0x07060302u);
    L.u[0] = __builtin_amdgcn_perm(x.y, x.x, 0x05040100u);
    L.u[1] = __builtin_amdgcn_perm(x.w, x.z, 0x05040100u);
    L.u[2] = __builtin_amdgcn_perm(y.y, y.x, 0x05040100u);
    L.u[3] = __builtin_amdgcn_perm(y.w, y.z, 0x05040100u);
    hi = H.v; lo = L.v;
}

// ---------------- init / CSR build ----------------

__global__ void k_init(int* __restrict__ cursor, int* __restrict__ gstart, int* __restrict__ gcnt){
    int i = blockIdx.x*256 + threadIdx.x;
    if (i < N_NODES) cursor[i] = 0;
    if (i < NB){ gstart[i] = 0x7fffffff; gcnt[i] = 0; }
}

__global__ void k_embed(const int* __restrict__ x, const float* __restrict__ emb, uint16_t* __restrict__ h){
    int i = blockIdx.x; int c = threadIdx.x;
    h[(size_t)i*HIDDEN + c] = to_b16(emb[x[i]*HIDDEN + c]);
}

__global__ void k_deg(const int* __restrict__ dst, int* __restrict__ cursor){
    int e = blockIdx.x*256 + threadIdx.x;
    if (e < N_EDGES) atomicAdd(&cursor[dst[e]], 1);
}

__global__ void k_meta(const int* __restrict__ batch, int* __restrict__ gstart, int* __restrict__ gcnt){
    int i = blockIdx.x*256 + threadIdx.x;
    if (i < N_NODES){ int b = batch[i]; atomicMin(&gstart[b], i); atomicAdd(&gcnt[b], 1); }
}

__global__ __launch_bounds__(1024) void k_scan(int* __restrict__ cursor, int* __restrict__ offs){
    __shared__ int part[1024];
    const int tid = threadIdx.x;
    const int CH = N_NODES/1024; // 48
    int local[48];
    int s = 0;
    int base = tid*CH;
    for (int j=0;j<CH;j++){ local[j] = cursor[base+j]; s += local[j]; }
    part[tid] = s;
    __syncthreads();
    for (int off=1; off<1024; off<<=1){
        int v = (tid>=off) ? part[tid-off] : 0;
        __syncthreads();
        part[tid] += v;
        __syncthreads();
    }
    int excl = (tid==0) ? 0 : part[tid-1];
    for (int j=0;j<CH;j++){ offs[base+j] = excl; excl += local[j]; cursor[base+j] = 0; }
    if (tid == 1023) offs[N_NODES] = excl;
}

__global__ void k_scatter(const int* __restrict__ src, const int* __restrict__ dst, const int* __restrict__ attr,
                          const int* __restrict__ offs, int* __restrict__ cursor, int* __restrict__ epack){
    int e = blockIdx.x*256 + threadIdx.x;
    if (e < N_EDGES){
        int d = dst[e];
        int pos = atomicAdd(&cursor[d], 1);
        epack[offs[d] + pos] = (src[e] & 0xffff) | (attr[e] << 16);
    }
}

// ---------------- message aggregation (bf16 activations) ----------------

__global__ void k_aggr(const uint16_t* __restrict__ h, const float* __restrict__ eemb,
                       const int* __restrict__ offs, const int* __restrict__ epack,
                       uint16_t* __restrict__ t){
    int i = blockIdx.x; int c = threadIdx.x;
    float s = from_b16(h[(size_t)i*HIDDEN + c]);
    int e0 = offs[i], e1 = offs[i+1];
    for (int j=e0;j<e1;j++){
        int p = epack[j];
        float v = from_b16(h[(size_t)(p & 0xffff)*HIDDEN + c]) + eemb[(p>>16)*HIDDEN + c];
        s += fmaxf(v, 0.f);
    }
    t[(size_t)i*HIDDEN + c] = to_b16(s);
}

// ---------------- weight / activation converters ----------------

__global__ void k_cvt_b16(const float* __restrict__ s, uint16_t* __restrict__ d, int n){
    int i = blockIdx.x*256 + threadIdx.x;
    if (i < n) d[i] = to_b16(s[i]);
}
// masked flow weights, separate hi/lo bf16 planes
__global__ void k_cvt_fw1s(const float* __restrict__ w, uint16_t* __restrict__ hi, uint16_t* __restrict__ lo){
    int i = blockIdx.x*256 + threadIdx.x;
    if (i >= NFLOWS*FHID*LAT) return;
    int o = (i >> 7) & 255;
    int kk = i & 127;
    float v = (kk <= (o % 127)) ? w[i] : 0.f;
    uint32_t h = bf16_rne_bits(v);
    hi[i] = (uint16_t)(h >> 16);
    lo[i] = (uint16_t)(bf16_rne_bits(v - __uint_as_float(h)) >> 16);
}
__global__ void k_cvt_fw2s(const float* __restrict__ w, uint16_t* __restrict__ hi, uint16_t* __restrict__ lo){
    int i = blockIdx.x*256 + threadIdx.x;
    if (i >= NFLOWS*2*LAT*FHID) return;
    int o = (i >> 8) & 255;
    int hh = i & 255;
    float v = ((hh % 127) < (o & 127)) ? w[i] : 0.f;
    uint32_t h = bf16_rne_bits(v);
    hi[i] = (uint16_t)(h >> 16);
    lo[i] = (uint16_t)(bf16_rne_bits(v - __uint_as_float(h)) >> 16);
}
// combined mu/lv weight [256][256] + bias [256] (packed split)
__global__ void k_cvt_mv(const float* __restrict__ mu_w, const float* __restrict__ mu_b,
                         const float* __restrict__ lv_w, const float* __restrict__ lv_b,
                         uint32_t* __restrict__ wpk, float* __restrict__ bpk){
    int i = blockIdx.x*256 + threadIdx.x;
    if (i < 256*256){
        int o = i >> 8, k2 = i & 255;
        float v = (o < 128) ? mu_w[o*256 + k2] : lv_w[(o-128)*256 + k2];
        wpk[i] = pack_hl(v);
    }
    if (i < 256) bpk[i] = (i < 128) ? mu_b[i] : lv_b[i-128];
}

// ---------------- MFMA GEMM:  C[M,N] = act(A[M,K] @ W[N,K]^T + bias) ----------------

template<int SPLIT, int OUTM>
__global__ __launch_bounds__(256) void mfma_gemm(
    const void* __restrict__ Ap, const void* __restrict__ Wp,
    const float* __restrict__ bias, void* __restrict__ Cp,
    int M, int N, int K, int relu)
{
    extern __shared__ __align__(16) char smem[];
    const int tid  = threadIdx.x;
    const int wave = tid >> 6;
    const int lane = tid & 63;
    const int l15  = lane & 15;
    const int lq   = lane >> 4;
    const int l7   = lane & 7;
    const int row0 = blockIdx.y * 64;
    const int n0   = blockIdx.x * 256;
    const int ELB  = SPLIT ? 4 : 2;
    const int KC   = (K < 256) ? K : 256;
    const int GR   = (KC * ELB) >> 4;
    const int rsh  = (GR == 64) ? 6 : ((GR == 32) ? 5 : 4);

    f32x4 acc[4][4];
    #pragma unroll
    for (int mt=0;mt<4;mt++)
        #pragma unroll
        for (int nt=0;nt<4;nt++) acc[mt][nt] = (f32x4)(0.f);

    const char* Ab = (const char*)Ap;
    const char* Wb = (const char*)Wp;

    for (int kbase = 0; kbase < K; kbase += KC) {
        const int rounds = GR >> 2;
        for (int it = 0; it < rounds; ++it) {
            int sbase = it*256 + wave*64;
            int s  = sbase + lane;
            int m  = s >> rsh;
            int gl = (s & (GR-1)) ^ (m & 7);
            const char* gp = Ab + ((size_t)(row0+m)*K + kbase)*ELB + gl*16;
            __builtin_amdgcn_global_load_lds(
                (const __attribute__((address_space(1))) uint32_t*)gp,
                (__attribute__((address_space(3))) uint32_t*)(smem + sbase*16),
                16, 0, 0);
        }
        __syncthreads();

        for (int kc = 0; kc < (KC >> 5); ++kc) {
            bf16x8 bhi[4], blo[4];
            #pragma unroll
            for (int nt=0;nt<4;nt++){
                int n = n0 + wave*64 + nt*16 + l15;
                if (n >= N) n = N-1;
                if (SPLIT){
                    const uint4* wp4 = (const uint4*)(Wb + ((size_t)n*K + kbase + kc*32 + lq*8)*4);
                    uint4 xx = wp4[0], yy = wp4[1];
                    unpack_frag(xx, yy, bhi[nt], blo[nt]);
                } else {
                    bhi[nt] = *(const bf16x8*)(Wb + ((size_t)n*K + kbase + kc*32 + lq*8)*2);
                }
            }
            #pragma unroll
            for (int mt=0;mt<4;mt++){
                const int mb = (mt*16 + l15) << rsh;
                if (SPLIT){
                    int g0 = kc*8 + lq*2;
                    uint4 xx = *(const uint4*)(smem + (size_t)(mb + ((g0  ) ^ l7))*16);
                    uint4 yy = *(const uint4*)(smem + (size_t)(mb + ((g0+1) ^ l7))*16);
                    bf16x8 ahi, alo;
                    unpack_frag(xx, yy, ahi, alo);
                    #pragma unroll
                    for (int nt=0;nt<4;nt++){
                        acc[mt][nt] = __builtin_amdgcn_mfma_f32_16x16x32_bf16(ahi, bhi[nt], acc[mt][nt], 0, 0, 0);
                        acc[mt][nt] = __builtin_amdgcn_mfma_f32_16x16x32_bf16(ahi, blo[nt], acc[mt][nt], 0, 0, 0);
                        acc[mt][nt] = __builtin_amdgcn_mfma_f32_16x16x32_bf16(alo, bhi[nt], acc[mt][nt], 0, 0, 0);
                    }
                } else {
                    int g = kc*4 + lq;
                    bf16x8 a = *(const bf16x8*)(smem + (size_t)(mb + (g ^ l7))*16);
                    #pragma unroll
                    for (int nt=0;nt<4;nt++){
                        acc[mt][nt] = __builtin_amdgcn_mfma_f32_16x16x32_bf16(a, bhi[nt], acc[mt][nt], 0, 0, 0);
                    }
                }
            }
        }
        __syncthreads();
    }

    char* rs = smem + wave*16384;
    const int colbase = n0 + wave*64;
    #pragma unroll
    for (int mt=0;mt<4;mt++){
        #pragma unroll
        for (int nt=0;nt<4;nt++){
            int cl = nt*16 + l15;
            int col = colbase + cl;
            float bb = bias[col < N ? col : N-1];
            #pragma unroll
            for (int reg=0;reg<4;reg++){
                int r = mt*16 + lq*4 + reg;
                float v = acc[mt][nt][reg] + bb;
                if (relu) v = fmaxf(v, 0.f);
                if (OUTM == 0) ((uint32_t*)rs)[r*64 + cl] = pack_hl(v);
                else           ((float*)rs)[r*64 + cl] = v;
            }
        }
    }
    __syncthreads();
    for (int it = 0; it < 32; ++it) {
        int r   = it*2 + (lane>>5);
        int clp = lane & 31;
        int col = colbase + clp*2;
        if (col < N){
            if (OUTM == 0){
                uint2 d = *(const uint2*)((const uint32_t*)rs + r*64 + clp*2);
                *(uint2*)((uint32_t*)Cp + (size_t)(row0+r)*N + col) = d;
            } else if (OUTM == 1){
                const float* f = (const float*)rs + r*64 + clp*2;
                uint32_t b0 = bf16_rne_bits(f[0]) >> 16;
                uint32_t b1 = bf16_rne_bits(f[1]) >> 16;
                *(uint32_t*)((char*)Cp + ((size_t)(row0+r)*N + col)*2) = b0 | (b1 << 16);
            } else {
                float2 d = *(const float2*)((const float*)rs + r*64 + clp*2);
                *(float2*)((float*)Cp + (size_t)(row0+r)*N + col) = d;
            }
        }
    }
}

// ---------------- pooling (bf16 in, packed split out) + z0 elementwise ----------------

__global__ void k_pool(const uint16_t* __restrict__ h, const int* __restrict__ gstart,
                       const int* __restrict__ gcnt, uint32_t* __restrict__ hg){
    int b = blockIdx.x; int c = threadIdx.x;
    int s0 = gstart[b]; int n = gcnt[b];
    float s = 0.f;
    for (int j=0;j<n;j++) s += from_b16(h[(size_t)(s0+j)*HIDDEN + c]);
    hg[(size_t)b*HIDDEN + c] = pack_hl(s);
}

__global__ void k_z0(const float* __restrict__ mv, const float* __restrict__ eps,
                     float* __restrict__ mu_o, float* __restrict__ lv_o, float* __restrict__ z0_o){
    int i = blockIdx.x*256 + threadIdx.x;
    if (i >= NB*LAT) return;
    int b = i >> 7, l = i & 127;
    float m = mv[(size_t)b*256 + l];
    float v = mv[(size_t)b*256 + l + 128];
    mu_o[i] = m;
    lv_o[i] = v;
    z0_o[i] = m + eps[i]*expf(0.5f*v);
}

// ---------------- fused MFMA flows v2 ----------------

__global__ __launch_bounds__(256) void k_flows_mfma2(
    const float* __restrict__ z0,
    const uint16_t* __restrict__ w1hi, const uint16_t* __restrict__ w1lo, const float* __restrict__ fb1,
    const uint16_t* __restrict__ w2hi, const uint16_t* __restrict__ w2lo, const float* __restrict__ fb2,
    float* __restrict__ zK, uint16_t* __restrict__ zkb, float* __restrict__ sld)
{
    __shared__ __align__(16) uint16_t zhi[16][136];
    __shared__ __align__(16) uint16_t zlo[16][136];
    __shared__ __align__(16) uint16_t h1hi[16][272];
    __shared__ __align__(16) uint16_t h1lo[16][272];
    __shared__ __align__(16) float    oS[16][264];
    const int tid  = threadIdx.x;
    const int wave = tid >> 6;
    const int lane = tid & 63;
    const int l15  = lane & 15;
    const int lq   = lane >> 4;
    const int g0   = blockIdx.x * FGPB;

    #pragma unroll
    for (int q=0;q<8;q++){
        int idx = q*256 + tid;
        int r = idx >> 7, l = idx & 127;
        float v = z0[(size_t)(g0 + (r & 7))*LAT + l];
        uint32_t h = bf16_rne_bits(v);
        zhi[r][l] = (uint16_t)(h >> 16);
        zlo[r][l] = (uint16_t)(bf16_rne_bits(v - __uint_as_float(h)) >> 16);
    }
    float ldacc = 0.f;
    __syncthreads();

    for (int kf=0; kf<NFLOWS; kf++){
        const uint16_t* W1h = w1hi + (size_t)kf*FHID*LAT;
        const uint16_t* W1l = w1lo + (size_t)kf*FHID*LAT;
        const float*    b1  = fb1 + kf*FHID;
        const uint16_t* W2h = w2hi + (size_t)kf*2*LAT*FHID;
        const uint16_t* W2l = w2lo + (size_t)kf*2*LAT*FHID;
        const float*    b2  = fb2 + kf*2*LAT;

        {
            f32x4 acc[4];
            #pragma unroll
            for (int nt=0;nt<4;nt++) acc[nt] = (f32x4)(0.f);
            bf16x8 bh[2][4], bl[2][4];
            #pragma unroll
            for (int nt=0;nt<4;nt++){
                size_t o = (size_t)(wave*64 + nt*16 + l15)*LAT + lq*8;
                bh[0][nt] = *(const bf16x8*)(W1h + o);
                bl[0][nt] = *(const bf16x8*)(W1l + o);
            }
            #pragma unroll
            for (int kc=0;kc<4;kc++){
                int cur = kc & 1, nxt = cur ^ 1;
                if (kc < 3){
                    #pragma unroll
                    for (int nt=0;nt<4;nt++){
                        size_t o = (size_t)(wave*64 + nt*16 + l15)*LAT + (kc+1)*32 + lq*8;
                        bh[nxt][nt] = *(const bf16x8*)(W1h + o);
                        bl[nxt][nt] = *(const bf16x8*)(W1l + o);
                    }
                }
                bf16x8 ah = *(const bf16x8*)&zhi[l15][kc*32 + lq*8];
                bf16x8 al = *(const bf16x8*)&zlo[l15][kc*32 + lq*8];
                #pragma unroll
                for (int nt=0;nt<4;nt++){
                    acc[nt] = __builtin_amdgcn_mfma_f32_16x16x32_bf16(ah, bh[cur][nt], acc[nt], 0, 0, 0);
                    acc[nt] = __builtin_amdgcn_mfma_f32_16x16x32_bf16(ah, bl[cur][nt], acc[nt], 0, 0, 0);
                    acc[nt] = __builtin_amdgcn_mfma_f32_16x16x32_bf16(al, bh[cur][nt], acc[nt], 0, 0, 0);
                }
            }
            #pragma unroll
            for (int nt=0;nt<4;nt++){
                int col = wave*64 + nt*16 + l15;
                float bb = b1[col];
                #pragma unroll
                for (int reg=0;reg<4;reg++){
                    int r = lq*4 + reg;
                    float v = fmaxf(acc[nt][reg] + bb, 0.f);
                    uint32_t h = bf16_rne_bits(v);
                    h1hi[r][col] = (uint16_t)(h >> 16);
                    h1lo[r][col] = (uint16_t)(bf16_rne_bits(v - __uint_as_float(h)) >> 16);
                }
            }
        }
        __syncthreads();

        {
            f32x4 acc[4];
            #pragma unroll
            for (int nt=0;nt<4;nt++) acc[nt] = (f32x4)(0.f);
            bf16x8 bh[2][4], bl[2][4];
            #pragma unroll
            for (int nt=0;nt<4;nt++){
                size_t o = (size_t)(wave*64 + nt*16 + l15)*FHID + lq*8;
                bh[0][nt] = *(const bf16x8*)(W2h + o);
                bl[0][nt] = *(const bf16x8*)(W2l + o);
            }
            #pragma unroll
            for (int kc=0;kc<8;kc++){
                int cur = kc & 1, nxt = cur ^ 1;
                if (kc < 7){
                    #pragma unroll
                    for (int nt=0;nt<4;nt++){
                        size_t o = (size_t)(wave*64 + nt*16 + l15)*FHID + (kc+1)*32 + lq*8;
                        bh[nxt][nt] = *(const bf16x8*)(W2h + o);
                        bl[nxt][nt] = *(const bf16x8*)(W2l + o);
                    }
                }
                bf16x8 ah = *(const bf16x8*)&h1hi[l15][kc*32 + lq*8];
                bf16x8 al = *(const bf16x8*)&h1lo[l15][kc*32 + lq*8];
                #pragma unroll
                for (int nt=0;nt<4;nt++){
                    acc[nt] = __builtin_amdgcn_mfma_f32_16x16x32_bf16(ah, bh[cur][nt], acc[nt], 0, 0, 0);
                    acc[nt] = __builtin_amdgcn_mfma_f32_16x16x32_bf16(ah, bl[cur][nt], acc[nt], 0, 0, 0);
                    acc[nt] = __builtin_amdgcn_mfma_f32_16x16x32_bf16(al, bh[cur][nt], acc[nt], 0, 0, 0);
                }
            }
            #pragma unroll
            for (int nt=0;nt<4;nt++){
                int col = wave*64 + nt*16 + l15;
                float bb = b2[col];
                #pragma unroll
                for (int reg=0;reg<4;reg++)
                    oS[lq*4 + reg][col] = acc[nt][reg] + bb;
            }
        }
        __syncthreads();

        {
            int r  = tid >> 5;
            int lc = tid & 31;
            float ldp = 0.f;
            #pragma unroll
            for (int j=0;j<4;j++){
                int l = lc + j*32;
                float m = oS[r][l];
                float s = oS[r][l + 128];
                float g = 1.f/(1.f + expf(-s));
                float zv = __uint_as_float((uint32_t)zhi[r][l] << 16)
                         + __uint_as_float((uint32_t)zlo[r][l] << 16);
                float zn = g*zv + (1.f - g)*m;
                uint32_t h = bf16_rne_bits(zn);
                uint16_t hb = (uint16_t)(h >> 16);
                uint16_t lb = (uint16_t)(bf16_rne_bits(zn - __uint_as_float(h)) >> 16);
                zhi[r][l] = hb; zlo[r][l] = lb;
                zhi[r+8][l] = hb; zlo[r+8][l] = lb;
                ldp += logf(g + 1e-8f);
            }
            ldp += __shfl_xor(ldp, 1, 32);
            ldp += __shfl_xor(ldp, 2, 32);
            ldp += __shfl_xor(ldp, 4, 32);
            ldp += __shfl_xor(ldp, 8, 32);
            ldp += __shfl_xor(ldp, 16, 32);
            ldacc += ldp;
        }
        __syncthreads();
    }

    #pragma unroll
    for (int q=0;q<4;q++){
        int idx = q*256 + tid;
        int r = idx >> 7, l = idx & 127;
        uint32_t h = (uint32_t)zhi[r][l] << 16;
        float zv = __uint_as_float(h) + __uint_as_float((uint32_t)zlo[r][l] << 16);
        zK[(size_t)(g0+r)*LAT + l] = zv;
        zkb[(size_t)(g0+r)*LAT + l] = (uint16_t)(h >> 16);
    }
    if ((tid & 31) == 0)
        sld[g0 + (tid >> 5)] = ldacc;
}

// ---------------- edge-logits symmetrize ----------------

__global__ void k_sym(const float* __restrict__ raw, float* __restrict__ outp){
    int idx = blockIdx.x*256 + threadIdx.x;
    const int total = NB*MA*MA;
    if (idx >= total) return;
    int b = idx / (MA*MA);
    int rem = idx - b*(MA*MA);
    int i = rem / MA;
    int j = rem - i*MA;
    const size_t base = (size_t)b*(MA*MA*NEF_);
    const float4 a  = *(const float4*)(raw + base + (size_t)(i*MA + j)*NEF_);
    const float4 bt = *(const float4*)(raw + base + (size_t)(j*MA + i)*NEF_);
    float4 r;
    r.x = (a.x + bt.x)*0.5f;
    r.y = (a.y + bt.y)*0.5f;
    r.z = (a.z + bt.z)*0.5f;
    r.w = (a.w + bt.w)*0.5f;
    *(float4*)(outp + base + (size_t)(i*MA + j)*NEF_) = r;
}

// ---------------- launch ----------------

extern "C" void kernel_launch(void* const* d_in, const int* in_sizes, int n_in,
                              void* d_out, int out_size, void* d_ws, size_t ws_size,
                              hipStream_t stream){
    (void)in_sizes; (void)n_in; (void)out_size; (void)ws_size;
    const int*   x        = (const int*)d_in[0];
    const int*   eidx     = (const int*)d_in[1];
    const int*   eattr    = (const int*)d_in[2];
    const int*   batch    = (const int*)d_in[3];
    const float* eps      = (const float*)d_in[4];
    const float* node_emb = (const float*)d_in[5];
    const float* edge_emb = (const float*)d_in[6];
    const float* conv_w1  = (const float*)d_in[7];
    const float* conv_b1  = (const float*)d_in[8];
    const float* conv_w2  = (const float*)d_in[9];
    const float* conv_b2  = (const float*)d_in[10];
    const float* mu_w     = (const float*)d_in[11];
    const float* mu_b     = (const float*)d_in[12];
    const float* lv_w     = (const float*)d_in[13];
    const float* lv_b     = (const float*)d_in[14];
    const float* fw1      = (const float*)d_in[15];
    const float* fb1      = (const float*)d_in[16];
    const float* fw2      = (const float*)d_in[17];
    const float* fb2      = (const float*)d_in[18];
    const float* dn_w1    = (const float*)d_in[19];
    const float* dn_b1    = (const float*)d_in[20];
    const float* dn_w2    = (const float*)d_in[21];
    const float* dn_b2    = (const float*)d_in[22];
    const float* de_w1    = (const float*)d_in[23];
    const float* de_b1    = (const float*)d_in[24];
    const float* de_w2    = (const float*)d_in[25];
    const float* de_b2    = (const float*)d_in[26];

    float* out = (float*)d_out;
    const size_t off_node = 0;
    const size_t off_edge = (size_t)NB*MA*NNF_;
    const size_t off_mu   = off_edge + (size_t)NB*MA*MA*NEF_;
    const size_t off_lv   = off_mu + (size_t)NB*LAT;
    const size_t off_z0   = off_lv + (size_t)NB*LAT;
    const size_t off_zk   = off_z0 + (size_t)NB*LAT;
    const size_t off_sld  = off_zk + (size_t)NB*LAT;

    char* p = (char*)d_ws;
    auto alloc = [&](size_t bytes)->char*{ char* r = p; p += (bytes + 255) & ~(size_t)255; return r; };
    uint16_t* h_b   = (uint16_t*)alloc((size_t)N_NODES*HIDDEN*2);
    uint16_t* t_b   = (uint16_t*)alloc((size_t)N_NODES*HIDDEN*2);
    int*   offs   = (int*)  alloc((size_t)(N_NODES+1)*4);
    int*   cursor = (int*)  alloc((size_t)N_NODES*4);
    int*   epack  = (int*)  alloc((size_t)N_EDGES*4);
    int*   gstart = (int*)  alloc((size_t)NB*4);
    int*   gcnt   = (int*)  alloc((size_t)NB*4);
    uint32_t* hg_pk = (uint32_t*)alloc((size_t)NB*HIDDEN*4);
    float* mv       = (float*)alloc((size_t)NB*256*4);
    uint16_t* cw1b  = (uint16_t*)alloc((size_t)4*HIDDEN*HIDDEN*2);
    uint16_t* cw2b  = (uint16_t*)alloc((size_t)4*HIDDEN*HIDDEN*2);
    uint32_t* mvwpk = (uint32_t*)alloc((size_t)256*256*4);
    float*    mvb   = (float*)  alloc((size_t)256*4);
    uint16_t* w1hi  = (uint16_t*)alloc((size_t)NFLOWS*FHID*LAT*2);
    uint16_t* w1lo  = (uint16_t*)alloc((size_t)NFLOWS*FHID*LAT*2);
    uint16_t* w2hi  = (uint16_t*)alloc((size_t)NFLOWS*2*LAT*FHID*2);
    uint16_t* w2lo  = (uint16_t*)alloc((size_t)NFLOWS*2*LAT*FHID*2);
    uint16_t* dnw1b = (uint16_t*)alloc((size_t)256*LAT*2);
    uint16_t* dnw2b = (uint16_t*)alloc((size_t)MA*NNF_*256*2);
    uint16_t* dew1b = (uint16_t*)alloc((size_t)512*LAT*2);
    uint16_t* dew2b = (uint16_t*)alloc((size_t)MA*MA*NEF_*512*2);
    uint16_t* zkb   = (uint16_t*)alloc((size_t)NB*LAT*2);
    uint16_t* hnb   = (uint16_t*)alloc((size_t)NB*256*2);
    uint16_t* heb   = (uint16_t*)alloc((size_t)NB*512*2);
    float* edge_raw = (float*)alloc((size_t)NB*MA*MA*NEF_*4);

    const int* esrc = eidx;
    const int* edst = eidx + N_EDGES;

    // weight conversions
    k_cvt_b16<<<(4*HIDDEN*HIDDEN+255)/256, 256, 0, stream>>>(conv_w1, cw1b, 4*HIDDEN*HIDDEN);
    k_cvt_b16<<<(4*HIDDEN*HIDDEN+255)/256, 256, 0, stream>>>(conv_w2, cw2b, 4*HIDDEN*HIDDEN);
    k_cvt_mv<<<(256*256+255)/256, 256, 0, stream>>>(mu_w, mu_b, lv_w, lv_b, mvwpk, mvb);
    k_cvt_fw1s<<<(NFLOWS*FHID*LAT+255)/256, 256, 0, stream>>>(fw1, w1hi, w1lo);
    k_cvt_fw2s<<<(NFLOWS*2*LAT*FHID+255)/256, 256, 0, stream>>>(fw2, w2hi, w2lo);
    k_cvt_b16<<<(256*LAT+255)/256, 256, 0, stream>>>(dn_w1, dnw1b, 256*LAT);
    k_cvt_b16<<<(MA*NNF_*256+255)/256, 256, 0, stream>>>(dn_w2, dnw2b, MA*NNF_*256);
    k_cvt_b16<<<(512*LAT+255)/256, 256, 0, stream>>>(de_w1, dew1b, 512*LAT);
    k_cvt_b16<<<(MA*MA*NEF_*512+255)/256, 256, 0, stream>>>(de_w2, dew2b, MA*MA*NEF_*512);

    k_init   <<<(N_NODES+255)/256, 256, 0, stream>>>(cursor, gstart, gcnt);
    k_embed  <<<N_NODES, HIDDEN, 0, stream>>>(x, node_emb, h_b);
    k_deg    <<<(N_EDGES+255)/256, 256, 0, stream>>>(edst, cursor);
    k_meta   <<<(N_NODES+255)/256, 256, 0, stream>>>(batch, gstart, gcnt);
    k_scan   <<<1, 1024, 0, stream>>>(cursor, offs);
    k_scatter<<<(N_EDGES+255)/256, 256, 0, stream>>>(esrc, edst, eattr, offs, cursor, epack);

    const size_t SM = 65536;
    for (int k=0;k<4;k++){
        k_aggr<<<N_NODES, HIDDEN, 0, stream>>>(h_b, edge_emb, offs, epack, t_b);
        mfma_gemm<0,1><<<dim3(1, N_NODES/64), 256, SM, stream>>>(
            t_b, cw1b + (size_t)k*HIDDEN*HIDDEN, conv_b1 + (size_t)k*HIDDEN,
            t_b, N_NODES, HIDDEN, HIDDEN, 1);
        mfma_gemm<0,1><<<dim3(1, N_NODES/64), 256, SM, stream>>>(
            t_b, cw2b + (size_t)k*HIDDEN*HIDDEN, conv_b2 + (size_t)k*HIDDEN,
            h_b, N_NODES, HIDDEN, HIDDEN, 1);
    }

    k_pool<<<NB, HIDDEN, 0, stream>>>(h_b, gstart, gcnt, hg_pk);
    mfma_gemm<1,2><<<dim3(1, NB/64), 256, SM, stream>>>(hg_pk, mvwpk, mvb, mv, NB, 256, HIDDEN, 0);
    k_z0<<<(NB*LAT+255)/256, 256, 0, stream>>>(mv, eps, out+off_mu, out+off_lv, out+off_z0);

    k_flows_mfma2<<<NB/FGPB, 256, 0, stream>>>(out+off_z0, w1hi, w1lo, fb1, w2hi, w2lo, fb2,
                                               out+off_zk, zkb, out+off_sld);

    // decoders (plain bf16 MFMA)
    mfma_gemm<0,1><<<dim3(1, NB/64), 256, SM, stream>>>(zkb, dnw1b, dn_b1, hnb, NB, 256, LAT, 1);
    mfma_gemm<0,2><<<dim3(6, NB/64), 256, SM, stream>>>(hnb, dnw2b, dn_b2, out+off_node, NB, MA*NNF_, 256, 0);
    mfma_gemm<0,1><<<dim3(2, NB/64), 256, SM, stream>>>(zkb, dew1b, de_b1, heb, NB, 512, LAT, 1);
    mfma_gemm<0,2><<<dim3(23, NB/64), 256, SM, stream>>>(heb, dew2b, de_b2, edge_raw, NB, MA*MA*NEF_, 512, 0);
    k_sym<<<(NB*MA*MA + 255)/256, 256, 0, stream>>>(edge_raw, out + off_edge);
}

// Round 6
// 663.866 us; speedup vs baseline: 1.9925x; 1.2358x over previous
//
#include <hip/hip_runtime.h>
#include <hip/hip_bf16.h>
#include <math.h>
#include <stdint.h>

#define N_NODES 49152
#define N_EDGES 196608
#define NB      2048
#define HIDDEN  256
#define LAT     128
#define FHID    256
#define NFLOWS  4
#define MA      38
#define NNF_    38
#define NEF_    4
#define FGPB    8

typedef __attribute__((ext_vector_type(8))) short bf16x8;
typedef __attribute__((ext_vector_type(4))) float f32x4;

// ---------- bf16 helpers ----------
__device__ inline uint32_t bf16_rne_bits(float v){
    uint32_t u = __float_as_uint(v);
    u += 0x7fffu + ((u >> 16) & 1u);
    return u & 0xffff0000u;
}
__device__ inline uint16_t to_b16(float v){ return (uint16_t)(bf16_rne_bits(v) >> 16); }
__device__ inline float from_b16(uint16_t u){ return __uint_as_float((uint32_t)u << 16); }
__device__ inline uint32_t pack_hl(float v){
    uint32_t hu = bf16_rne_bits(v);
    float r = v - __uint_as_float(hu);
    uint32_t lu = bf16_rne_bits(r);
    return hu | (lu >> 16);
}

__device__ inline void unpack_frag(const uint4& x, const uint4& y, bf16x8& hi, bf16x8& lo){
    union { bf16x8 v; uint32_t u[4]; } H, L;
    H.u[0] = __builtin_amdgcn_perm(x.y, x.x, 0x07060302u);
    H.u[1] = __builtin_amdgcn_perm(x.w, x.z, 0x07060302u);
    H.u[2] = __builtin_amdgcn_perm(y.y, y.x, 0x07060302u);
    H.u[3] = __builtin_amdgcn_perm(y.w, y.z, 0x07060302u);
    L.u[0] = __builtin_amdgcn_perm(x.y, x.x, 0x05040100u);
    L.u[1] = __builtin_amdgcn_perm(x.w, x.z, 0x05040100u);
    L.u[2] = __builtin_amdgcn_perm(y.y, y.x, 0x05040100u);
    L.u[3] = __builtin_amdgcn_perm(y.w, y.z, 0x05040100u);
    hi = H.v; lo = L.v;
}

// ---------------- init / CSR build ----------------

__global__ void k_init(int* __restrict__ cursor, int* __restrict__ gstart, int* __restrict__ gcnt){
    int i = blockIdx.x*256 + threadIdx.x;
    if (i < N_NODES) cursor[i] = 0;
    if (i < NB){ gstart[i] = 0x7fffffff; gcnt[i] = 0; }
}

__global__ void k_embed(const int* __restrict__ x, const float* __restrict__ emb, uint16_t* __restrict__ h){
    int i = blockIdx.x; int c = threadIdx.x;
    h[(size_t)i*HIDDEN + c] = to_b16(emb[x[i]*HIDDEN + c]);
}

__global__ void k_deg(const int* __restrict__ dst, int* __restrict__ cursor){
    int e = blockIdx.x*256 + threadIdx.x;
    if (e < N_EDGES) atomicAdd(&cursor[dst[e]], 1);
}

__global__ void k_meta(const int* __restrict__ batch, int* __restrict__ gstart, int* __restrict__ gcnt){
    int i = blockIdx.x*256 + threadIdx.x;
    if (i < N_NODES){ int b = batch[i]; atomicMin(&gstart[b], i); atomicAdd(&gcnt[b], 1); }
}

__global__ __launch_bounds__(1024) void k_scan(int* __restrict__ cursor, int* __restrict__ offs){
    __shared__ int part[1024];
    const int tid = threadIdx.x;
    const int CH = N_NODES/1024; // 48
    int local[48];
    int s = 0;
    int base = tid*CH;
    for (int j=0;j<CH;j++){ local[j] = cursor[base+j]; s += local[j]; }
    part[tid] = s;
    __syncthreads();
    for (int off=1; off<1024; off<<=1){
        int v = (tid>=off) ? part[tid-off] : 0;
        __syncthreads();
        part[tid] += v;
        __syncthreads();
    }
    int excl = (tid==0) ? 0 : part[tid-1];
    for (int j=0;j<CH;j++){ offs[base+j] = excl; excl += local[j]; cursor[base+j] = 0; }
    if (tid == 1023) offs[N_NODES] = excl;
}

__global__ void k_scatter(const int* __restrict__ src, const int* __restrict__ dst, const int* __restrict__ attr,
                          const int* __restrict__ offs, int* __restrict__ cursor, int* __restrict__ epack){
    int e = blockIdx.x*256 + threadIdx.x;
    if (e < N_EDGES){
        int d = dst[e];
        int pos = atomicAdd(&cursor[d], 1);
        epack[offs[d] + pos] = (src[e] & 0xffff) | (attr[e] << 16);
    }
}

// ---------------- message aggregation: wave-per-node, 4-edge MLP chunks ----------------
// lane l handles cols [4l, 4l+4); one dwordx2 gather covers the whole 512B row per wave.

__global__ __launch_bounds__(256) void k_aggr(const uint16_t* __restrict__ h, const float* __restrict__ eemb,
                                              const int* __restrict__ offs, const int* __restrict__ epack,
                                              uint16_t* __restrict__ t){
    __shared__ float sE[NEF_*HIDDEN];
    const int tid  = threadIdx.x;
    #pragma unroll
    for (int q=0;q<NEF_;q++) sE[q*256 + tid] = eemb[q*256 + tid];
    __syncthreads();

    const int wave = tid >> 6;
    const int lane = tid & 63;
    const int node = blockIdx.x*4 + wave;
    const int c4   = lane*4;

    uint2 hu = *(const uint2*)(h + (size_t)node*HIDDEN + c4);
    float4 acc;
    acc.x = __uint_as_float(hu.x << 16);
    acc.y = __uint_as_float(hu.x & 0xffff0000u);
    acc.z = __uint_as_float(hu.y << 16);
    acc.w = __uint_as_float(hu.y & 0xffff0000u);

    const int e0 = offs[node], e1 = offs[node+1];
    for (int j = e0; j < e1; j += 4){
        int p0 = epack[j];
        int p1 = (j+1 < e1) ? epack[j+1] : p0;
        int p2 = (j+2 < e1) ? epack[j+2] : p0;
        int p3 = (j+3 < e1) ? epack[j+3] : p0;
        uint2 g0 = *(const uint2*)(h + (size_t)(p0 & 0xffff)*HIDDEN + c4);
        uint2 g1 = *(const uint2*)(h + (size_t)(p1 & 0xffff)*HIDDEN + c4);
        uint2 g2 = *(const uint2*)(h + (size_t)(p2 & 0xffff)*HIDDEN + c4);
        uint2 g3 = *(const uint2*)(h + (size_t)(p3 & 0xffff)*HIDDEN + c4);
        {
            const float4 ev = *(const float4*)&sE[(p0 >> 16)*HIDDEN + c4];
            acc.x += fmaxf(__uint_as_float(g0.x << 16)        + ev.x, 0.f);
            acc.y += fmaxf(__uint_as_float(g0.x & 0xffff0000u) + ev.y, 0.f);
            acc.z += fmaxf(__uint_as_float(g0.y << 16)        + ev.z, 0.f);
            acc.w += fmaxf(__uint_as_float(g0.y & 0xffff0000u) + ev.w, 0.f);
        }
        if (j+1 < e1){
            const float4 ev = *(const float4*)&sE[(p1 >> 16)*HIDDEN + c4];
            acc.x += fmaxf(__uint_as_float(g1.x << 16)        + ev.x, 0.f);
            acc.y += fmaxf(__uint_as_float(g1.x & 0xffff0000u) + ev.y, 0.f);
            acc.z += fmaxf(__uint_as_float(g1.y << 16)        + ev.z, 0.f);
            acc.w += fmaxf(__uint_as_float(g1.y & 0xffff0000u) + ev.w, 0.f);
        }
        if (j+2 < e1){
            const float4 ev = *(const float4*)&sE[(p2 >> 16)*HIDDEN + c4];
            acc.x += fmaxf(__uint_as_float(g2.x << 16)        + ev.x, 0.f);
            acc.y += fmaxf(__uint_as_float(g2.x & 0xffff0000u) + ev.y, 0.f);
            acc.z += fmaxf(__uint_as_float(g2.y << 16)        + ev.z, 0.f);
            acc.w += fmaxf(__uint_as_float(g2.y & 0xffff0000u) + ev.w, 0.f);
        }
        if (j+3 < e1){
            const float4 ev = *(const float4*)&sE[(p3 >> 16)*HIDDEN + c4];
            acc.x += fmaxf(__uint_as_float(g3.x << 16)        + ev.x, 0.f);
            acc.y += fmaxf(__uint_as_float(g3.x & 0xffff0000u) + ev.y, 0.f);
            acc.z += fmaxf(__uint_as_float(g3.y << 16)        + ev.z, 0.f);
            acc.w += fmaxf(__uint_as_float(g3.y & 0xffff0000u) + ev.w, 0.f);
        }
    }

    uint2 o;
    o.x = (uint32_t)to_b16(acc.x) | ((uint32_t)to_b16(acc.y) << 16);
    o.y = (uint32_t)to_b16(acc.z) | ((uint32_t)to_b16(acc.w) << 16);
    *(uint2*)(t + (size_t)node*HIDDEN + c4) = o;
}

// ---------------- weight / activation converters ----------------

__global__ void k_cvt_b16(const float* __restrict__ s, uint16_t* __restrict__ d, int n){
    int i = blockIdx.x*256 + threadIdx.x;
    if (i < n) d[i] = to_b16(s[i]);
}
__global__ void k_cvt_fw1s(const float* __restrict__ w, uint16_t* __restrict__ hi, uint16_t* __restrict__ lo){
    int i = blockIdx.x*256 + threadIdx.x;
    if (i >= NFLOWS*FHID*LAT) return;
    int o = (i >> 7) & 255;
    int kk = i & 127;
    float v = (kk <= (o % 127)) ? w[i] : 0.f;
    uint32_t h = bf16_rne_bits(v);
    hi[i] = (uint16_t)(h >> 16);
    lo[i] = (uint16_t)(bf16_rne_bits(v - __uint_as_float(h)) >> 16);
}
__global__ void k_cvt_fw2s(const float* __restrict__ w, uint16_t* __restrict__ hi, uint16_t* __restrict__ lo){
    int i = blockIdx.x*256 + threadIdx.x;
    if (i >= NFLOWS*2*LAT*FHID) return;
    int o = (i >> 8) & 255;
    int hh = i & 255;
    float v = ((hh % 127) < (o & 127)) ? w[i] : 0.f;
    uint32_t h = bf16_rne_bits(v);
    hi[i] = (uint16_t)(h >> 16);
    lo[i] = (uint16_t)(bf16_rne_bits(v - __uint_as_float(h)) >> 16);
}
__global__ void k_cvt_mv(const float* __restrict__ mu_w, const float* __restrict__ mu_b,
                         const float* __restrict__ lv_w, const float* __restrict__ lv_b,
                         uint32_t* __restrict__ wpk, float* __restrict__ bpk){
    int i = blockIdx.x*256 + threadIdx.x;
    if (i < 256*256){
        int o = i >> 8, k2 = i & 255;
        float v = (o < 128) ? mu_w[o*256 + k2] : lv_w[(o-128)*256 + k2];
        wpk[i] = pack_hl(v);
    }
    if (i < 256) bpk[i] = (i < 128) ? mu_b[i] : lv_b[i-128];
}

// ---------------- MFMA GEMM:  C[M,N] = act(A[M,K] @ W[N,K]^T + bias) ----------------
// OUTM: 1 = bf16 out (bf16 epilogue LDS, 2B/elem), 2 = fp32 out (4B/elem).

template<int SPLIT, int OUTM>
__global__ __launch_bounds__(256) void mfma_gemm(
    const void* __restrict__ Ap, const void* __restrict__ Wp,
    const float* __restrict__ bias, void* __restrict__ Cp,
    int M, int N, int K, int relu)
{
    extern __shared__ __align__(16) char smem[];
    const int tid  = threadIdx.x;
    const int wave = tid >> 6;
    const int lane = tid & 63;
    const int l15  = lane & 15;
    const int lq   = lane >> 4;
    const int l7   = lane & 7;
    const int row0 = blockIdx.y * 64;
    const int n0   = blockIdx.x * 256;
    const int ELB  = SPLIT ? 4 : 2;
    const int KC   = (K < 256) ? K : 256;
    const int GR   = (KC * ELB) >> 4;
    const int rsh  = (GR == 64) ? 6 : ((GR == 32) ? 5 : 4);

    f32x4 acc[4][4];
    #pragma unroll
    for (int mt=0;mt<4;mt++)
        #pragma unroll
        for (int nt=0;nt<4;nt++) acc[mt][nt] = (f32x4)(0.f);

    const char* Ab = (const char*)Ap;
    const char* Wb = (const char*)Wp;

    for (int kbase = 0; kbase < K; kbase += KC) {
        const int rounds = GR >> 2;
        for (int it = 0; it < rounds; ++it) {
            int sbase = it*256 + wave*64;
            int s  = sbase + lane;
            int m  = s >> rsh;
            int gl = (s & (GR-1)) ^ (m & 7);
            const char* gp = Ab + ((size_t)(row0+m)*K + kbase)*ELB + gl*16;
            __builtin_amdgcn_global_load_lds(
                (const __attribute__((address_space(1))) uint32_t*)gp,
                (__attribute__((address_space(3))) uint32_t*)(smem + sbase*16),
                16, 0, 0);
        }
        __syncthreads();

        for (int kc = 0; kc < (KC >> 5); ++kc) {
            bf16x8 bhi[4], blo[4];
            #pragma unroll
            for (int nt=0;nt<4;nt++){
                int n = n0 + wave*64 + nt*16 + l15;
                if (n >= N) n = N-1;
                if (SPLIT){
                    const uint4* wp4 = (const uint4*)(Wb + ((size_t)n*K + kbase + kc*32 + lq*8)*4);
                    uint4 xx = wp4[0], yy = wp4[1];
                    unpack_frag(xx, yy, bhi[nt], blo[nt]);
                } else {
                    bhi[nt] = *(const bf16x8*)(Wb + ((size_t)n*K + kbase + kc*32 + lq*8)*2);
                }
            }
            #pragma unroll
            for (int mt=0;mt<4;mt++){
                const int mb = (mt*16 + l15) << rsh;
                if (SPLIT){
                    int g0 = kc*8 + lq*2;
                    uint4 xx = *(const uint4*)(smem + (size_t)(mb + ((g0  ) ^ l7))*16);
                    uint4 yy = *(const uint4*)(smem + (size_t)(mb + ((g0+1) ^ l7))*16);
                    bf16x8 ahi, alo;
                    unpack_frag(xx, yy, ahi, alo);
                    #pragma unroll
                    for (int nt=0;nt<4;nt++){
                        acc[mt][nt] = __builtin_amdgcn_mfma_f32_16x16x32_bf16(ahi, bhi[nt], acc[mt][nt], 0, 0, 0);
                        acc[mt][nt] = __builtin_amdgcn_mfma_f32_16x16x32_bf16(ahi, blo[nt], acc[mt][nt], 0, 0, 0);
                        acc[mt][nt] = __builtin_amdgcn_mfma_f32_16x16x32_bf16(alo, bhi[nt], acc[mt][nt], 0, 0, 0);
                    }
                } else {
                    int g = kc*4 + lq;
                    bf16x8 a = *(const bf16x8*)(smem + (size_t)(mb + (g ^ l7))*16);
                    #pragma unroll
                    for (int nt=0;nt<4;nt++){
                        acc[mt][nt] = __builtin_amdgcn_mfma_f32_16x16x32_bf16(a, bhi[nt], acc[mt][nt], 0, 0, 0);
                    }
                }
            }
        }
        __syncthreads();
    }

    const int ES = (OUTM == 1) ? 2 : 4;
    char* rs = smem + wave*(64*64*ES);
    const int colbase = n0 + wave*64;
    #pragma unroll
    for (int mt=0;mt<4;mt++){
        #pragma unroll
        for (int nt=0;nt<4;nt++){
            int cl = nt*16 + l15;
            int col = colbase + cl;
            float bb = bias[col < N ? col : N-1];
            #pragma unroll
            for (int reg=0;reg<4;reg++){
                int r = mt*16 + lq*4 + reg;
                float v = acc[mt][nt][reg] + bb;
                if (relu) v = fmaxf(v, 0.f);
                if (OUTM == 1) ((uint16_t*)rs)[r*64 + cl] = to_b16(v);
                else           ((float*)rs)[r*64 + cl] = v;
            }
        }
    }
    __syncthreads();
    for (int it = 0; it < 32; ++it) {
        int r   = it*2 + (lane>>5);
        int clp = lane & 31;
        int col = colbase + clp*2;
        if (col < N){
            if (OUTM == 1){
                uint32_t d = *(const uint32_t*)((const uint16_t*)rs + r*64 + clp*2);
                *(uint32_t*)((char*)Cp + ((size_t)(row0+r)*N + col)*2) = d;
            } else {
                float2 d = *(const float2*)((const float*)rs + r*64 + clp*2);
                *(float2*)((float*)Cp + (size_t)(row0+r)*N + col) = d;
            }
        }
    }
}

// ---------------- pooling (bf16 in, packed split out) + z0 elementwise ----------------

__global__ void k_pool(const uint16_t* __restrict__ h, const int* __restrict__ gstart,
                       const int* __restrict__ gcnt, uint32_t* __restrict__ hg){
    int b = blockIdx.x; int c = threadIdx.x;
    int s0 = gstart[b]; int n = gcnt[b];
    float s = 0.f;
    for (int j=0;j<n;j++) s += from_b16(h[(size_t)(s0+j)*HIDDEN + c]);
    hg[(size_t)b*HIDDEN + c] = pack_hl(s);
}

__global__ void k_z0(const float* __restrict__ mv, const float* __restrict__ eps,
                     float* __restrict__ mu_o, float* __restrict__ lv_o, float* __restrict__ z0_o){
    int i = blockIdx.x*256 + threadIdx.x;
    if (i >= NB*LAT) return;
    int b = i >> 7, l = i & 127;
    float m = mv[(size_t)b*256 + l];
    float v = mv[(size_t)b*256 + l + 128];
    mu_o[i] = m;
    lv_o[i] = v;
    z0_o[i] = m + eps[i]*expf(0.5f*v);
}

// ---------------- fused MFMA flows v2 ----------------

__global__ __launch_bounds__(256) void k_flows_mfma2(
    const float* __restrict__ z0,
    const uint16_t* __restrict__ w1hi, const uint16_t* __restrict__ w1lo, const float* __restrict__ fb1,
    const uint16_t* __restrict__ w2hi, const uint16_t* __restrict__ w2lo, const float* __restrict__ fb2,
    float* __restrict__ zK, uint16_t* __restrict__ zkb, float* __restrict__ sld)
{
    __shared__ __align__(16) uint16_t zhi[16][136];
    __shared__ __align__(16) uint16_t zlo[16][136];
    __shared__ __align__(16) uint16_t h1hi[16][272];
    __shared__ __align__(16) uint16_t h1lo[16][272];
    __shared__ __align__(16) float    oS[16][264];
    const int tid  = threadIdx.x;
    const int wave = tid >> 6;
    const int lane = tid & 63;
    const int l15  = lane & 15;
    const int lq   = lane >> 4;
    const int g0   = blockIdx.x * FGPB;

    #pragma unroll
    for (int q=0;q<8;q++){
        int idx = q*256 + tid;
        int r = idx >> 7, l = idx & 127;
        float v = z0[(size_t)(g0 + (r & 7))*LAT + l];
        uint32_t h = bf16_rne_bits(v);
        zhi[r][l] = (uint16_t)(h >> 16);
        zlo[r][l] = (uint16_t)(bf16_rne_bits(v - __uint_as_float(h)) >> 16);
    }
    float ldacc = 0.f;
    __syncthreads();

    for (int kf=0; kf<NFLOWS; kf++){
        const uint16_t* W1h = w1hi + (size_t)kf*FHID*LAT;
        const uint16_t* W1l = w1lo + (size_t)kf*FHID*LAT;
        const float*    b1  = fb1 + kf*FHID;
        const uint16_t* W2h = w2hi + (size_t)kf*2*LAT*FHID;
        const uint16_t* W2l = w2lo + (size_t)kf*2*LAT*FHID;
        const float*    b2  = fb2 + kf*2*LAT;

        {
            f32x4 acc[4];
            #pragma unroll
            for (int nt=0;nt<4;nt++) acc[nt] = (f32x4)(0.f);
            bf16x8 bh[2][4], bl[2][4];
            #pragma unroll
            for (int nt=0;nt<4;nt++){
                size_t o = (size_t)(wave*64 + nt*16 + l15)*LAT + lq*8;
                bh[0][nt] = *(const bf16x8*)(W1h + o);
                bl[0][nt] = *(const bf16x8*)(W1l + o);
            }
            #pragma unroll
            for (int kc=0;kc<4;kc++){
                int cur = kc & 1, nxt = cur ^ 1;
                if (kc < 3){
                    #pragma unroll
                    for (int nt=0;nt<4;nt++){
                        size_t o = (size_t)(wave*64 + nt*16 + l15)*LAT + (kc+1)*32 + lq*8;
                        bh[nxt][nt] = *(const bf16x8*)(W1h + o);
                        bl[nxt][nt] = *(const bf16x8*)(W1l + o);
                    }
                }
                bf16x8 ah = *(const bf16x8*)&zhi[l15][kc*32 + lq*8];
                bf16x8 al = *(const bf16x8*)&zlo[l15][kc*32 + lq*8];
                #pragma unroll
                for (int nt=0;nt<4;nt++){
                    acc[nt] = __builtin_amdgcn_mfma_f32_16x16x32_bf16(ah, bh[cur][nt], acc[nt], 0, 0, 0);
                    acc[nt] = __builtin_amdgcn_mfma_f32_16x16x32_bf16(ah, bl[cur][nt], acc[nt], 0, 0, 0);
                    acc[nt] = __builtin_amdgcn_mfma_f32_16x16x32_bf16(al, bh[cur][nt], acc[nt], 0, 0, 0);
                }
            }
            #pragma unroll
            for (int nt=0;nt<4;nt++){
                int col = wave*64 + nt*16 + l15;
                float bb = b1[col];
                #pragma unroll
                for (int reg=0;reg<4;reg++){
                    int r = lq*4 + reg;
                    float v = fmaxf(acc[nt][reg] + bb, 0.f);
                    uint32_t h = bf16_rne_bits(v);
                    h1hi[r][col] = (uint16_t)(h >> 16);
                    h1lo[r][col] = (uint16_t)(bf16_rne_bits(v - __uint_as_float(h)) >> 16);
                }
            }
        }
        __syncthreads();

        {
            f32x4 acc[4];
            #pragma unroll
            for (int nt=0;nt<4;nt++) acc[nt] = (f32x4)(0.f);
            bf16x8 bh[2][4], bl[2][4];
            #pragma unroll
            for (int nt=0;nt<4;nt++){
                size_t o = (size_t)(wave*64 + nt*16 + l15)*FHID + lq*8;
                bh[0][nt] = *(const bf16x8*)(W2h + o);
                bl[0][nt] = *(const bf16x8*)(W2l + o);
            }
            #pragma unroll
            for (int kc=0;kc<8;kc++){
                int cur = kc & 1, nxt = cur ^ 1;
                if (kc < 7){
                    #pragma unroll
                    for (int nt=0;nt<4;nt++){
                        size_t o = (size_t)(wave*64 + nt*16 + l15)*FHID + (kc+1)*32 + lq*8;
                        bh[nxt][nt] = *(const bf16x8*)(W2h + o);
                        bl[nxt][nt] = *(const bf16x8*)(W2l + o);
                    }
                }
                bf16x8 ah = *(const bf16x8*)&h1hi[l15][kc*32 + lq*8];
                bf16x8 al = *(const bf16x8*)&h1lo[l15][kc*32 + lq*8];
                #pragma unroll
                for (int nt=0;nt<4;nt++){
                    acc[nt] = __builtin_amdgcn_mfma_f32_16x16x32_bf16(ah, bh[cur][nt], acc[nt], 0, 0, 0);
                    acc[nt] = __builtin_amdgcn_mfma_f32_16x16x32_bf16(ah, bl[cur][nt], acc[nt], 0, 0, 0);
                    acc[nt] = __builtin_amdgcn_mfma_f32_16x16x32_bf16(al, bh[cur][nt], acc[nt], 0, 0, 0);
                }
            }
            #pragma unroll
            for (int nt=0;nt<4;nt++){
                int col = wave*64 + nt*16 + l15;
                float bb = b2[col];
                #pragma unroll
                for (int reg=0;reg<4;reg++)
                    oS[lq*4 + reg][col] = acc[nt][reg] + bb;
            }
        }
        __syncthreads();

        {
            int r  = tid >> 5;
            int lc = tid & 31;
            float ldp = 0.f;
            #pragma unroll
            for (int j=0;j<4;j++){
                int l = lc + j*32;
                float m = oS[r][l];
                float s = oS[r][l + 128];
                float g = 1.f/(1.f + expf(-s));
                float zv = __uint_as_float((uint32_t)zhi[r][l] << 16)
                         + __uint_as_float((uint32_t)zlo[r][l] << 16);
                float zn = g*zv + (1.f - g)*m;
                uint32_t h = bf16_rne_bits(zn);
                uint16_t hb = (uint16_t)(h >> 16);
                uint16_t lb = (uint16_t)(bf16_rne_bits(zn - __uint_as_float(h)) >> 16);
                zhi[r][l] = hb; zlo[r][l] = lb;
                zhi[r+8][l] = hb; zlo[r+8][l] = lb;
                ldp += logf(g + 1e-8f);
            }
            ldp += __shfl_xor(ldp, 1, 32);
            ldp += __shfl_xor(ldp, 2, 32);
            ldp += __shfl_xor(ldp, 4, 32);
            ldp += __shfl_xor(ldp, 8, 32);
            ldp += __shfl_xor(ldp, 16, 32);
            ldacc += ldp;
        }
        __syncthreads();
    }

    #pragma unroll
    for (int q=0;q<4;q++){
        int idx = q*256 + tid;
        int r = idx >> 7, l = idx & 127;
        uint32_t h = (uint32_t)zhi[r][l] << 16;
        float zv = __uint_as_float(h) + __uint_as_float((uint32_t)zlo[r][l] << 16);
        zK[(size_t)(g0+r)*LAT + l] = zv;
        zkb[(size_t)(g0+r)*LAT + l] = (uint16_t)(h >> 16);
    }
    if ((tid & 31) == 0)
        sld[g0 + (tid >> 5)] = ldacc;
}

// ---------------- edge-logits symmetrize ----------------

__global__ void k_sym(const float* __restrict__ raw, float* __restrict__ outp){
    int idx = blockIdx.x*256 + threadIdx.x;
    const int total = NB*MA*MA;
    if (idx >= total) return;
    int b = idx / (MA*MA);
    int rem = idx - b*(MA*MA);
    int i = rem / MA;
    int j = rem - i*MA;
    const size_t base = (size_t)b*(MA*MA*NEF_);
    const float4 a  = *(const float4*)(raw + base + (size_t)(i*MA + j)*NEF_);
    const float4 bt = *(const float4*)(raw + base + (size_t)(j*MA + i)*NEF_);
    float4 r;
    r.x = (a.x + bt.x)*0.5f;
    r.y = (a.y + bt.y)*0.5f;
    r.z = (a.z + bt.z)*0.5f;
    r.w = (a.w + bt.w)*0.5f;
    *(float4*)(outp + base + (size_t)(i*MA + j)*NEF_) = r;
}

// ---------------- launch ----------------

extern "C" void kernel_launch(void* const* d_in, const int* in_sizes, int n_in,
                              void* d_out, int out_size, void* d_ws, size_t ws_size,
                              hipStream_t stream){
    (void)in_sizes; (void)n_in; (void)out_size; (void)ws_size;
    const int*   x        = (const int*)d_in[0];
    const int*   eidx     = (const int*)d_in[1];
    const int*   eattr    = (const int*)d_in[2];
    const int*   batch    = (const int*)d_in[3];
    const float* eps      = (const float*)d_in[4];
    const float* node_emb = (const float*)d_in[5];
    const float* edge_emb = (const float*)d_in[6];
    const float* conv_w1  = (const float*)d_in[7];
    const float* conv_b1  = (const float*)d_in[8];
    const float* conv_w2  = (const float*)d_in[9];
    const float* conv_b2  = (const float*)d_in[10];
    const float* mu_w     = (const float*)d_in[11];
    const float* mu_b     = (const float*)d_in[12];
    const float* lv_w     = (const float*)d_in[13];
    const float* lv_b     = (const float*)d_in[14];
    const float* fw1      = (const float*)d_in[15];
    const float* fb1      = (const float*)d_in[16];
    const float* fw2      = (const float*)d_in[17];
    const float* fb2      = (const float*)d_in[18];
    const float* dn_w1    = (const float*)d_in[19];
    const float* dn_b1    = (const float*)d_in[20];
    const float* dn_w2    = (const float*)d_in[21];
    const float* dn_b2    = (const float*)d_in[22];
    const float* de_w1    = (const float*)d_in[23];
    const float* de_b1    = (const float*)d_in[24];
    const float* de_w2    = (const float*)d_in[25];
    const float* de_b2    = (const float*)d_in[26];

    float* out = (float*)d_out;
    const size_t off_node = 0;
    const size_t off_edge = (size_t)NB*MA*NNF_;
    const size_t off_mu   = off_edge + (size_t)NB*MA*MA*NEF_;
    const size_t off_lv   = off_mu + (size_t)NB*LAT;
    const size_t off_z0   = off_lv + (size_t)NB*LAT;
    const size_t off_zk   = off_z0 + (size_t)NB*LAT;
    const size_t off_sld  = off_zk + (size_t)NB*LAT;

    char* p = (char*)d_ws;
    auto alloc = [&](size_t bytes)->char*{ char* r = p; p += (bytes + 255) & ~(size_t)255; return r; };
    uint16_t* h_b   = (uint16_t*)alloc((size_t)N_NODES*HIDDEN*2);
    uint16_t* t_b   = (uint16_t*)alloc((size_t)N_NODES*HIDDEN*2);
    int*   offs   = (int*)  alloc((size_t)(N_NODES+1)*4);
    int*   cursor = (int*)  alloc((size_t)N_NODES*4);
    int*   epack  = (int*)  alloc((size_t)N_EDGES*4);
    int*   gstart = (int*)  alloc((size_t)NB*4);
    int*   gcnt   = (int*)  alloc((size_t)NB*4);
    uint32_t* hg_pk = (uint32_t*)alloc((size_t)NB*HIDDEN*4);
    float* mv       = (float*)alloc((size_t)NB*256*4);
    uint16_t* cw1b  = (uint16_t*)alloc((size_t)4*HIDDEN*HIDDEN*2);
    uint16_t* cw2b  = (uint16_t*)alloc((size_t)4*HIDDEN*HIDDEN*2);
    uint32_t* mvwpk = (uint32_t*)alloc((size_t)256*256*4);
    float*    mvb   = (float*)  alloc((size_t)256*4);
    uint16_t* w1hi  = (uint16_t*)alloc((size_t)NFLOWS*FHID*LAT*2);
    uint16_t* w1lo  = (uint16_t*)alloc((size_t)NFLOWS*FHID*LAT*2);
    uint16_t* w2hi  = (uint16_t*)alloc((size_t)NFLOWS*2*LAT*FHID*2);
    uint16_t* w2lo  = (uint16_t*)alloc((size_t)NFLOWS*2*LAT*FHID*2);
    uint16_t* dnw1b = (uint16_t*)alloc((size_t)256*LAT*2);
    uint16_t* dnw2b = (uint16_t*)alloc((size_t)MA*NNF_*256*2);
    uint16_t* dew1b = (uint16_t*)alloc((size_t)512*LAT*2);
    uint16_t* dew2b = (uint16_t*)alloc((size_t)MA*MA*NEF_*512*2);
    uint16_t* zkb   = (uint16_t*)alloc((size_t)NB*LAT*2);
    uint16_t* hnb   = (uint16_t*)alloc((size_t)NB*256*2);
    uint16_t* heb   = (uint16_t*)alloc((size_t)NB*512*2);
    float* edge_raw = (float*)alloc((size_t)NB*MA*MA*NEF_*4);

    const int* esrc = eidx;
    const int* edst = eidx + N_EDGES;

    // weight conversions
    k_cvt_b16<<<(4*HIDDEN*HIDDEN+255)/256, 256, 0, stream>>>(conv_w1, cw1b, 4*HIDDEN*HIDDEN);
    k_cvt_b16<<<(4*HIDDEN*HIDDEN+255)/256, 256, 0, stream>>>(conv_w2, cw2b, 4*HIDDEN*HIDDEN);
    k_cvt_mv<<<(256*256+255)/256, 256, 0, stream>>>(mu_w, mu_b, lv_w, lv_b, mvwpk, mvb);
    k_cvt_fw1s<<<(NFLOWS*FHID*LAT+255)/256, 256, 0, stream>>>(fw1, w1hi, w1lo);
    k_cvt_fw2s<<<(NFLOWS*2*LAT*FHID+255)/256, 256, 0, stream>>>(fw2, w2hi, w2lo);
    k_cvt_b16<<<(256*LAT+255)/256, 256, 0, stream>>>(dn_w1, dnw1b, 256*LAT);
    k_cvt_b16<<<(MA*NNF_*256+255)/256, 256, 0, stream>>>(dn_w2, dnw2b, MA*NNF_*256);
    k_cvt_b16<<<(512*LAT+255)/256, 256, 0, stream>>>(de_w1, dew1b, 512*LAT);
    k_cvt_b16<<<(MA*MA*NEF_*512+255)/256, 256, 0, stream>>>(de_w2, dew2b, MA*MA*NEF_*512);

    k_init   <<<(N_NODES+255)/256, 256, 0, stream>>>(cursor, gstart, gcnt);
    k_embed  <<<N_NODES, HIDDEN, 0, stream>>>(x, node_emb, h_b);
    k_deg    <<<(N_EDGES+255)/256, 256, 0, stream>>>(edst, cursor);
    k_meta   <<<(N_NODES+255)/256, 256, 0, stream>>>(batch, gstart, gcnt);
    k_scan   <<<1, 1024, 0, stream>>>(cursor, offs);
    k_scatter<<<(N_EDGES+255)/256, 256, 0, stream>>>(esrc, edst, eattr, offs, cursor, epack);

    const size_t SM32 = 32768, SM64 = 65536;
    for (int k=0;k<4;k++){
        k_aggr<<<N_NODES/4, 256, 0, stream>>>(h_b, edge_emb, offs, epack, t_b);
        mfma_gemm<0,1><<<dim3(1, N_NODES/64), 256, SM32, stream>>>(
            t_b, cw1b + (size_t)k*HIDDEN*HIDDEN, conv_b1 + (size_t)k*HIDDEN,
            t_b, N_NODES, HIDDEN, HIDDEN, 1);
        mfma_gemm<0,1><<<dim3(1, N_NODES/64), 256, SM32, stream>>>(
            t_b, cw2b + (size_t)k*HIDDEN*HIDDEN, conv_b2 + (size_t)k*HIDDEN,
            h_b, N_NODES, HIDDEN, HIDDEN, 1);
    }

    k_pool<<<NB, HIDDEN, 0, stream>>>(h_b, gstart, gcnt, hg_pk);
    mfma_gemm<1,2><<<dim3(1, NB/64), 256, SM64, stream>>>(hg_pk, mvwpk, mvb, mv, NB, 256, HIDDEN, 0);
    k_z0<<<(NB*LAT+255)/256, 256, 0, stream>>>(mv, eps, out+off_mu, out+off_lv, out+off_z0);

    k_flows_mfma2<<<NB/FGPB, 256, 0, stream>>>(out+off_z0, w1hi, w1lo, fb1, w2hi, w2lo, fb2,
                                               out+off_zk, zkb, out+off_sld);

    // decoders (plain bf16 MFMA)
    mfma_gemm<0,1><<<dim3(1, NB/64), 256, SM32, stream>>>(zkb, dnw1b, dn_b1, hnb, NB, 256, LAT, 1);
    mfma_gemm<0,2><<<dim3(6, NB/64), 256, SM64, stream>>>(hnb, dnw2b, dn_b2, out+off_node, NB, MA*NNF_, 256, 0);
    mfma_gemm<0,1><<<dim3(2, NB/64), 256, SM32, stream>>>(zkb, dew1b, de_b1, heb, NB, 512, LAT, 1);
    mfma_gemm<0,2><<<dim3(23, NB/64), 256, SM64, stream>>>(heb, dew2b, de_b2, edge_raw, NB, MA*MA*NEF_, 512, 0);
    k_sym<<<(NB*MA*MA + 255)/256, 256, 0, stream>>>(edge_raw, out + off_edge);
}

// Round 7
// 663.414 us; speedup vs baseline: 1.9938x; 1.0007x over previous
//
#include <hip/hip_runtime.h>
#include <hip/hip_bf16.h>
#include <math.h>
#include <stdint.h>

#define N_NODES 49152
#define N_EDGES 196608
#define NB      2048
#define HIDDEN  256
#define LAT     128
#define FHID    256
#define NFLOWS  4
#define MA      38
#define NNF_    38
#define NEF_    4

typedef __attribute__((ext_vector_type(8))) short bf16x8;
typedef __attribute__((ext_vector_type(4))) float f32x4;

// ---------- bf16 helpers ----------
__device__ inline uint32_t bf16_rne_bits(float v){
    uint32_t u = __float_as_uint(v);
    u += 0x7fffu + ((u >> 16) & 1u);
    return u & 0xffff0000u;
}
__device__ inline uint16_t to_b16(float v){ return (uint16_t)(bf16_rne_bits(v) >> 16); }
__device__ inline float from_b16(uint16_t u){ return __uint_as_float((uint32_t)u << 16); }
__device__ inline uint32_t pack_hl(float v){
    uint32_t hu = bf16_rne_bits(v);
    float r = v - __uint_as_float(hu);
    uint32_t lu = bf16_rne_bits(r);
    return hu | (lu >> 16);
}

__device__ inline void unpack_frag(const uint4& x, const uint4& y, bf16x8& hi, bf16x8& lo){
    union { bf16x8 v; uint32_t u[4]; } H, L;
    H.u[0] = __builtin_amdgcn_perm(x.y, x.x, 0x07060302u);
    H.u[1] = __builtin_amdgcn_perm(x.w, x.z, 0x07060302u);
    H.u[2] = __builtin_amdgcn_perm(y.y, y.x, 0x07060302u);
    H.u[3] = __builtin_amdgcn_perm(y.w, y.z, 0x07060302u);
    L.u[0] = __builtin_amdgcn_perm(x.y, x.x, 0x05040100u);
    L.u[1] = __builtin_amdgcn_perm(x.w, x.z, 0x05040100u);
    L.u[2] = __builtin_amdgcn_perm(y.y, y.x, 0x05040100u);
    L.u[3] = __builtin_amdgcn_perm(y.w, y.z, 0x05040100u);
    hi = H.v; lo = L.v;
}

// ---------------- init / CSR build ----------------

__global__ void k_init(int* __restrict__ cursor, int* __restrict__ gstart, int* __restrict__ gcnt){
    int i = blockIdx.x*256 + threadIdx.x;
    if (i < N_NODES) cursor[i] = 0;
    if (i < NB){ gstart[i] = 0x7fffffff; gcnt[i] = 0; }
}

__global__ void k_embed(const int* __restrict__ x, const float* __restrict__ emb, uint16_t* __restrict__ h){
    int i = blockIdx.x; int c = threadIdx.x;
    h[(size_t)i*HIDDEN + c] = to_b16(emb[x[i]*HIDDEN + c]);
}

__global__ void k_deg(const int* __restrict__ dst, int* __restrict__ cursor){
    int e = blockIdx.x*256 + threadIdx.x;
    if (e < N_EDGES) atomicAdd(&cursor[dst[e]], 1);
}

__global__ void k_meta(const int* __restrict__ batch, int* __restrict__ gstart, int* __restrict__ gcnt){
    int i = blockIdx.x*256 + threadIdx.x;
    if (i < N_NODES){ int b = batch[i]; atomicMin(&gstart[b], i); atomicAdd(&gcnt[b], 1); }
}

__global__ __launch_bounds__(1024) void k_scan(int* __restrict__ cursor, int* __restrict__ offs){
    __shared__ int part[1024];
    const int tid = threadIdx.x;
    const int CH = N_NODES/1024; // 48
    int local[48];
    int s = 0;
    int base = tid*CH;
    for (int j=0;j<CH;j++){ local[j] = cursor[base+j]; s += local[j]; }
    part[tid] = s;
    __syncthreads();
    for (int off=1; off<1024; off<<=1){
        int v = (tid>=off) ? part[tid-off] : 0;
        __syncthreads();
        part[tid] += v;
        __syncthreads();
    }
    int excl = (tid==0) ? 0 : part[tid-1];
    for (int j=0;j<CH;j++){ offs[base+j] = excl; excl += local[j]; cursor[base+j] = 0; }
    if (tid == 1023) offs[N_NODES] = excl;
}

__global__ void k_scatter(const int* __restrict__ src, const int* __restrict__ dst, const int* __restrict__ attr,
                          const int* __restrict__ offs, int* __restrict__ cursor, int* __restrict__ epack){
    int e = blockIdx.x*256 + threadIdx.x;
    if (e < N_EDGES){
        int d = dst[e];
        int pos = atomicAdd(&cursor[d], 1);
        epack[offs[d] + pos] = (src[e] & 0xffff) | (attr[e] << 16);
    }
}

// ---------------- message aggregation: wave-per-node, 4-edge MLP chunks ----------------

__global__ __launch_bounds__(256) void k_aggr(const uint16_t* __restrict__ h, const float* __restrict__ eemb,
                                              const int* __restrict__ offs, const int* __restrict__ epack,
                                              uint16_t* __restrict__ t){
    __shared__ float sE[NEF_*HIDDEN];
    const int tid  = threadIdx.x;
    #pragma unroll
    for (int q=0;q<NEF_;q++) sE[q*256 + tid] = eemb[q*256 + tid];
    __syncthreads();

    const int wave = tid >> 6;
    const int lane = tid & 63;
    const int node = blockIdx.x*4 + wave;
    const int c4   = lane*4;

    uint2 hu = *(const uint2*)(h + (size_t)node*HIDDEN + c4);
    float4 acc;
    acc.x = __uint_as_float(hu.x << 16);
    acc.y = __uint_as_float(hu.x & 0xffff0000u);
    acc.z = __uint_as_float(hu.y << 16);
    acc.w = __uint_as_float(hu.y & 0xffff0000u);

    const int e0 = offs[node], e1 = offs[node+1];
    for (int j = e0; j < e1; j += 4){
        int p0 = epack[j];
        int p1 = (j+1 < e1) ? epack[j+1] : p0;
        int p2 = (j+2 < e1) ? epack[j+2] : p0;
        int p3 = (j+3 < e1) ? epack[j+3] : p0;
        uint2 g0 = *(const uint2*)(h + (size_t)(p0 & 0xffff)*HIDDEN + c4);
        uint2 g1 = *(const uint2*)(h + (size_t)(p1 & 0xffff)*HIDDEN + c4);
        uint2 g2 = *(const uint2*)(h + (size_t)(p2 & 0xffff)*HIDDEN + c4);
        uint2 g3 = *(const uint2*)(h + (size_t)(p3 & 0xffff)*HIDDEN + c4);
        {
            const float4 ev = *(const float4*)&sE[(p0 >> 16)*HIDDEN + c4];
            acc.x += fmaxf(__uint_as_float(g0.x << 16)        + ev.x, 0.f);
            acc.y += fmaxf(__uint_as_float(g0.x & 0xffff0000u) + ev.y, 0.f);
            acc.z += fmaxf(__uint_as_float(g0.y << 16)        + ev.z, 0.f);
            acc.w += fmaxf(__uint_as_float(g0.y & 0xffff0000u) + ev.w, 0.f);
        }
        if (j+1 < e1){
            const float4 ev = *(const float4*)&sE[(p1 >> 16)*HIDDEN + c4];
            acc.x += fmaxf(__uint_as_float(g1.x << 16)        + ev.x, 0.f);
            acc.y += fmaxf(__uint_as_float(g1.x & 0xffff0000u) + ev.y, 0.f);
            acc.z += fmaxf(__uint_as_float(g1.y << 16)        + ev.z, 0.f);
            acc.w += fmaxf(__uint_as_float(g1.y & 0xffff0000u) + ev.w, 0.f);
        }
        if (j+2 < e1){
            const float4 ev = *(const float4*)&sE[(p2 >> 16)*HIDDEN + c4];
            acc.x += fmaxf(__uint_as_float(g2.x << 16)        + ev.x, 0.f);
            acc.y += fmaxf(__uint_as_float(g2.x & 0xffff0000u) + ev.y, 0.f);
            acc.z += fmaxf(__uint_as_float(g2.y << 16)        + ev.z, 0.f);
            acc.w += fmaxf(__uint_as_float(g2.y & 0xffff0000u) + ev.w, 0.f);
        }
        if (j+3 < e1){
            const float4 ev = *(const float4*)&sE[(p3 >> 16)*HIDDEN + c4];
            acc.x += fmaxf(__uint_as_float(g3.x << 16)        + ev.x, 0.f);
            acc.y += fmaxf(__uint_as_float(g3.x & 0xffff0000u) + ev.y, 0.f);
            acc.z += fmaxf(__uint_as_float(g3.y << 16)        + ev.z, 0.f);
            acc.w += fmaxf(__uint_as_float(g3.y & 0xffff0000u) + ev.w, 0.f);
        }
    }

    uint2 o;
    o.x = (uint32_t)to_b16(acc.x) | ((uint32_t)to_b16(acc.y) << 16);
    o.y = (uint32_t)to_b16(acc.z) | ((uint32_t)to_b16(acc.w) << 16);
    *(uint2*)(t + (size_t)node*HIDDEN + c4) = o;
}

// ---------------- weight / activation converters ----------------

__global__ void k_cvt_b16(const float* __restrict__ s, uint16_t* __restrict__ d, int n){
    int i = blockIdx.x*256 + threadIdx.x;
    if (i < n) d[i] = to_b16(s[i]);
}
__global__ void k_cvt_fw1s(const float* __restrict__ w, uint16_t* __restrict__ hi, uint16_t* __restrict__ lo){
    int i = blockIdx.x*256 + threadIdx.x;
    if (i >= NFLOWS*FHID*LAT) return;
    int o = (i >> 7) & 255;
    int kk = i & 127;
    float v = (kk <= (o % 127)) ? w[i] : 0.f;
    uint32_t h = bf16_rne_bits(v);
    hi[i] = (uint16_t)(h >> 16);
    lo[i] = (uint16_t)(bf16_rne_bits(v - __uint_as_float(h)) >> 16);
}
__global__ void k_cvt_fw2s(const float* __restrict__ w, uint16_t* __restrict__ hi, uint16_t* __restrict__ lo){
    int i = blockIdx.x*256 + threadIdx.x;
    if (i >= NFLOWS*2*LAT*FHID) return;
    int o = (i >> 8) & 255;
    int hh = i & 255;
    float v = ((hh % 127) < (o & 127)) ? w[i] : 0.f;
    uint32_t h = bf16_rne_bits(v);
    hi[i] = (uint16_t)(h >> 16);
    lo[i] = (uint16_t)(bf16_rne_bits(v - __uint_as_float(h)) >> 16);
}
__global__ void k_cvt_mv(const float* __restrict__ mu_w, const float* __restrict__ mu_b,
                         const float* __restrict__ lv_w, const float* __restrict__ lv_b,
                         uint32_t* __restrict__ wpk, float* __restrict__ bpk){
    int i = blockIdx.x*256 + threadIdx.x;
    if (i < 256*256){
        int o = i >> 8, k2 = i & 255;
        float v = (o < 128) ? mu_w[o*256 + k2] : lv_w[(o-128)*256 + k2];
        wpk[i] = pack_hl(v);
    }
    if (i < 256) bpk[i] = (i < 128) ? mu_b[i] : lv_b[i-128];
}

// ---------------- fused conv: h_out = relu(relu(A@W1^T+b1)@W2^T+b2) ----------------
// 64 rows/block, 256 threads. A staged via global_load_lds (swizzled granules).
// h1 kept in LDS (granule-swizzled, 32KB) -> total dynamic LDS exactly 64KB.

__global__ __launch_bounds__(256) void k_conv2(
    const uint16_t* __restrict__ A,
    const uint16_t* __restrict__ W1, const float* __restrict__ B1,
    const uint16_t* __restrict__ W2, const float* __restrict__ B2,
    uint16_t* __restrict__ C)
{
    extern __shared__ __align__(16) char smem[];          // [0,32KB) stage/epilogue
    uint16_t* h1 = (uint16_t*)(smem + 32768);             // [32KB,64KB) h1 swizzled
    const int tid  = threadIdx.x;
    const int wave = tid >> 6;
    const int lane = tid & 63;
    const int l15  = lane & 15;
    const int lq   = lane >> 4;
    const int l7   = lane & 7;
    const int row0 = blockIdx.x * 64;

    // stage A (64 rows x 256 cols bf16 = 2048 granules of 16B)
    #pragma unroll
    for (int it = 0; it < 8; ++it) {
        int s  = it*256 + wave*64 + lane;
        int m  = s >> 5;
        int gl = (s & 31) ^ (m & 7);
        const char* gp = (const char*)A + ((size_t)(row0+m)*HIDDEN)*2 + gl*16;
        __builtin_amdgcn_global_load_lds(
            (const __attribute__((address_space(1))) uint32_t*)gp,
            (__attribute__((address_space(3))) uint32_t*)(smem + (it*256 + wave*64 + lane)*16),
            16, 0, 0);
    }
    __syncthreads();

    // ---- GEMM1 ----
    f32x4 acc[4][4];
    #pragma unroll
    for (int mt=0;mt<4;mt++)
        #pragma unroll
        for (int nt=0;nt<4;nt++) acc[mt][nt] = (f32x4)(0.f);

    #pragma unroll
    for (int kc = 0; kc < 8; ++kc){
        bf16x8 bw[4];
        #pragma unroll
        for (int nt=0;nt<4;nt++)
            bw[nt] = *(const bf16x8*)(W1 + (size_t)(wave*64 + nt*16 + l15)*HIDDEN + kc*32 + lq*8);
        #pragma unroll
        for (int mt=0;mt<4;mt++){
            const int mb = (mt*16 + l15) << 5;
            int g = kc*4 + lq;
            bf16x8 a = *(const bf16x8*)(smem + (size_t)(mb + (g ^ l7))*16);
            #pragma unroll
            for (int nt=0;nt<4;nt++)
                acc[mt][nt] = __builtin_amdgcn_mfma_f32_16x16x32_bf16(a, bw[nt], acc[mt][nt], 0, 0, 0);
        }
    }

    // epilogue1 -> h1 (granule-swizzled: u16 idx = (r*32 + ((col>>3)^(r&7)))*8 + (col&7))
    #pragma unroll
    for (int mt=0;mt<4;mt++){
        #pragma unroll
        for (int nt=0;nt<4;nt++){
            int col = wave*64 + nt*16 + l15;
            float bb = B1[col];
            #pragma unroll
            for (int reg=0;reg<4;reg++){
                int r = mt*16 + lq*4 + reg;
                float v = fmaxf(acc[mt][nt][reg] + bb, 0.f);
                h1[(r*32 + ((col>>3) ^ (r&7)))*8 + (col&7)] = to_b16(v);
            }
        }
    }
    __syncthreads();

    // ---- GEMM2 ----
    #pragma unroll
    for (int mt=0;mt<4;mt++)
        #pragma unroll
        for (int nt=0;nt<4;nt++) acc[mt][nt] = (f32x4)(0.f);

    #pragma unroll
    for (int kc = 0; kc < 8; ++kc){
        bf16x8 bw[4];
        #pragma unroll
        for (int nt=0;nt<4;nt++)
            bw[nt] = *(const bf16x8*)(W2 + (size_t)(wave*64 + nt*16 + l15)*HIDDEN + kc*32 + lq*8);
        #pragma unroll
        for (int mt=0;mt<4;mt++){
            int m = mt*16 + l15;
            bf16x8 a = *(const bf16x8*)(h1 + (size_t)(m*32 + ((kc*4 + lq) ^ (m & 7)))*8);
            #pragma unroll
            for (int nt=0;nt<4;nt++)
                acc[mt][nt] = __builtin_amdgcn_mfma_f32_16x16x32_bf16(a, bw[nt], acc[mt][nt], 0, 0, 0);
        }
    }
    __syncthreads();   // h1 + stage no longer needed by any wave

    // epilogue2: bias+relu, repack via wave-private LDS, coalesced bf16 store
    uint16_t* rs = (uint16_t*)(smem + wave*8192);
    #pragma unroll
    for (int mt=0;mt<4;mt++){
        #pragma unroll
        for (int nt=0;nt<4;nt++){
            int cl = nt*16 + l15;
            float bb = B2[wave*64 + cl];
            #pragma unroll
            for (int reg=0;reg<4;reg++){
                int r = mt*16 + lq*4 + reg;
                rs[r*64 + cl] = to_b16(fmaxf(acc[mt][nt][reg] + bb, 0.f));
            }
        }
    }
    __syncthreads();
    #pragma unroll
    for (int it = 0; it < 32; ++it){
        int r   = it*2 + (lane >> 5);
        int clp = lane & 31;
        int col = wave*64 + clp*2;
        *(uint32_t*)(C + (size_t)(row0+r)*HIDDEN + col) = *(const uint32_t*)(rs + r*64 + clp*2);
    }
}

// ---------------- MFMA GEMM (mu/lv + decoders) ----------------

template<int SPLIT, int OUTM>
__global__ __launch_bounds__(256) void mfma_gemm(
    const void* __restrict__ Ap, const void* __restrict__ Wp,
    const float* __restrict__ bias, void* __restrict__ Cp,
    int M, int N, int K, int relu)
{
    extern __shared__ __align__(16) char smem[];
    const int tid  = threadIdx.x;
    const int wave = tid >> 6;
    const int lane = tid & 63;
    const int l15  = lane & 15;
    const int lq   = lane >> 4;
    const int l7   = lane & 7;
    const int row0 = blockIdx.y * 64;
    const int n0   = blockIdx.x * 256;
    const int ELB  = SPLIT ? 4 : 2;
    const int KC   = (K < 256) ? K : 256;
    const int GR   = (KC * ELB) >> 4;
    const int rsh  = (GR == 64) ? 6 : ((GR == 32) ? 5 : 4);

    f32x4 acc[4][4];
    #pragma unroll
    for (int mt=0;mt<4;mt++)
        #pragma unroll
        for (int nt=0;nt<4;nt++) acc[mt][nt] = (f32x4)(0.f);

    const char* Ab = (const char*)Ap;
    const char* Wb = (const char*)Wp;

    for (int kbase = 0; kbase < K; kbase += KC) {
        const int rounds = GR >> 2;
        for (int it = 0; it < rounds; ++it) {
            int sbase = it*256 + wave*64;
            int s  = sbase + lane;
            int m  = s >> rsh;
            int gl = (s & (GR-1)) ^ (m & 7);
            const char* gp = Ab + ((size_t)(row0+m)*K + kbase)*ELB + gl*16;
            __builtin_amdgcn_global_load_lds(
                (const __attribute__((address_space(1))) uint32_t*)gp,
                (__attribute__((address_space(3))) uint32_t*)(smem + sbase*16),
                16, 0, 0);
        }
        __syncthreads();

        for (int kc = 0; kc < (KC >> 5); ++kc) {
            bf16x8 bhi[4], blo[4];
            #pragma unroll
            for (int nt=0;nt<4;nt++){
                int n = n0 + wave*64 + nt*16 + l15;
                if (n >= N) n = N-1;
                if (SPLIT){
                    const uint4* wp4 = (const uint4*)(Wb + ((size_t)n*K + kbase + kc*32 + lq*8)*4);
                    uint4 xx = wp4[0], yy = wp4[1];
                    unpack_frag(xx, yy, bhi[nt], blo[nt]);
                } else {
                    bhi[nt] = *(const bf16x8*)(Wb + ((size_t)n*K + kbase + kc*32 + lq*8)*2);
                }
            }
            #pragma unroll
            for (int mt=0;mt<4;mt++){
                const int mb = (mt*16 + l15) << rsh;
                if (SPLIT){
                    int g0 = kc*8 + lq*2;
                    uint4 xx = *(const uint4*)(smem + (size_t)(mb + ((g0  ) ^ l7))*16);
                    uint4 yy = *(const uint4*)(smem + (size_t)(mb + ((g0+1) ^ l7))*16);
                    bf16x8 ahi, alo;
                    unpack_frag(xx, yy, ahi, alo);
                    #pragma unroll
                    for (int nt=0;nt<4;nt++){
                        acc[mt][nt] = __builtin_amdgcn_mfma_f32_16x16x32_bf16(ahi, bhi[nt], acc[mt][nt], 0, 0, 0);
                        acc[mt][nt] = __builtin_amdgcn_mfma_f32_16x16x32_bf16(ahi, blo[nt], acc[mt][nt], 0, 0, 0);
                        acc[mt][nt] = __builtin_amdgcn_mfma_f32_16x16x32_bf16(alo, bhi[nt], acc[mt][nt], 0, 0, 0);
                    }
                } else {
                    int g = kc*4 + lq;
                    bf16x8 a = *(const bf16x8*)(smem + (size_t)(mb + (g ^ l7))*16);
                    #pragma unroll
                    for (int nt=0;nt<4;nt++){
                        acc[mt][nt] = __builtin_amdgcn_mfma_f32_16x16x32_bf16(a, bhi[nt], acc[mt][nt], 0, 0, 0);
                    }
                }
            }
        }
        __syncthreads();
    }

    const int ES = (OUTM == 1) ? 2 : 4;
    char* rs = smem + wave*(64*64*ES);
    const int colbase = n0 + wave*64;
    #pragma unroll
    for (int mt=0;mt<4;mt++){
        #pragma unroll
        for (int nt=0;nt<4;nt++){
            int cl = nt*16 + l15;
            int col = colbase + cl;
            float bb = bias[col < N ? col : N-1];
            #pragma unroll
            for (int reg=0;reg<4;reg++){
                int r = mt*16 + lq*4 + reg;
                float v = acc[mt][nt][reg] + bb;
                if (relu) v = fmaxf(v, 0.f);
                if (OUTM == 1) ((uint16_t*)rs)[r*64 + cl] = to_b16(v);
                else           ((float*)rs)[r*64 + cl] = v;
            }
        }
    }
    __syncthreads();
    for (int it = 0; it < 32; ++it) {
        int r   = it*2 + (lane>>5);
        int clp = lane & 31;
        int col = colbase + clp*2;
        if (col < N){
            if (OUTM == 1){
                uint32_t d = *(const uint32_t*)((const uint16_t*)rs + r*64 + clp*2);
                *(uint32_t*)((char*)Cp + ((size_t)(row0+r)*N + col)*2) = d;
            } else {
                float2 d = *(const float2*)((const float*)rs + r*64 + clp*2);
                *(float2*)((float*)Cp + (size_t)(row0+r)*N + col) = d;
            }
        }
    }
}

// ---------------- pooling + z0 elementwise ----------------

__global__ void k_pool(const uint16_t* __restrict__ h, const int* __restrict__ gstart,
                       const int* __restrict__ gcnt, uint32_t* __restrict__ hg){
    int b = blockIdx.x; int c = threadIdx.x;
    int s0 = gstart[b]; int n = gcnt[b];
    float s = 0.f;
    for (int j=0;j<n;j++) s += from_b16(h[(size_t)(s0+j)*HIDDEN + c]);
    hg[(size_t)b*HIDDEN + c] = pack_hl(s);
}

__global__ void k_z0(const float* __restrict__ mv, const float* __restrict__ eps,
                     float* __restrict__ mu_o, float* __restrict__ lv_o, float* __restrict__ z0_o){
    int i = blockIdx.x*256 + threadIdx.x;
    if (i >= NB*LAT) return;
    int b = i >> 7, l = i & 127;
    float m = mv[(size_t)b*256 + l];
    float v = mv[(size_t)b*256 + l + 128];
    mu_o[i] = m;
    lv_o[i] = v;
    z0_o[i] = m + eps[i]*expf(0.5f*v);
}

// ---------------- fused MFMA flows v3 ----------------
// 128 blocks x 1024 threads (16 waves); 16 graphs/block; wave w owns output cols
// [16w,16w+16) AND z-row w in the update stage. Weights: pre-masked hi/lo planes.

__global__ __launch_bounds__(1024) void k_flows_mfma3(
    const float* __restrict__ z0,
    const uint16_t* __restrict__ w1hi, const uint16_t* __restrict__ w1lo, const float* __restrict__ fb1,
    const uint16_t* __restrict__ w2hi, const uint16_t* __restrict__ w2lo, const float* __restrict__ fb2,
    float* __restrict__ zK, uint16_t* __restrict__ zkb, float* __restrict__ sld)
{
    __shared__ __align__(16) uint16_t zhi[16][136];   // 68 dw/row ≡ 4 mod 32 -> 2-way
    __shared__ __align__(16) uint16_t zlo[16][136];
    __shared__ __align__(16) uint16_t h1hi[16][280];  // 140 dw/row ≡ 12 mod 32 -> 2-way
    __shared__ __align__(16) uint16_t h1lo[16][280];
    __shared__ __align__(16) float    oS[16][268];    // 268 ≡ 12 mod 32 -> 2-way
    const int tid  = threadIdx.x;
    const int wave = tid >> 6;       // 0..15
    const int lane = tid & 63;
    const int l15  = lane & 15;
    const int lq   = lane >> 4;
    const int g0   = blockIdx.x * 16;
    const int col  = wave*16 + l15;  // output column this lane produces

    #pragma unroll
    for (int q=0;q<2;q++){
        int idx = q*1024 + tid;
        int r = idx >> 7, l = idx & 127;
        float v = z0[(size_t)(g0 + r)*LAT + l];
        uint32_t h = bf16_rne_bits(v);
        zhi[r][l] = (uint16_t)(h >> 16);
        zlo[r][l] = (uint16_t)(bf16_rne_bits(v - __uint_as_float(h)) >> 16);
    }
    float ldacc = 0.f;
    __syncthreads();

    for (int kf=0; kf<NFLOWS; kf++){
        const uint16_t* W1h = w1hi + (size_t)kf*FHID*LAT;
        const uint16_t* W1l = w1lo + (size_t)kf*FHID*LAT;
        const float*    b1  = fb1 + kf*FHID;
        const uint16_t* W2h = w2hi + (size_t)kf*2*LAT*FHID;
        const uint16_t* W2l = w2lo + (size_t)kf*2*LAT*FHID;
        const float*    b2  = fb2 + kf*2*LAT;

        // ---- GEMM1: h1[16x256] = relu(z[16x128] @ w1m^T + b1) ----
        {
            f32x4 acc = (f32x4)(0.f);
            bf16x8 bh[2], bl[2];
            bh[0] = *(const bf16x8*)(W1h + (size_t)col*LAT + lq*8);
            bl[0] = *(const bf16x8*)(W1l + (size_t)col*LAT + lq*8);
            #pragma unroll
            for (int kc=0;kc<4;kc++){
                int cur = kc & 1, nxt = cur ^ 1;
                if (kc < 3){
                    bh[nxt] = *(const bf16x8*)(W1h + (size_t)col*LAT + (kc+1)*32 + lq*8);
                    bl[nxt] = *(const bf16x8*)(W1l + (size_t)col*LAT + (kc+1)*32 + lq*8);
                }
                bf16x8 ah = *(const bf16x8*)&zhi[l15][kc*32 + lq*8];
                bf16x8 al = *(const bf16x8*)&zlo[l15][kc*32 + lq*8];
                acc = __builtin_amdgcn_mfma_f32_16x16x32_bf16(ah, bh[cur], acc, 0, 0, 0);
                acc = __builtin_amdgcn_mfma_f32_16x16x32_bf16(ah, bl[cur], acc, 0, 0, 0);
                acc = __builtin_amdgcn_mfma_f32_16x16x32_bf16(al, bh[cur], acc, 0, 0, 0);
            }
            float bb = b1[col];
            #pragma unroll
            for (int reg=0;reg<4;reg++){
                int r = lq*4 + reg;
                float v = fmaxf(acc[reg] + bb, 0.f);
                uint32_t h = bf16_rne_bits(v);
                h1hi[r][col] = (uint16_t)(h >> 16);
                h1lo[r][col] = (uint16_t)(bf16_rne_bits(v - __uint_as_float(h)) >> 16);
            }
        }
        __syncthreads();

        // ---- GEMM2: out[16x256] = h1 @ w2m^T + b2 ----
        {
            f32x4 acc = (f32x4)(0.f);
            bf16x8 bh[2], bl[2];
            bh[0] = *(const bf16x8*)(W2h + (size_t)col*FHID + lq*8);
            bl[0] = *(const bf16x8*)(W2l + (size_t)col*FHID + lq*8);
            #pragma unroll
            for (int kc=0;kc<8;kc++){
                int cur = kc & 1, nxt = cur ^ 1;
                if (kc < 7){
                    bh[nxt] = *(const bf16x8*)(W2h + (size_t)col*FHID + (kc+1)*32 + lq*8);
                    bl[nxt] = *(const bf16x8*)(W2l + (size_t)col*FHID + (kc+1)*32 + lq*8);
                }
                bf16x8 ah = *(const bf16x8*)&h1hi[l15][kc*32 + lq*8];
                bf16x8 al = *(const bf16x8*)&h1lo[l15][kc*32 + lq*8];
                acc = __builtin_amdgcn_mfma_f32_16x16x32_bf16(ah, bh[cur], acc, 0, 0, 0);
                acc = __builtin_amdgcn_mfma_f32_16x16x32_bf16(ah, bl[cur], acc, 0, 0, 0);
                acc = __builtin_amdgcn_mfma_f32_16x16x32_bf16(al, bh[cur], acc, 0, 0, 0);
            }
            float bb = b2[col];
            #pragma unroll
            for (int reg=0;reg<4;reg++)
                oS[lq*4 + reg][col] = acc[reg] + bb;
        }
        __syncthreads();

        // ---- z update + log-det: wave w handles row w, 2 cols/lane ----
        {
            const int r = wave;
            float ldp = 0.f;
            #pragma unroll
            for (int j=0;j<2;j++){
                int l = lane + j*64;
                float m = oS[r][l];
                float s = oS[r][l + 128];
                float g = 1.f/(1.f + expf(-s));
                float zv = __uint_as_float((uint32_t)zhi[r][l] << 16)
                         + __uint_as_float((uint32_t)zlo[r][l] << 16);
                float zn = g*zv + (1.f - g)*m;
                uint32_t h = bf16_rne_bits(zn);
                zhi[r][l] = (uint16_t)(h >> 16);
                zlo[r][l] = (uint16_t)(bf16_rne_bits(zn - __uint_as_float(h)) >> 16);
                ldp += logf(g + 1e-8f);
            }
            #pragma unroll
            for (int off=1; off<64; off<<=1) ldp += __shfl_xor(ldp, off);
            ldacc += ldp;
        }
        __syncthreads();
    }

    #pragma unroll
    for (int q=0;q<2;q++){
        int idx = q*1024 + tid;
        int r = idx >> 7, l = idx & 127;
        uint32_t h = (uint32_t)zhi[r][l] << 16;
        float zv = __uint_as_float(h) + __uint_as_float((uint32_t)zlo[r][l] << 16);
        zK[(size_t)(g0+r)*LAT + l] = zv;
        zkb[(size_t)(g0+r)*LAT + l] = (uint16_t)(h >> 16);
    }
    if (lane == 0) sld[g0 + wave] = ldacc;
}

// ---------------- edge-logits symmetrize ----------------

__global__ void k_sym(const float* __restrict__ raw, float* __restrict__ outp){
    int idx = blockIdx.x*256 + threadIdx.x;
    const int total = NB*MA*MA;
    if (idx >= total) return;
    int b = idx / (MA*MA);
    int rem = idx - b*(MA*MA);
    int i = rem / MA;
    int j = rem - i*MA;
    const size_t base = (size_t)b*(MA*MA*NEF_);
    const float4 a  = *(const float4*)(raw + base + (size_t)(i*MA + j)*NEF_);
    const float4 bt = *(const float4*)(raw + base + (size_t)(j*MA + i)*NEF_);
    float4 r;
    r.x = (a.x + bt.x)*0.5f;
    r.y = (a.y + bt.y)*0.5f;
    r.z = (a.z + bt.z)*0.5f;
    r.w = (a.w + bt.w)*0.5f;
    *(float4*)(outp + base + (size_t)(i*MA + j)*NEF_) = r;
}

// ---------------- launch ----------------

extern "C" void kernel_launch(void* const* d_in, const int* in_sizes, int n_in,
                              void* d_out, int out_size, void* d_ws, size_t ws_size,
                              hipStream_t stream){
    (void)in_sizes; (void)n_in; (void)out_size; (void)ws_size;
    const int*   x        = (const int*)d_in[0];
    const int*   eidx     = (const int*)d_in[1];
    const int*   eattr    = (const int*)d_in[2];
    const int*   batch    = (const int*)d_in[3];
    const float* eps      = (const float*)d_in[4];
    const float* node_emb = (const float*)d_in[5];
    const float* edge_emb = (const float*)d_in[6];
    const float* conv_w1  = (const float*)d_in[7];
    const float* conv_b1  = (const float*)d_in[8];
    const float* conv_w2  = (const float*)d_in[9];
    const float* conv_b2  = (const float*)d_in[10];
    const float* mu_w     = (const float*)d_in[11];
    const float* mu_b     = (const float*)d_in[12];
    const float* lv_w     = (const float*)d_in[13];
    const float* lv_b     = (const float*)d_in[14];
    const float* fw1      = (const float*)d_in[15];
    const float* fb1      = (const float*)d_in[16];
    const float* fw2      = (const float*)d_in[17];
    const float* fb2      = (const float*)d_in[18];
    const float* dn_w1    = (const float*)d_in[19];
    const float* dn_b1    = (const float*)d_in[20];
    const float* dn_w2    = (const float*)d_in[21];
    const float* dn_b2    = (const float*)d_in[22];
    const float* de_w1    = (const float*)d_in[23];
    const float* de_b1    = (const float*)d_in[24];
    const float* de_w2    = (const float*)d_in[25];
    const float* de_b2    = (const float*)d_in[26];

    float* out = (float*)d_out;
    const size_t off_node = 0;
    const size_t off_edge = (size_t)NB*MA*NNF_;
    const size_t off_mu   = off_edge + (size_t)NB*MA*MA*NEF_;
    const size_t off_lv   = off_mu + (size_t)NB*LAT;
    const size_t off_z0   = off_lv + (size_t)NB*LAT;
    const size_t off_zk   = off_z0 + (size_t)NB*LAT;
    const size_t off_sld  = off_zk + (size_t)NB*LAT;

    char* p = (char*)d_ws;
    auto alloc = [&](size_t bytes)->char*{ char* r = p; p += (bytes + 255) & ~(size_t)255; return r; };
    uint16_t* h_b   = (uint16_t*)alloc((size_t)N_NODES*HIDDEN*2);
    uint16_t* t_b   = (uint16_t*)alloc((size_t)N_NODES*HIDDEN*2);
    int*   offs   = (int*)  alloc((size_t)(N_NODES+1)*4);
    int*   cursor = (int*)  alloc((size_t)N_NODES*4);
    int*   epack  = (int*)  alloc((size_t)N_EDGES*4);
    int*   gstart = (int*)  alloc((size_t)NB*4);
    int*   gcnt   = (int*)  alloc((size_t)NB*4);
    uint32_t* hg_pk = (uint32_t*)alloc((size_t)NB*HIDDEN*4);
    float* mv       = (float*)alloc((size_t)NB*256*4);
    uint16_t* cw1b  = (uint16_t*)alloc((size_t)4*HIDDEN*HIDDEN*2);
    uint16_t* cw2b  = (uint16_t*)alloc((size_t)4*HIDDEN*HIDDEN*2);
    uint32_t* mvwpk = (uint32_t*)alloc((size_t)256*256*4);
    float*    mvb   = (float*)  alloc((size_t)256*4);
    uint16_t* w1hi  = (uint16_t*)alloc((size_t)NFLOWS*FHID*LAT*2);
    uint16_t* w1lo  = (uint16_t*)alloc((size_t)NFLOWS*FHID*LAT*2);
    uint16_t* w2hi  = (uint16_t*)alloc((size_t)NFLOWS*2*LAT*FHID*2);
    uint16_t* w2lo  = (uint16_t*)alloc((size_t)NFLOWS*2*LAT*FHID*2);
    uint16_t* dnw1b = (uint16_t*)alloc((size_t)256*LAT*2);
    uint16_t* dnw2b = (uint16_t*)alloc((size_t)MA*NNF_*256*2);
    uint16_t* dew1b = (uint16_t*)alloc((size_t)512*LAT*2);
    uint16_t* dew2b = (uint16_t*)alloc((size_t)MA*MA*NEF_*512*2);
    uint16_t* zkb   = (uint16_t*)alloc((size_t)NB*LAT*2);
    uint16_t* hnb   = (uint16_t*)alloc((size_t)NB*256*2);
    uint16_t* heb   = (uint16_t*)alloc((size_t)NB*512*2);
    float* edge_raw = (float*)alloc((size_t)NB*MA*MA*NEF_*4);

    const int* esrc = eidx;
    const int* edst = eidx + N_EDGES;

    // weight conversions
    k_cvt_b16<<<(4*HIDDEN*HIDDEN+255)/256, 256, 0, stream>>>(conv_w1, cw1b, 4*HIDDEN*HIDDEN);
    k_cvt_b16<<<(4*HIDDEN*HIDDEN+255)/256, 256, 0, stream>>>(conv_w2, cw2b, 4*HIDDEN*HIDDEN);
    k_cvt_mv<<<(256*256+255)/256, 256, 0, stream>>>(mu_w, mu_b, lv_w, lv_b, mvwpk, mvb);
    k_cvt_fw1s<<<(NFLOWS*FHID*LAT+255)/256, 256, 0, stream>>>(fw1, w1hi, w1lo);
    k_cvt_fw2s<<<(NFLOWS*2*LAT*FHID+255)/256, 256, 0, stream>>>(fw2, w2hi, w2lo);
    k_cvt_b16<<<(256*LAT+255)/256, 256, 0, stream>>>(dn_w1, dnw1b, 256*LAT);
    k_cvt_b16<<<(MA*NNF_*256+255)/256, 256, 0, stream>>>(dn_w2, dnw2b, MA*NNF_*256);
    k_cvt_b16<<<(512*LAT+255)/256, 256, 0, stream>>>(de_w1, dew1b, 512*LAT);
    k_cvt_b16<<<(MA*MA*NEF_*512+255)/256, 256, 0, stream>>>(de_w2, dew2b, MA*MA*NEF_*512);

    k_init   <<<(N_NODES+255)/256, 256, 0, stream>>>(cursor, gstart, gcnt);
    k_embed  <<<N_NODES, HIDDEN, 0, stream>>>(x, node_emb, h_b);
    k_deg    <<<(N_EDGES+255)/256, 256, 0, stream>>>(edst, cursor);
    k_meta   <<<(N_NODES+255)/256, 256, 0, stream>>>(batch, gstart, gcnt);
    k_scan   <<<1, 1024, 0, stream>>>(cursor, offs);
    k_scatter<<<(N_EDGES+255)/256, 256, 0, stream>>>(esrc, edst, eattr, offs, cursor, epack);

    const size_t SM32 = 32768, SM64 = 65536;
    for (int k=0;k<4;k++){
        k_aggr<<<N_NODES/4, 256, 0, stream>>>(h_b, edge_emb, offs, epack, t_b);
        k_conv2<<<N_NODES/64, 256, SM64, stream>>>(
            t_b,
            cw1b + (size_t)k*HIDDEN*HIDDEN, conv_b1 + (size_t)k*HIDDEN,
            cw2b + (size_t)k*HIDDEN*HIDDEN, conv_b2 + (size_t)k*HIDDEN,
            h_b);
    }

    k_pool<<<NB, HIDDEN, 0, stream>>>(h_b, gstart, gcnt, hg_pk);
    mfma_gemm<1,2><<<dim3(1, NB/64), 256, SM64, stream>>>(hg_pk, mvwpk, mvb, mv, NB, 256, HIDDEN, 0);
    k_z0<<<(NB*LAT+255)/256, 256, 0, stream>>>(mv, eps, out+off_mu, out+off_lv, out+off_z0);

    k_flows_mfma3<<<NB/16, 1024, 0, stream>>>(out+off_z0, w1hi, w1lo, fb1, w2hi, w2lo, fb2,
                                              out+off_zk, zkb, out+off_sld);

    // decoders (plain bf16 MFMA)
    mfma_gemm<0,1><<<dim3(1, NB/64), 256, SM32, stream>>>(zkb, dnw1b, dn_b1, hnb, NB, 256, LAT, 1);
    mfma_gemm<0,2><<<dim3(6, NB/64), 256, SM64, stream>>>(hnb, dnw2b, dn_b2, out+off_node, NB, MA*NNF_, 256, 0);
    mfma_gemm<0,1><<<dim3(2, NB/64), 256, SM32, stream>>>(zkb, dew1b, de_b1, heb, NB, 512, LAT, 1);
    mfma_gemm<0,2><<<dim3(23, NB/64), 256, SM64, stream>>>(heb, dew2b, de_b2, edge_raw, NB, MA*MA*NEF_, 512, 0);
    k_sym<<<(NB*MA*MA + 255)/256, 256, 0, stream>>>(edge_raw, out + off_edge);
}

// Round 8
// 643.258 us; speedup vs baseline: 2.0563x; 1.0313x over previous
//
#include <hip/hip_runtime.h>
#include <hip/hip_bf16.h>
#include <math.h>
#include <stdint.h>

#define N_NODES 49152
#define N_EDGES 196608
#define NB      2048
#define HIDDEN  256
#define LAT     128
#define FHID    256
#define NFLOWS  4
#define MA      38
#define NNF_    38
#define NEF_    4

typedef __attribute__((ext_vector_type(8))) short bf16x8;
typedef __attribute__((ext_vector_type(4))) float f32x4;

// ---------- bf16 helpers ----------
__device__ inline uint32_t bf16_rne_bits(float v){
    uint32_t u = __float_as_uint(v);
    u += 0x7fffu + ((u >> 16) & 1u);
    return u & 0xffff0000u;
}
__device__ inline uint16_t to_b16(float v){ return (uint16_t)(bf16_rne_bits(v) >> 16); }
__device__ inline float from_b16(uint16_t u){ return __uint_as_float((uint32_t)u << 16); }
__device__ inline uint32_t pack_hl(float v){
    uint32_t hu = bf16_rne_bits(v);
    float r = v - __uint_as_float(hu);
    uint32_t lu = bf16_rne_bits(r);
    return hu | (lu >> 16);
}

__device__ inline void unpack_frag(const uint4& x, const uint4& y, bf16x8& hi, bf16x8& lo){
    union { bf16x8 v; uint32_t u[4]; } H, L;
    H.u[0] = __builtin_amdgcn_perm(x.y, x.x, 0x07060302u);
    H.u[1] = __builtin_amdgcn_perm(x.w, x.z, 0x07060302u);
    H.u[2] = __builtin_amdgcn_perm(y.y, y.x, 0x07060302u);
    H.u[3] = __builtin_amdgcn_perm(y.w, y.z, 0x07060302u);
    L.u[0] = __builtin_amdgcn_perm(x.y, x.x, 0x05040100u);
    L.u[1] = __builtin_amdgcn_perm(x.w, x.z, 0x05040100u);
    L.u[2] = __builtin_amdgcn_perm(y.y, y.x, 0x05040100u);
    L.u[3] = __builtin_amdgcn_perm(y.w, y.z, 0x05040100u);
    hi = H.v; lo = L.v;
}

// ---------------- init / CSR build ----------------

__global__ void k_init(int* __restrict__ cursor, int* __restrict__ gstart, int* __restrict__ gcnt){
    int i = blockIdx.x*256 + threadIdx.x;
    if (i < N_NODES) cursor[i] = 0;
    if (i < NB){ gstart[i] = 0x7fffffff; gcnt[i] = 0; }
}

__global__ void k_embed(const int* __restrict__ x, const float* __restrict__ emb, uint16_t* __restrict__ h){
    int i = blockIdx.x; int c = threadIdx.x;
    h[(size_t)i*HIDDEN + c] = to_b16(emb[x[i]*HIDDEN + c]);
}

__global__ void k_deg(const int* __restrict__ dst, int* __restrict__ cursor){
    int e = blockIdx.x*256 + threadIdx.x;
    if (e < N_EDGES) atomicAdd(&cursor[dst[e]], 1);
}

__global__ void k_meta(const int* __restrict__ batch, int* __restrict__ gstart, int* __restrict__ gcnt){
    int i = blockIdx.x*256 + threadIdx.x;
    if (i < N_NODES){ int b = batch[i]; atomicMin(&gstart[b], i); atomicAdd(&gcnt[b], 1); }
}

__global__ __launch_bounds__(1024) void k_scan(int* __restrict__ cursor, int* __restrict__ offs){
    __shared__ int part[1024];
    const int tid = threadIdx.x;
    const int CH = N_NODES/1024; // 48
    int local[48];
    int s = 0;
    int base = tid*CH;
    for (int j=0;j<CH;j++){ local[j] = cursor[base+j]; s += local[j]; }
    part[tid] = s;
    __syncthreads();
    for (int off=1; off<1024; off<<=1){
        int v = (tid>=off) ? part[tid-off] : 0;
        __syncthreads();
        part[tid] += v;
        __syncthreads();
    }
    int excl = (tid==0) ? 0 : part[tid-1];
    for (int j=0;j<CH;j++){ offs[base+j] = excl; excl += local[j]; cursor[base+j] = 0; }
    if (tid == 1023) offs[N_NODES] = excl;
}

__global__ void k_scatter(const int* __restrict__ src, const int* __restrict__ dst, const int* __restrict__ attr,
                          const int* __restrict__ offs, int* __restrict__ cursor, int* __restrict__ epack){
    int e = blockIdx.x*256 + threadIdx.x;
    if (e < N_EDGES){
        int d = dst[e];
        int pos = atomicAdd(&cursor[d], 1);
        epack[offs[d] + pos] = (src[e] & 0xffff) | (attr[e] << 16);
    }
}

// ---------------- message aggregation: wave-per-node, 4-edge MLP chunks ----------------

__global__ __launch_bounds__(256) void k_aggr(const uint16_t* __restrict__ h, const float* __restrict__ eemb,
                                              const int* __restrict__ offs, const int* __restrict__ epack,
                                              uint16_t* __restrict__ t){
    __shared__ float sE[NEF_*HIDDEN];
    const int tid  = threadIdx.x;
    #pragma unroll
    for (int q=0;q<NEF_;q++) sE[q*256 + tid] = eemb[q*256 + tid];
    __syncthreads();

    const int wave = tid >> 6;
    const int lane = tid & 63;
    const int node = blockIdx.x*4 + wave;
    const int c4   = lane*4;

    uint2 hu = *(const uint2*)(h + (size_t)node*HIDDEN + c4);
    float4 acc;
    acc.x = __uint_as_float(hu.x << 16);
    acc.y = __uint_as_float(hu.x & 0xffff0000u);
    acc.z = __uint_as_float(hu.y << 16);
    acc.w = __uint_as_float(hu.y & 0xffff0000u);

    const int e0 = offs[node], e1 = offs[node+1];
    for (int j = e0; j < e1; j += 4){
        int p0 = epack[j];
        int p1 = (j+1 < e1) ? epack[j+1] : p0;
        int p2 = (j+2 < e1) ? epack[j+2] : p0;
        int p3 = (j+3 < e1) ? epack[j+3] : p0;
        uint2 g0 = *(const uint2*)(h + (size_t)(p0 & 0xffff)*HIDDEN + c4);
        uint2 g1 = *(const uint2*)(h + (size_t)(p1 & 0xffff)*HIDDEN + c4);
        uint2 g2 = *(const uint2*)(h + (size_t)(p2 & 0xffff)*HIDDEN + c4);
        uint2 g3 = *(const uint2*)(h + (size_t)(p3 & 0xffff)*HIDDEN + c4);
        {
            const float4 ev = *(const float4*)&sE[(p0 >> 16)*HIDDEN + c4];
            acc.x += fmaxf(__uint_as_float(g0.x << 16)        + ev.x, 0.f);
            acc.y += fmaxf(__uint_as_float(g0.x & 0xffff0000u) + ev.y, 0.f);
            acc.z += fmaxf(__uint_as_float(g0.y << 16)        + ev.z, 0.f);
            acc.w += fmaxf(__uint_as_float(g0.y & 0xffff0000u) + ev.w, 0.f);
        }
        if (j+1 < e1){
            const float4 ev = *(const float4*)&sE[(p1 >> 16)*HIDDEN + c4];
            acc.x += fmaxf(__uint_as_float(g1.x << 16)        + ev.x, 0.f);
            acc.y += fmaxf(__uint_as_float(g1.x & 0xffff0000u) + ev.y, 0.f);
            acc.z += fmaxf(__uint_as_float(g1.y << 16)        + ev.z, 0.f);
            acc.w += fmaxf(__uint_as_float(g1.y & 0xffff0000u) + ev.w, 0.f);
        }
        if (j+2 < e1){
            const float4 ev = *(const float4*)&sE[(p2 >> 16)*HIDDEN + c4];
            acc.x += fmaxf(__uint_as_float(g2.x << 16)        + ev.x, 0.f);
            acc.y += fmaxf(__uint_as_float(g2.x & 0xffff0000u) + ev.y, 0.f);
            acc.z += fmaxf(__uint_as_float(g2.y << 16)        + ev.z, 0.f);
            acc.w += fmaxf(__uint_as_float(g2.y & 0xffff0000u) + ev.w, 0.f);
        }
        if (j+3 < e1){
            const float4 ev = *(const float4*)&sE[(p3 >> 16)*HIDDEN + c4];
            acc.x += fmaxf(__uint_as_float(g3.x << 16)        + ev.x, 0.f);
            acc.y += fmaxf(__uint_as_float(g3.x & 0xffff0000u) + ev.y, 0.f);
            acc.z += fmaxf(__uint_as_float(g3.y << 16)        + ev.z, 0.f);
            acc.w += fmaxf(__uint_as_float(g3.y & 0xffff0000u) + ev.w, 0.f);
        }
    }

    uint2 o;
    o.x = (uint32_t)to_b16(acc.x) | ((uint32_t)to_b16(acc.y) << 16);
    o.y = (uint32_t)to_b16(acc.z) | ((uint32_t)to_b16(acc.w) << 16);
    *(uint2*)(t + (size_t)node*HIDDEN + c4) = o;
}

// ---------------- weight / activation converters ----------------

__global__ void k_cvt_b16(const float* __restrict__ s, uint16_t* __restrict__ d, int n){
    int i = blockIdx.x*256 + threadIdx.x;
    if (i < n) d[i] = to_b16(s[i]);
}
__global__ void k_cvt_fw1s(const float* __restrict__ w, uint16_t* __restrict__ hi, uint16_t* __restrict__ lo){
    int i = blockIdx.x*256 + threadIdx.x;
    if (i >= NFLOWS*FHID*LAT) return;
    int o = (i >> 7) & 255;
    int kk = i & 127;
    float v = (kk <= (o % 127)) ? w[i] : 0.f;
    uint32_t h = bf16_rne_bits(v);
    hi[i] = (uint16_t)(h >> 16);
    lo[i] = (uint16_t)(bf16_rne_bits(v - __uint_as_float(h)) >> 16);
}
__global__ void k_cvt_fw2s(const float* __restrict__ w, uint16_t* __restrict__ hi, uint16_t* __restrict__ lo){
    int i = blockIdx.x*256 + threadIdx.x;
    if (i >= NFLOWS*2*LAT*FHID) return;
    int o = (i >> 8) & 255;
    int hh = i & 255;
    float v = ((hh % 127) < (o & 127)) ? w[i] : 0.f;
    uint32_t h = bf16_rne_bits(v);
    hi[i] = (uint16_t)(h >> 16);
    lo[i] = (uint16_t)(bf16_rne_bits(v - __uint_as_float(h)) >> 16);
}
__global__ void k_cvt_mv(const float* __restrict__ mu_w, const float* __restrict__ mu_b,
                         const float* __restrict__ lv_w, const float* __restrict__ lv_b,
                         uint32_t* __restrict__ wpk, float* __restrict__ bpk){
    int i = blockIdx.x*256 + threadIdx.x;
    if (i < 256*256){
        int o = i >> 8, k2 = i & 255;
        float v = (o < 128) ? mu_w[o*256 + k2] : lv_w[(o-128)*256 + k2];
        wpk[i] = pack_hl(v);
    }
    if (i < 256) bpk[i] = (i < 128) ? mu_b[i] : lv_b[i-128];
}

// ---------------- fused conv: h_out = relu(relu(A@W1^T+b1)@W2^T+b2) ----------------
// 2-deep register double-buffer on weight loads (latency hiding).

__global__ __launch_bounds__(256) void k_conv2(
    const uint16_t* __restrict__ A,
    const uint16_t* __restrict__ W1, const float* __restrict__ B1,
    const uint16_t* __restrict__ W2, const float* __restrict__ B2,
    uint16_t* __restrict__ C)
{
    extern __shared__ __align__(16) char smem[];          // [0,32KB) stage/epilogue
    uint16_t* h1 = (uint16_t*)(smem + 32768);             // [32KB,64KB) h1 swizzled
    const int tid  = threadIdx.x;
    const int wave = tid >> 6;
    const int lane = tid & 63;
    const int l15  = lane & 15;
    const int lq   = lane >> 4;
    const int l7   = lane & 7;
    const int row0 = blockIdx.x * 64;

    // stage A
    #pragma unroll
    for (int it = 0; it < 8; ++it) {
        int s  = it*256 + wave*64 + lane;
        int m  = s >> 5;
        int gl = (s & 31) ^ (m & 7);
        const char* gp = (const char*)A + ((size_t)(row0+m)*HIDDEN)*2 + gl*16;
        __builtin_amdgcn_global_load_lds(
            (const __attribute__((address_space(1))) uint32_t*)gp,
            (__attribute__((address_space(3))) uint32_t*)(smem + (it*256 + wave*64 + lane)*16),
            16, 0, 0);
    }
    __syncthreads();

    // ---- GEMM1 ----
    f32x4 acc[4][4];
    #pragma unroll
    for (int mt=0;mt<4;mt++)
        #pragma unroll
        for (int nt=0;nt<4;nt++) acc[mt][nt] = (f32x4)(0.f);

    {
        bf16x8 bw[2][4];
        #pragma unroll
        for (int nt=0;nt<4;nt++)
            bw[0][nt] = *(const bf16x8*)(W1 + (size_t)(wave*64 + nt*16 + l15)*HIDDEN + lq*8);
        #pragma unroll
        for (int kc = 0; kc < 8; ++kc){
            int cur = kc & 1, nxt = cur ^ 1;
            if (kc < 7){
                #pragma unroll
                for (int nt=0;nt<4;nt++)
                    bw[nxt][nt] = *(const bf16x8*)(W1 + (size_t)(wave*64 + nt*16 + l15)*HIDDEN + (kc+1)*32 + lq*8);
            }
            #pragma unroll
            for (int mt=0;mt<4;mt++){
                const int mb = (mt*16 + l15) << 5;
                int g = kc*4 + lq;
                bf16x8 a = *(const bf16x8*)(smem + (size_t)(mb + (g ^ l7))*16);
                #pragma unroll
                for (int nt=0;nt<4;nt++)
                    acc[mt][nt] = __builtin_amdgcn_mfma_f32_16x16x32_bf16(a, bw[cur][nt], acc[mt][nt], 0, 0, 0);
            }
        }
    }

    // epilogue1 -> h1 (granule-swizzled)
    #pragma unroll
    for (int mt=0;mt<4;mt++){
        #pragma unroll
        for (int nt=0;nt<4;nt++){
            int col = wave*64 + nt*16 + l15;
            float bb = B1[col];
            #pragma unroll
            for (int reg=0;reg<4;reg++){
                int r = mt*16 + lq*4 + reg;
                float v = fmaxf(acc[mt][nt][reg] + bb, 0.f);
                h1[(r*32 + ((col>>3) ^ (r&7)))*8 + (col&7)] = to_b16(v);
            }
        }
    }
    __syncthreads();

    // ---- GEMM2 ----
    #pragma unroll
    for (int mt=0;mt<4;mt++)
        #pragma unroll
        for (int nt=0;nt<4;nt++) acc[mt][nt] = (f32x4)(0.f);

    {
        bf16x8 bw[2][4];
        #pragma unroll
        for (int nt=0;nt<4;nt++)
            bw[0][nt] = *(const bf16x8*)(W2 + (size_t)(wave*64 + nt*16 + l15)*HIDDEN + lq*8);
        #pragma unroll
        for (int kc = 0; kc < 8; ++kc){
            int cur = kc & 1, nxt = cur ^ 1;
            if (kc < 7){
                #pragma unroll
                for (int nt=0;nt<4;nt++)
                    bw[nxt][nt] = *(const bf16x8*)(W2 + (size_t)(wave*64 + nt*16 + l15)*HIDDEN + (kc+1)*32 + lq*8);
            }
            #pragma unroll
            for (int mt=0;mt<4;mt++){
                int m = mt*16 + l15;
                bf16x8 a = *(const bf16x8*)(h1 + (size_t)(m*32 + ((kc*4 + lq) ^ (m & 7)))*8);
                #pragma unroll
                for (int nt=0;nt<4;nt++)
                    acc[mt][nt] = __builtin_amdgcn_mfma_f32_16x16x32_bf16(a, bw[cur][nt], acc[mt][nt], 0, 0, 0);
            }
        }
    }
    __syncthreads();

    // epilogue2
    uint16_t* rs = (uint16_t*)(smem + wave*8192);
    #pragma unroll
    for (int mt=0;mt<4;mt++){
        #pragma unroll
        for (int nt=0;nt<4;nt++){
            int cl = nt*16 + l15;
            float bb = B2[wave*64 + cl];
            #pragma unroll
            for (int reg=0;reg<4;reg++){
                int r = mt*16 + lq*4 + reg;
                rs[r*64 + cl] = to_b16(fmaxf(acc[mt][nt][reg] + bb, 0.f));
            }
        }
    }
    __syncthreads();
    #pragma unroll
    for (int it = 0; it < 32; ++it){
        int r   = it*2 + (lane >> 5);
        int clp = lane & 31;
        int col = wave*64 + clp*2;
        *(uint32_t*)(C + (size_t)(row0+r)*HIDDEN + col) = *(const uint32_t*)(rs + r*64 + clp*2);
    }
}

// ---------------- MFMA GEMM (mu/lv + decoders) ----------------

template<int SPLIT, int OUTM>
__global__ __launch_bounds__(256) void mfma_gemm(
    const void* __restrict__ Ap, const void* __restrict__ Wp,
    const float* __restrict__ bias, void* __restrict__ Cp,
    int M, int N, int K, int relu)
{
    extern __shared__ __align__(16) char smem[];
    const int tid  = threadIdx.x;
    const int wave = tid >> 6;
    const int lane = tid & 63;
    const int l15  = lane & 15;
    const int lq   = lane >> 4;
    const int l7   = lane & 7;
    const int row0 = blockIdx.y * 64;
    const int n0   = blockIdx.x * 256;
    const int ELB  = SPLIT ? 4 : 2;
    const int KC   = (K < 256) ? K : 256;
    const int GR   = (KC * ELB) >> 4;
    const int rsh  = (GR == 64) ? 6 : ((GR == 32) ? 5 : 4);

    f32x4 acc[4][4];
    #pragma unroll
    for (int mt=0;mt<4;mt++)
        #pragma unroll
        for (int nt=0;nt<4;nt++) acc[mt][nt] = (f32x4)(0.f);

    const char* Ab = (const char*)Ap;
    const char* Wb = (const char*)Wp;

    for (int kbase = 0; kbase < K; kbase += KC) {
        const int rounds = GR >> 2;
        for (int it = 0; it < rounds; ++it) {
            int sbase = it*256 + wave*64;
            int s  = sbase + lane;
            int m  = s >> rsh;
            int gl = (s & (GR-1)) ^ (m & 7);
            const char* gp = Ab + ((size_t)(row0+m)*K + kbase)*ELB + gl*16;
            __builtin_amdgcn_global_load_lds(
                (const __attribute__((address_space(1))) uint32_t*)gp,
                (__attribute__((address_space(3))) uint32_t*)(smem + sbase*16),
                16, 0, 0);
        }
        __syncthreads();

        for (int kc = 0; kc < (KC >> 5); ++kc) {
            bf16x8 bhi[4], blo[4];
            #pragma unroll
            for (int nt=0;nt<4;nt++){
                int n = n0 + wave*64 + nt*16 + l15;
                if (n >= N) n = N-1;
                if (SPLIT){
                    const uint4* wp4 = (const uint4*)(Wb + ((size_t)n*K + kbase + kc*32 + lq*8)*4);
                    uint4 xx = wp4[0], yy = wp4[1];
                    unpack_frag(xx, yy, bhi[nt], blo[nt]);
                } else {
                    bhi[nt] = *(const bf16x8*)(Wb + ((size_t)n*K + kbase + kc*32 + lq*8)*2);
                }
            }
            #pragma unroll
            for (int mt=0;mt<4;mt++){
                const int mb = (mt*16 + l15) << rsh;
                if (SPLIT){
                    int g0 = kc*8 + lq*2;
                    uint4 xx = *(const uint4*)(smem + (size_t)(mb + ((g0  ) ^ l7))*16);
                    uint4 yy = *(const uint4*)(smem + (size_t)(mb + ((g0+1) ^ l7))*16);
                    bf16x8 ahi, alo;
                    unpack_frag(xx, yy, ahi, alo);
                    #pragma unroll
                    for (int nt=0;nt<4;nt++){
                        acc[mt][nt] = __builtin_amdgcn_mfma_f32_16x16x32_bf16(ahi, bhi[nt], acc[mt][nt], 0, 0, 0);
                        acc[mt][nt] = __builtin_amdgcn_mfma_f32_16x16x32_bf16(ahi, blo[nt], acc[mt][nt], 0, 0, 0);
                        acc[mt][nt] = __builtin_amdgcn_mfma_f32_16x16x32_bf16(alo, bhi[nt], acc[mt][nt], 0, 0, 0);
                    }
                } else {
                    int g = kc*4 + lq;
                    bf16x8 a = *(const bf16x8*)(smem + (size_t)(mb + (g ^ l7))*16);
                    #pragma unroll
                    for (int nt=0;nt<4;nt++){
                        acc[mt][nt] = __builtin_amdgcn_mfma_f32_16x16x32_bf16(a, bhi[nt], acc[mt][nt], 0, 0, 0);
                    }
                }
            }
        }
        __syncthreads();
    }

    const int ES = (OUTM == 1) ? 2 : 4;
    char* rs = smem + wave*(64*64*ES);
    const int colbase = n0 + wave*64;
    #pragma unroll
    for (int mt=0;mt<4;mt++){
        #pragma unroll
        for (int nt=0;nt<4;nt++){
            int cl = nt*16 + l15;
            int col = colbase + cl;
            float bb = bias[col < N ? col : N-1];
            #pragma unroll
            for (int reg=0;reg<4;reg++){
                int r = mt*16 + lq*4 + reg;
                float v = acc[mt][nt][reg] + bb;
                if (relu) v = fmaxf(v, 0.f);
                if (OUTM == 1) ((uint16_t*)rs)[r*64 + cl] = to_b16(v);
                else           ((float*)rs)[r*64 + cl] = v;
            }
        }
    }
    __syncthreads();
    for (int it = 0; it < 32; ++it) {
        int r   = it*2 + (lane>>5);
        int clp = lane & 31;
        int col = colbase + clp*2;
        if (col < N){
            if (OUTM == 1){
                uint32_t d = *(const uint32_t*)((const uint16_t*)rs + r*64 + clp*2);
                *(uint32_t*)((char*)Cp + ((size_t)(row0+r)*N + col)*2) = d;
            } else {
                float2 d = *(const float2*)((const float*)rs + r*64 + clp*2);
                *(float2*)((float*)Cp + (size_t)(row0+r)*N + col) = d;
            }
        }
    }
}

// ---------------- pooling + z0 elementwise ----------------

__global__ void k_pool(const uint16_t* __restrict__ h, const int* __restrict__ gstart,
                       const int* __restrict__ gcnt, uint32_t* __restrict__ hg){
    int b = blockIdx.x; int c = threadIdx.x;
    int s0 = gstart[b]; int n = gcnt[b];
    float s = 0.f;
    for (int j=0;j<n;j++) s += from_b16(h[(size_t)(s0+j)*HIDDEN + c]);
    hg[(size_t)b*HIDDEN + c] = pack_hl(s);
}

__global__ void k_z0(const float* __restrict__ mv, const float* __restrict__ eps,
                     float* __restrict__ mu_o, float* __restrict__ lv_o, float* __restrict__ z0_o){
    int i = blockIdx.x*256 + threadIdx.x;
    if (i >= NB*LAT) return;
    int b = i >> 7, l = i & 127;
    float m = mv[(size_t)b*256 + l];
    float v = mv[(size_t)b*256 + l + 128];
    mu_o[i] = m;
    lv_o[i] = v;
    z0_o[i] = m + eps[i]*expf(0.5f*v);
}

// ---------------- fused MFMA flows v4: full-flow register weight preload ----------------
// 128 blocks x 1024 threads (16 waves); 16 graphs/block; wave w owns output cols
// [16w,16w+16). All 24 weight vectors for the flow are issued upfront -> one
// latency exposure per flow instead of 12.

__global__ __launch_bounds__(1024) void k_flows_mfma4(
    const float* __restrict__ z0,
    const uint16_t* __restrict__ w1hi, const uint16_t* __restrict__ w1lo, const float* __restrict__ fb1,
    const uint16_t* __restrict__ w2hi, const uint16_t* __restrict__ w2lo, const float* __restrict__ fb2,
    float* __restrict__ zK, uint16_t* __restrict__ zkb, float* __restrict__ sld)
{
    __shared__ __align__(16) uint16_t zhi[16][136];
    __shared__ __align__(16) uint16_t zlo[16][136];
    __shared__ __align__(16) uint16_t h1hi[16][280];
    __shared__ __align__(16) uint16_t h1lo[16][280];
    __shared__ __align__(16) float    oS[16][268];
    const int tid  = threadIdx.x;
    const int wave = tid >> 6;
    const int lane = tid & 63;
    const int l15  = lane & 15;
    const int lq   = lane >> 4;
    const int g0   = blockIdx.x * 16;
    const int col  = wave*16 + l15;

    #pragma unroll
    for (int q=0;q<2;q++){
        int idx = q*1024 + tid;
        int r = idx >> 7, l = idx & 127;
        float v = z0[(size_t)(g0 + r)*LAT + l];
        uint32_t h = bf16_rne_bits(v);
        zhi[r][l] = (uint16_t)(h >> 16);
        zlo[r][l] = (uint16_t)(bf16_rne_bits(v - __uint_as_float(h)) >> 16);
    }
    float ldacc = 0.f;
    __syncthreads();

    for (int kf=0; kf<NFLOWS; kf++){
        const uint16_t* W1h = w1hi + (size_t)kf*FHID*LAT;
        const uint16_t* W1l = w1lo + (size_t)kf*FHID*LAT;
        const float*    b1  = fb1 + kf*FHID;
        const uint16_t* W2h = w2hi + (size_t)kf*2*LAT*FHID;
        const uint16_t* W2l = w2lo + (size_t)kf*2*LAT*FHID;
        const float*    b2  = fb2 + kf*2*LAT;

        // ---- preload ALL weights for this flow (24 x 16B loads in flight) ----
        bf16x8 v1h[4], v1l[4], v2h[8], v2l[8];
        #pragma unroll
        for (int kc=0;kc<4;kc++){
            v1h[kc] = *(const bf16x8*)(W1h + (size_t)col*LAT + kc*32 + lq*8);
            v1l[kc] = *(const bf16x8*)(W1l + (size_t)col*LAT + kc*32 + lq*8);
        }
        #pragma unroll
        for (int kc=0;kc<8;kc++){
            v2h[kc] = *(const bf16x8*)(W2h + (size_t)col*FHID + kc*32 + lq*8);
            v2l[kc] = *(const bf16x8*)(W2l + (size_t)col*FHID + kc*32 + lq*8);
        }

        // ---- GEMM1: h1[16x256] = relu(z[16x128] @ w1m^T + b1) ----
        {
            f32x4 acc = (f32x4)(0.f);
            #pragma unroll
            for (int kc=0;kc<4;kc++){
                bf16x8 ah = *(const bf16x8*)&zhi[l15][kc*32 + lq*8];
                bf16x8 al = *(const bf16x8*)&zlo[l15][kc*32 + lq*8];
                acc = __builtin_amdgcn_mfma_f32_16x16x32_bf16(ah, v1h[kc], acc, 0, 0, 0);
                acc = __builtin_amdgcn_mfma_f32_16x16x32_bf16(ah, v1l[kc], acc, 0, 0, 0);
                acc = __builtin_amdgcn_mfma_f32_16x16x32_bf16(al, v1h[kc], acc, 0, 0, 0);
            }
            float bb = b1[col];
            #pragma unroll
            for (int reg=0;reg<4;reg++){
                int r = lq*4 + reg;
                float v = fmaxf(acc[reg] + bb, 0.f);
                uint32_t h = bf16_rne_bits(v);
                h1hi[r][col] = (uint16_t)(h >> 16);
                h1lo[r][col] = (uint16_t)(bf16_rne_bits(v - __uint_as_float(h)) >> 16);
            }
        }
        __syncthreads();

        // ---- GEMM2: out[16x256] = h1 @ w2m^T + b2 ----
        {
            f32x4 acc = (f32x4)(0.f);
            #pragma unroll
            for (int kc=0;kc<8;kc++){
                bf16x8 ah = *(const bf16x8*)&h1hi[l15][kc*32 + lq*8];
                bf16x8 al = *(const bf16x8*)&h1lo[l15][kc*32 + lq*8];
                acc = __builtin_amdgcn_mfma_f32_16x16x32_bf16(ah, v2h[kc], acc, 0, 0, 0);
                acc = __builtin_amdgcn_mfma_f32_16x16x32_bf16(ah, v2l[kc], acc, 0, 0, 0);
                acc = __builtin_amdgcn_mfma_f32_16x16x32_bf16(al, v2h[kc], acc, 0, 0, 0);
            }
            float bb = b2[col];
            #pragma unroll
            for (int reg=0;reg<4;reg++)
                oS[lq*4 + reg][col] = acc[reg] + bb;
        }
        __syncthreads();

        // ---- z update + log-det: wave w handles row w, 2 cols/lane ----
        {
            const int r = wave;
            float ldp = 0.f;
            #pragma unroll
            for (int j=0;j<2;j++){
                int l = lane + j*64;
                float m = oS[r][l];
                float s = oS[r][l + 128];
                float g = 1.f/(1.f + expf(-s));
                float zv = __uint_as_float((uint32_t)zhi[r][l] << 16)
                         + __uint_as_float((uint32_t)zlo[r][l] << 16);
                float zn = g*zv + (1.f - g)*m;
                uint32_t h = bf16_rne_bits(zn);
                zhi[r][l] = (uint16_t)(h >> 16);
                zlo[r][l] = (uint16_t)(bf16_rne_bits(zn - __uint_as_float(h)) >> 16);
                ldp += logf(g + 1e-8f);
            }
            #pragma unroll
            for (int off=1; off<64; off<<=1) ldp += __shfl_xor(ldp, off);
            ldacc += ldp;
        }
        __syncthreads();
    }

    #pragma unroll
    for (int q=0;q<2;q++){
        int idx = q*1024 + tid;
        int r = idx >> 7, l = idx & 127;
        uint32_t h = (uint32_t)zhi[r][l] << 16;
        float zv = __uint_as_float(h) + __uint_as_float((uint32_t)zlo[r][l] << 16);
        zK[(size_t)(g0+r)*LAT + l] = zv;
        zkb[(size_t)(g0+r)*LAT + l] = (uint16_t)(h >> 16);
    }
    if (lane == 0) sld[g0 + wave] = ldacc;
}

// ---------------- edge-logits symmetrize ----------------

__global__ void k_sym(const float* __restrict__ raw, float* __restrict__ outp){
    int idx = blockIdx.x*256 + threadIdx.x;
    const int total = NB*MA*MA;
    if (idx >= total) return;
    int b = idx / (MA*MA);
    int rem = idx - b*(MA*MA);
    int i = rem / MA;
    int j = rem - i*MA;
    const size_t base = (size_t)b*(MA*MA*NEF_);
    const float4 a  = *(const float4*)(raw + base + (size_t)(i*MA + j)*NEF_);
    const float4 bt = *(const float4*)(raw + base + (size_t)(j*MA + i)*NEF_);
    float4 r;
    r.x = (a.x + bt.x)*0.5f;
    r.y = (a.y + bt.y)*0.5f;
    r.z = (a.z + bt.z)*0.5f;
    r.w = (a.w + bt.w)*0.5f;
    *(float4*)(outp + base + (size_t)(i*MA + j)*NEF_) = r;
}

// ---------------- launch ----------------

extern "C" void kernel_launch(void* const* d_in, const int* in_sizes, int n_in,
                              void* d_out, int out_size, void* d_ws, size_t ws_size,
                              hipStream_t stream){
    (void)in_sizes; (void)n_in; (void)out_size; (void)ws_size;
    const int*   x        = (const int*)d_in[0];
    const int*   eidx     = (const int*)d_in[1];
    const int*   eattr    = (const int*)d_in[2];
    const int*   batch    = (const int*)d_in[3];
    const float* eps      = (const float*)d_in[4];
    const float* node_emb = (const float*)d_in[5];
    const float* edge_emb = (const float*)d_in[6];
    const float* conv_w1  = (const float*)d_in[7];
    const float* conv_b1  = (const float*)d_in[8];
    const float* conv_w2  = (const float*)d_in[9];
    const float* conv_b2  = (const float*)d_in[10];
    const float* mu_w     = (const float*)d_in[11];
    const float* mu_b     = (const float*)d_in[12];
    const float* lv_w     = (const float*)d_in[13];
    const float* lv_b     = (const float*)d_in[14];
    const float* fw1      = (const float*)d_in[15];
    const float* fb1      = (const float*)d_in[16];
    const float* fw2      = (const float*)d_in[17];
    const float* fb2      = (const float*)d_in[18];
    const float* dn_w1    = (const float*)d_in[19];
    const float* dn_b1    = (const float*)d_in[20];
    const float* dn_w2    = (const float*)d_in[21];
    const float* dn_b2    = (const float*)d_in[22];
    const float* de_w1    = (const float*)d_in[23];
    const float* de_b1    = (const float*)d_in[24];
    const float* de_w2    = (const float*)d_in[25];
    const float* de_b2    = (const float*)d_in[26];

    float* out = (float*)d_out;
    const size_t off_node = 0;
    const size_t off_edge = (size_t)NB*MA*NNF_;
    const size_t off_mu   = off_edge + (size_t)NB*MA*MA*NEF_;
    const size_t off_lv   = off_mu + (size_t)NB*LAT;
    const size_t off_z0   = off_lv + (size_t)NB*LAT;
    const size_t off_zk   = off_z0 + (size_t)NB*LAT;
    const size_t off_sld  = off_zk + (size_t)NB*LAT;

    char* p = (char*)d_ws;
    auto alloc = [&](size_t bytes)->char*{ char* r = p; p += (bytes + 255) & ~(size_t)255; return r; };
    uint16_t* h_b   = (uint16_t*)alloc((size_t)N_NODES*HIDDEN*2);
    uint16_t* t_b   = (uint16_t*)alloc((size_t)N_NODES*HIDDEN*2);
    int*   offs   = (int*)  alloc((size_t)(N_NODES+1)*4);
    int*   cursor = (int*)  alloc((size_t)N_NODES*4);
    int*   epack  = (int*)  alloc((size_t)N_EDGES*4);
    int*   gstart = (int*)  alloc((size_t)NB*4);
    int*   gcnt   = (int*)  alloc((size_t)NB*4);
    uint32_t* hg_pk = (uint32_t*)alloc((size_t)NB*HIDDEN*4);
    float* mv       = (float*)alloc((size_t)NB*256*4);
    uint16_t* cw1b  = (uint16_t*)alloc((size_t)4*HIDDEN*HIDDEN*2);
    uint16_t* cw2b  = (uint16_t*)alloc((size_t)4*HIDDEN*HIDDEN*2);
    uint32_t* mvwpk = (uint32_t*)alloc((size_t)256*256*4);
    float*    mvb   = (float*)  alloc((size_t)256*4);
    uint16_t* w1hi  = (uint16_t*)alloc((size_t)NFLOWS*FHID*LAT*2);
    uint16_t* w1lo  = (uint16_t*)alloc((size_t)NFLOWS*FHID*LAT*2);
    uint16_t* w2hi  = (uint16_t*)alloc((size_t)NFLOWS*2*LAT*FHID*2);
    uint16_t* w2lo  = (uint16_t*)alloc((size_t)NFLOWS*2*LAT*FHID*2);
    uint16_t* dnw1b = (uint16_t*)alloc((size_t)256*LAT*2);
    uint16_t* dnw2b = (uint16_t*)alloc((size_t)MA*NNF_*256*2);
    uint16_t* dew1b = (uint16_t*)alloc((size_t)512*LAT*2);
    uint16_t* dew2b = (uint16_t*)alloc((size_t)MA*MA*NEF_*512*2);
    uint16_t* zkb   = (uint16_t*)alloc((size_t)NB*LAT*2);
    uint16_t* hnb   = (uint16_t*)alloc((size_t)NB*256*2);
    uint16_t* heb   = (uint16_t*)alloc((size_t)NB*512*2);
    float* edge_raw = (float*)alloc((size_t)NB*MA*MA*NEF_*4);

    const int* esrc = eidx;
    const int* edst = eidx + N_EDGES;

    // weight conversions
    k_cvt_b16<<<(4*HIDDEN*HIDDEN+255)/256, 256, 0, stream>>>(conv_w1, cw1b, 4*HIDDEN*HIDDEN);
    k_cvt_b16<<<(4*HIDDEN*HIDDEN+255)/256, 256, 0, stream>>>(conv_w2, cw2b, 4*HIDDEN*HIDDEN);
    k_cvt_mv<<<(256*256+255)/256, 256, 0, stream>>>(mu_w, mu_b, lv_w, lv_b, mvwpk, mvb);
    k_cvt_fw1s<<<(NFLOWS*FHID*LAT+255)/256, 256, 0, stream>>>(fw1, w1hi, w1lo);
    k_cvt_fw2s<<<(NFLOWS*2*LAT*FHID+255)/256, 256, 0, stream>>>(fw2, w2hi, w2lo);
    k_cvt_b16<<<(256*LAT+255)/256, 256, 0, stream>>>(dn_w1, dnw1b, 256*LAT);
    k_cvt_b16<<<(MA*NNF_*256+255)/256, 256, 0, stream>>>(dn_w2, dnw2b, MA*NNF_*256);
    k_cvt_b16<<<(512*LAT+255)/256, 256, 0, stream>>>(de_w1, dew1b, 512*LAT);
    k_cvt_b16<<<(MA*MA*NEF_*512+255)/256, 256, 0, stream>>>(de_w2, dew2b, MA*MA*NEF_*512);

    k_init   <<<(N_NODES+255)/256, 256, 0, stream>>>(cursor, gstart, gcnt);
    k_embed  <<<N_NODES, HIDDEN, 0, stream>>>(x, node_emb, h_b);
    k_deg    <<<(N_EDGES+255)/256, 256, 0, stream>>>(edst, cursor);
    k_meta   <<<(N_NODES+255)/256, 256, 0, stream>>>(batch, gstart, gcnt);
    k_scan   <<<1, 1024, 0, stream>>>(cursor, offs);
    k_scatter<<<(N_EDGES+255)/256, 256, 0, stream>>>(esrc, edst, eattr, offs, cursor, epack);

    const size_t SM32 = 32768, SM64 = 65536;
    for (int k=0;k<4;k++){
        k_aggr<<<N_NODES/4, 256, 0, stream>>>(h_b, edge_emb, offs, epack, t_b);
        k_conv2<<<N_NODES/64, 256, SM64, stream>>>(
            t_b,
            cw1b + (size_t)k*HIDDEN*HIDDEN, conv_b1 + (size_t)k*HIDDEN,
            cw2b + (size_t)k*HIDDEN*HIDDEN, conv_b2 + (size_t)k*HIDDEN,
            h_b);
    }

    k_pool<<<NB, HIDDEN, 0, stream>>>(h_b, gstart, gcnt, hg_pk);
    mfma_gemm<1,2><<<dim3(1, NB/64), 256, SM64, stream>>>(hg_pk, mvwpk, mvb, mv, NB, 256, HIDDEN, 0);
    k_z0<<<(NB*LAT+255)/256, 256, 0, stream>>>(mv, eps, out+off_mu, out+off_lv, out+off_z0);

    k_flows_mfma4<<<NB/16, 1024, 0, stream>>>(out+off_z0, w1hi, w1lo, fb1, w2hi, w2lo, fb2,
                                              out+off_zk, zkb, out+off_sld);

    // decoders (plain bf16 MFMA)
    mfma_gemm<0,1><<<dim3(1, NB/64), 256, SM32, stream>>>(zkb, dnw1b, dn_b1, hnb, NB, 256, LAT, 1);
    mfma_gemm<0,2><<<dim3(6, NB/64), 256, SM64, stream>>>(hnb, dnw2b, dn_b2, out+off_node, NB, MA*NNF_, 256, 0);
    mfma_gemm<0,1><<<dim3(2, NB/64), 256, SM32, stream>>>(zkb, dew1b, de_b1, heb, NB, 512, LAT, 1);
    mfma_gemm<0,2><<<dim3(23, NB/64), 256, SM64, stream>>>(heb, dew2b, de_b2, edge_raw, NB, MA*MA*NEF_, 512, 0);
    k_sym<<<(NB*MA*MA + 255)/256, 256, 0, stream>>>(edge_raw, out + off_edge);
}